// Round 1
// baseline (2646.862 us; speedup 1.0000x reference)
//
#include <hip/hip_runtime.h>
#include <math.h>

#define EDIM 32
#define NG 64

__device__ inline float wsum64(float v){
  #pragma unroll
  for (int off=32; off>0; off>>=1) v += __shfl_xor(v, off, 64);
  return v;
}

// ---------- relation table precompute: base[r]=emb/||emb||*irf ; efb = base @ We ----------
__global__ void k_rel(const float* __restrict__ emb, const float* __restrict__ irf,
                      const float* __restrict__ We1, const float* __restrict__ We2,
                      float* __restrict__ base, float* __restrict__ efb1, float* __restrict__ efb2){
  int r = blockIdx.x; int t = threadIdx.x;       // 256 threads
  __shared__ float b[EDIM];
  if (t < EDIM){
    float v = emb[r*EDIM + t];
    float ss = v*v;
    #pragma unroll
    for (int off=16; off>0; off>>=1) ss += __shfl_xor(ss, off, 64);
    float nrm = sqrtf(ss);
    float bb = v / fmaxf(nrm, 1e-12f) * irf[r];
    b[t] = bb;
    base[r*EDIM + t] = bb;
  }
  __syncthreads();
  float a1 = 0.f;
  #pragma unroll
  for (int k=0;k<EDIM;k++) a1 += b[k]*We1[k*256 + t];
  efb1[r*256 + t] = a1;
  if (t < 128){
    float a2 = 0.f;
    #pragma unroll
    for (int k=0;k<EDIM;k++) a2 += b[k]*We2[k*128 + t];
    efb2[r*128 + t] = a2;
  }
}

// ---------- CSR build ----------
__global__ void k_count(const int* __restrict__ dst, int* __restrict__ cnt, int E){
  int e = blockIdx.x*256 + threadIdx.x;
  if (e < E) atomicAdd(&cnt[dst[e]], 1);
}

__global__ __launch_bounds__(1024) void k_scan1(const int* __restrict__ cnt, int* __restrict__ incl,
                                                int* __restrict__ bsum, int n){
  __shared__ int s[1024];
  int i = blockIdx.x*1024 + threadIdx.x;
  int v = (i<n)? cnt[i] : 0;
  s[threadIdx.x] = v; __syncthreads();
  for (int off=1; off<1024; off<<=1){
    int add = (threadIdx.x>=(unsigned)off)? s[threadIdx.x-off] : 0;
    __syncthreads();
    s[threadIdx.x] += add;
    __syncthreads();
  }
  if (i<n) incl[i] = s[threadIdx.x];
  if (threadIdx.x==1023) bsum[blockIdx.x] = s[1023];
}
__global__ void k_scan2(int* __restrict__ bsum, int nb){
  if (threadIdx.x==0 && blockIdx.x==0){
    int acc=0;
    for (int b=0;b<nb;b++){ int t=bsum[b]; bsum[b]=acc; acc+=t; }
  }
}
__global__ void k_scan3(const int* __restrict__ incl, const int* __restrict__ bsum,
                        int* __restrict__ rowptr, int n){
  int i = blockIdx.x*256 + threadIdx.x;
  if (i<n) rowptr[i+1] = incl[i] + bsum[i>>10];
  if (i==0) rowptr[0] = 0;
}
__global__ void k_fill(const int* __restrict__ dst, const int* __restrict__ rowptr,
                       int* __restrict__ fill, int* __restrict__ eids, int E){
  int e = blockIdx.x*256 + threadIdx.x;
  if (e<E){ int d = dst[e]; int pos = rowptr[d] + atomicAdd(&fill[d],1); eids[pos]=e; }
}

// ---------- loop_feat[n] = (sum_in w_e * base[rel_e]) / max(deg,1) ----------
__global__ void k_loopfeat(const int* __restrict__ rowptr, const int* __restrict__ eids,
                           const int* __restrict__ rel, const float* __restrict__ ew,
                           const float* __restrict__ base, float* __restrict__ lf, int N){
  int gid = blockIdx.x*256 + threadIdx.x;
  int n = gid >> 5; int k = gid & 31;
  if (n >= N) return;
  int beg = rowptr[n], end = rowptr[n+1];
  float s = 0.f;
  for (int p=beg;p<end;p++){
    int e = eids[p];
    s += ew[e]*base[rel[e]*EDIM + k];
  }
  int c = end - beg;
  lf[n*EDIM + k] = s / (float)max(c,1);
}

// ---------- fp32 tiled GEMM: C[M,N] = A[M,K] @ B[K,N] + bias ----------
__global__ __launch_bounds__(256) void k_gemm(const float* __restrict__ A, const float* __restrict__ B,
                        const float* __restrict__ bias, float* __restrict__ C,
                        int M, int N, int K){
  const int BM=64, BN=64, BK=16;
  __shared__ float As[BK][BM];
  __shared__ float Bs[BK][BN];
  int bm = blockIdx.y*BM, bn = blockIdx.x*BN;
  int tid = threadIdx.x;
  int tx = tid & 15, ty = tid >> 4;
  float acc[4][4] = {};
  for (int k0=0;k0<K;k0+=BK){
    #pragma unroll
    for (int i=tid;i<BM*BK;i+=256){
      int r = i>>4, c = i&15;
      int gr = bm + r;
      As[c][r] = (gr<M)? A[(size_t)gr*K + k0 + c] : 0.f;
    }
    #pragma unroll
    for (int i=tid;i<BK*BN;i+=256){
      int r = i>>6, c = i&63;
      Bs[r][c] = B[(size_t)(k0+r)*N + bn + c];
    }
    __syncthreads();
    #pragma unroll
    for (int kk=0;kk<BK;kk++){
      float a[4], bb[4];
      #pragma unroll
      for (int i=0;i<4;i++) a[i] = As[kk][ty*4+i];
      #pragma unroll
      for (int j=0;j<4;j++) bb[j] = Bs[kk][tx*4+j];
      #pragma unroll
      for (int i=0;i<4;i++)
        #pragma unroll
        for (int j=0;j<4;j++) acc[i][j] += a[i]*bb[j];
    }
    __syncthreads();
  }
  #pragma unroll
  for (int i=0;i<4;i++){
    int gr = bm + ty*4 + i;
    if (gr < M){
      #pragma unroll
      for (int j=0;j<4;j++){
        int gc = bn + tx*4 + j;
        C[(size_t)gr*N + gc] = acc[i][j] + bias[gc];
      }
    }
  }
}

// ---------- fused GATv2 layer 1: H=2, C=128 ; one wave per node ----------
__global__ __launch_bounds__(256) void k_attn1(
  const float* __restrict__ xl, const float* __restrict__ xr, const float* __restrict__ xskip,
  const float* __restrict__ lf, const float* __restrict__ We1,
  const float* __restrict__ att, const float* __restrict__ bias,
  const float* __restrict__ efb1,
  const int* __restrict__ rowptr, const int* __restrict__ eids,
  const int* __restrict__ src, const int* __restrict__ rel, const float* __restrict__ ew,
  float* __restrict__ h1, int N)
{
  int wv = threadIdx.x >> 6, lane = threadIdx.x & 63;
  int n = blockIdx.x*4 + wv;
  if (n >= N) return;
  float xrr[4], av[4], xln[4], efs[4];
  #pragma unroll
  for (int j=0;j<4;j++){
    int idx = lane + 64*j;
    xrr[j] = xr[(size_t)n*256 + idx];
    xln[j] = xl[(size_t)n*256 + idx];
    av[j]  = att[idx];
    efs[j] = 0.f;
  }
  #pragma unroll
  for (int k=0;k<EDIM;k++){
    float l = lf[n*EDIM + k];
    #pragma unroll
    for (int j=0;j<4;j++) efs[j] += l*We1[k*256 + lane + 64*j];
  }
  int beg = rowptr[n], end = rowptr[n+1];
  float mx0 = -1e30f, mx1 = -1e30f;
  for (int p=beg;p<end;p++){
    int e = eids[p]; int s = src[e]; float w = ew[e]; int r = rel[e];
    float p0=0.f, p1=0.f;
    #pragma unroll
    for (int j=0;j<4;j++){
      int idx = lane + 64*j;
      float m = xl[(size_t)s*256 + idx] + xrr[j] + w*efb1[r*256 + idx];
      m = (m>0.f)? m : 0.2f*m;
      float t = av[j]*m;
      if (j<2) p0 += t; else p1 += t;
    }
    p0 = wsum64(p0); p1 = wsum64(p1);
    mx0 = fmaxf(mx0,p0); mx1 = fmaxf(mx1,p1);
  }
  float s0=0.f, s1=0.f;
  #pragma unroll
  for (int j=0;j<4;j++){
    float m = xln[j] + xrr[j] + efs[j];
    m = (m>0.f)? m : 0.2f*m;
    float t = av[j]*m;
    if (j<2) s0 += t; else s1 += t;
  }
  s0 = wsum64(s0); s1 = wsum64(s1);
  mx0 = fmaxf(mx0,s0); mx1 = fmaxf(mx1,s1);

  float den0=0.f, den1=0.f, acc[4]={0.f,0.f,0.f,0.f};
  for (int p=beg;p<end;p++){
    int e = eids[p]; int s = src[e]; float w = ew[e]; int r = rel[e];
    float xlv[4]; float p0=0.f, p1=0.f;
    #pragma unroll
    for (int j=0;j<4;j++){
      int idx = lane + 64*j;
      xlv[j] = xl[(size_t)s*256 + idx];
      float m = xlv[j] + xrr[j] + w*efb1[r*256 + idx];
      m = (m>0.f)? m : 0.2f*m;
      float t = av[j]*m;
      if (j<2) p0 += t; else p1 += t;
    }
    p0 = wsum64(p0); p1 = wsum64(p1);
    float e0 = __expf(p0-mx0), e1 = __expf(p1-mx1);
    den0 += e0; den1 += e1;
    #pragma unroll
    for (int j=0;j<4;j++) acc[j] += ((j<2)? e0 : e1) * xlv[j];
  }
  float e0s = __expf(s0-mx0), e1s = __expf(s1-mx1);
  den0 += e0s; den1 += e1s;
  #pragma unroll
  for (int j=0;j<4;j++) acc[j] += ((j<2)? e0s : e1s) * xln[j];
  float i0 = 1.f/(den0+1e-16f), i1 = 1.f/(den1+1e-16f);
  #pragma unroll
  for (int jj=0;jj<2;jj++){
    int c = lane + 64*jj;
    float v = 0.5f*(acc[jj]*i0 + acc[jj+2]*i1) + bias[c] + xskip[(size_t)n*128 + c];
    h1[(size_t)n*128 + c] = fmaxf(v, 0.f);
  }
}

// ---------- fused GATv2 layer 2: H=1, C=128 ----------
__global__ __launch_bounds__(256) void k_attn2(
  const float* __restrict__ xl, const float* __restrict__ xr,
  const float* __restrict__ lf, const float* __restrict__ We2,
  const float* __restrict__ att, const float* __restrict__ bias,
  const float* __restrict__ efb2,
  const int* __restrict__ rowptr, const int* __restrict__ eids,
  const int* __restrict__ src, const int* __restrict__ rel, const float* __restrict__ ew,
  float* __restrict__ h2, int N)
{
  int wv = threadIdx.x >> 6, lane = threadIdx.x & 63;
  int n = blockIdx.x*4 + wv;
  if (n >= N) return;
  float xrr[2], av[2], xln[2], efs[2];
  #pragma unroll
  for (int j=0;j<2;j++){
    int idx = lane + 64*j;
    xrr[j] = xr[(size_t)n*128 + idx];
    xln[j] = xl[(size_t)n*128 + idx];
    av[j]  = att[idx];
    efs[j] = 0.f;
  }
  #pragma unroll
  for (int k=0;k<EDIM;k++){
    float l = lf[n*EDIM + k];
    #pragma unroll
    for (int j=0;j<2;j++) efs[j] += l*We2[k*128 + lane + 64*j];
  }
  int beg = rowptr[n], end = rowptr[n+1];
  float mx = -1e30f;
  for (int p=beg;p<end;p++){
    int e = eids[p]; int s = src[e]; float w = ew[e]; int r = rel[e];
    float pp = 0.f;
    #pragma unroll
    for (int j=0;j<2;j++){
      int idx = lane + 64*j;
      float m = xl[(size_t)s*128 + idx] + xrr[j] + w*efb2[r*128 + idx];
      m = (m>0.f)? m : 0.2f*m;
      pp += av[j]*m;
    }
    pp = wsum64(pp);
    mx = fmaxf(mx, pp);
  }
  float ss = 0.f;
  #pragma unroll
  for (int j=0;j<2;j++){
    float m = xln[j] + xrr[j] + efs[j];
    m = (m>0.f)? m : 0.2f*m;
    ss += av[j]*m;
  }
  ss = wsum64(ss);
  mx = fmaxf(mx, ss);

  float den = 0.f, acc[2] = {0.f, 0.f};
  for (int p=beg;p<end;p++){
    int e = eids[p]; int s = src[e]; float w = ew[e]; int r = rel[e];
    float xlv[2]; float pp=0.f;
    #pragma unroll
    for (int j=0;j<2;j++){
      int idx = lane + 64*j;
      xlv[j] = xl[(size_t)s*128 + idx];
      float m = xlv[j] + xrr[j] + w*efb2[r*128 + idx];
      m = (m>0.f)? m : 0.2f*m;
      pp += av[j]*m;
    }
    pp = wsum64(pp);
    float e0 = __expf(pp - mx);
    den += e0;
    #pragma unroll
    for (int j=0;j<2;j++) acc[j] += e0 * xlv[j];
  }
  float es = __expf(ss - mx);
  den += es;
  #pragma unroll
  for (int j=0;j<2;j++) acc[j] += es * xln[j];
  float inv = 1.f/(den + 1e-16f);
  #pragma unroll
  for (int j=0;j<2;j++){
    int c = lane + 64*j;
    h2[(size_t)n*128 + c] = fmaxf(acc[j]*inv + bias[c], 0.f);
  }
}

// ---------- graph boundaries (batch sorted) ----------
__global__ void k_start(const int* __restrict__ batch, int* __restrict__ start, int N){
  int i = blockIdx.x*256 + threadIdx.x;
  if (i >= N) return;
  int b = batch[i];
  int pb = (i==0)? -1 : batch[i-1];
  for (int g=pb+1; g<=b; g++) start[g] = i;
  if (i == N-1){ for (int g=b+1; g<=NG; g++) start[g] = N; }
}

// ---------- pooling: jk=[x,h1,h2] -> [max(512) | mean(512)] per graph ----------
__global__ __launch_bounds__(256) void k_pool(const float* __restrict__ x, const float* __restrict__ h1,
                       const float* __restrict__ h2, const int* __restrict__ start,
                       float* __restrict__ xpool){
  int g = blockIdx.x; int f = blockIdx.y*256 + threadIdx.x; // f in [0,512)
  int beg = start[g], end = start[g+1];
  float mx = -1e30f, sm = 0.f;
  for (int i=beg;i<end;i++){
    float v;
    if (f < 256)      v = x[(size_t)i*256 + f];
    else if (f < 384) v = h1[(size_t)i*128 + f-256];
    else              v = h2[(size_t)i*128 + f-384];
    mx = fmaxf(mx, v); sm += v;
  }
  int c = end - beg;
  xpool[g*1024 + f]       = (c>0)? mx : 0.f;
  xpool[g*1024 + 512 + f] = sm / (float)max(c,1);
}

__global__ void k_mlp1(const float* __restrict__ xpool, const float* __restrict__ W1,
                       const float* __restrict__ b1, float* __restrict__ hmid){
  int g = blockIdx.x; int c = threadIdx.x; // 128
  float a = b1[c];
  for (int k=0;k<1024;k++) a += xpool[g*1024+k]*W1[k*128+c];
  hmid[g*128+c] = fmaxf(a, 0.f);
}
__global__ void k_mlp2(const float* __restrict__ hmid, const float* __restrict__ W2,
                       const float* __restrict__ b2, float* __restrict__ out){
  int g = threadIdx.x; if (g >= NG) return;
  float a = b2[0];
  for (int k=0;k<128;k++) a += hmid[g*128+k]*W2[k];
  out[g] = a;
}

extern "C" void kernel_launch(void* const* d_in, const int* in_sizes, int n_in,
                              void* d_out, int out_size, void* d_ws, size_t ws_size,
                              hipStream_t stream) {
  const float* x     = (const float*)d_in[0];
  const int*   eidx  = (const int*)d_in[1];
  const int*   eattr = (const int*)d_in[2];
  const float* ew    = (const float*)d_in[3];
  const int*   batch = (const int*)d_in[4];
  const float* irf   = (const float*)d_in[5];
  const float* emb   = (const float*)d_in[6];
  const float* Wl1   = (const float*)d_in[7];
  const float* bl1   = (const float*)d_in[8];
  const float* Wr1   = (const float*)d_in[9];
  const float* br1   = (const float*)d_in[10];
  const float* We1   = (const float*)d_in[11];
  const float* att1  = (const float*)d_in[12];
  const float* bias1 = (const float*)d_in[13];
  const float* Wl2   = (const float*)d_in[14];
  const float* bl2   = (const float*)d_in[15];
  const float* Wr2   = (const float*)d_in[16];
  const float* br2   = (const float*)d_in[17];
  const float* We2   = (const float*)d_in[18];
  const float* att2  = (const float*)d_in[19];
  const float* bias2 = (const float*)d_in[20];
  const float* skipW = (const float*)d_in[21];
  const float* skipb = (const float*)d_in[22];
  const float* W1    = (const float*)d_in[23];
  const float* b1    = (const float*)d_in[24];
  const float* W2    = (const float*)d_in[25];
  const float* b2    = (const float*)d_in[26];

  const int N = in_sizes[4];        // 50000
  const int E = in_sizes[3];        // 800000
  const int* srcp = eidx;
  const int* dstp = eidx + E;

  // ---- workspace carve ----
  char* w = (char*)d_ws;
  size_t off = 0;
  auto alloc = [&](size_t bytes)->void*{
    size_t o = off; off = (off + bytes + 255) & ~(size_t)255; return (void*)(w + o);
  };
  float* base  = (float*)alloc((size_t)40*EDIM*4);
  float* efb1  = (float*)alloc((size_t)40*256*4);
  float* efb2  = (float*)alloc((size_t)40*128*4);
  int*   cnt   = (int*)alloc((size_t)N*4);
  int*   fillc = (int*)alloc((size_t)N*4);
  int*   rowptr= (int*)alloc((size_t)(N+1)*4);
  int*   incl  = (int*)alloc((size_t)N*4);
  int*   bsum  = (int*)alloc((size_t)64*4);
  int*   eids  = (int*)alloc((size_t)E*4);
  float* lf    = (float*)alloc((size_t)N*EDIM*4);
  float* xl1   = (float*)alloc((size_t)N*256*4);
  float* xr1   = (float*)alloc((size_t)N*256*4);
  float* xskip = (float*)alloc((size_t)N*128*4);
  float* h1    = (float*)alloc((size_t)N*128*4);
  int*   start = (int*)alloc((size_t)(NG+1)*4);
  float* xpool = (float*)alloc((size_t)NG*1024*4);
  float* hmid  = (float*)alloc((size_t)NG*128*4);
  float* xl2 = xl1;   // reuse after layer-1 attention
  float* xr2 = xr1;

  float* outp  = (float*)d_out;        // (64,1)
  float* h2out = (float*)d_out + NG;   // (N,128)

  hipMemsetAsync(cnt,   0, (size_t)N*4, stream);
  hipMemsetAsync(fillc, 0, (size_t)N*4, stream);

  k_rel<<<40, 256, 0, stream>>>(emb, irf, We1, We2, base, efb1, efb2);
  k_count<<<(E+255)/256, 256, 0, stream>>>(dstp, cnt, E);
  int nb = (N + 1023)/1024;
  k_scan1<<<nb, 1024, 0, stream>>>(cnt, incl, bsum, N);
  k_scan2<<<1, 64, 0, stream>>>(bsum, nb);
  k_scan3<<<(N+255)/256, 256, 0, stream>>>(incl, bsum, rowptr, N);
  k_fill<<<(E+255)/256, 256, 0, stream>>>(dstp, rowptr, fillc, eids, E);
  k_loopfeat<<<((size_t)N*32+255)/256, 256, 0, stream>>>(rowptr, eids, eattr, ew, base, lf, N);

  int gy = (N + 63)/64;
  k_gemm<<<dim3(4, gy), 256, 0, stream>>>(x, Wl1, bl1, xl1, N, 256, 256);
  k_gemm<<<dim3(4, gy), 256, 0, stream>>>(x, Wr1, br1, xr1, N, 256, 256);
  k_gemm<<<dim3(2, gy), 256, 0, stream>>>(x, skipW, skipb, xskip, N, 128, 256);

  k_attn1<<<(N+3)/4, 256, 0, stream>>>(xl1, xr1, xskip, lf, We1, att1, bias1, efb1,
                                       rowptr, eids, srcp, eattr, ew, h1, N);

  k_gemm<<<dim3(2, gy), 256, 0, stream>>>(h1, Wl2, bl2, xl2, N, 128, 128);
  k_gemm<<<dim3(2, gy), 256, 0, stream>>>(h1, Wr2, br2, xr2, N, 128, 128);

  k_attn2<<<(N+3)/4, 256, 0, stream>>>(xl2, xr2, lf, We2, att2, bias2, efb2,
                                       rowptr, eids, srcp, eattr, ew, h2out, N);

  k_start<<<(N+255)/256, 256, 0, stream>>>(batch, start, N);
  k_pool<<<dim3(NG, 2), 256, 0, stream>>>(x, h1, h2out, start, xpool);
  k_mlp1<<<NG, 128, 0, stream>>>(xpool, W1, b1, hmid);
  k_mlp2<<<1, 64, 0, stream>>>(hmid, W2, b2, outp);
  (void)n_in; (void)out_size; (void)ws_size;
}

// Round 2
// 1095.933 us; speedup vs baseline: 2.4152x; 2.4152x over previous
//
#include <hip/hip_runtime.h>
#include <math.h>

#define EDIM 32
#define NG 64

// ---------- relation table precompute: base[r]=emb/||emb||*irf ; efb = base @ We ----------
__global__ void k_rel(const float* __restrict__ emb, const float* __restrict__ irf,
                      const float* __restrict__ We1, const float* __restrict__ We2,
                      float* __restrict__ base, float* __restrict__ efb1, float* __restrict__ efb2){
  int r = blockIdx.x; int t = threadIdx.x;       // 256 threads
  __shared__ float b[EDIM];
  if (t < EDIM){
    float v = emb[r*EDIM + t];
    float ss = v*v;
    #pragma unroll
    for (int off=16; off>0; off>>=1) ss += __shfl_xor(ss, off, 64);
    float nrm = sqrtf(ss);
    float bb = v / fmaxf(nrm, 1e-12f) * irf[r];
    b[t] = bb;
    base[r*EDIM + t] = bb;
  }
  __syncthreads();
  float a1 = 0.f;
  #pragma unroll
  for (int k=0;k<EDIM;k++) a1 += b[k]*We1[k*256 + t];
  efb1[r*256 + t] = a1;
  if (t < 128){
    float a2 = 0.f;
    #pragma unroll
    for (int k=0;k<EDIM;k++) a2 += b[k]*We2[k*128 + t];
    efb2[r*128 + t] = a2;
  }
}

// ---------- CSR build ----------
__global__ void k_count(const int* __restrict__ dst, int* __restrict__ cnt, int E){
  int e = blockIdx.x*256 + threadIdx.x;
  if (e < E) atomicAdd(&cnt[dst[e]], 1);
}

__global__ __launch_bounds__(1024) void k_scan1(const int* __restrict__ cnt, int* __restrict__ incl,
                                                int* __restrict__ bsum, int n){
  __shared__ int s[1024];
  int i = blockIdx.x*1024 + threadIdx.x;
  int v = (i<n)? cnt[i] : 0;
  s[threadIdx.x] = v; __syncthreads();
  for (int off=1; off<1024; off<<=1){
    int add = (threadIdx.x>=(unsigned)off)? s[threadIdx.x-off] : 0;
    __syncthreads();
    s[threadIdx.x] += add;
    __syncthreads();
  }
  if (i<n) incl[i] = s[threadIdx.x];
  if (threadIdx.x==1023) bsum[blockIdx.x] = s[1023];
}
__global__ void k_scan2(int* __restrict__ bsum, int nb){
  if (threadIdx.x==0 && blockIdx.x==0){
    int acc=0;
    for (int b=0;b<nb;b++){ int t=bsum[b]; bsum[b]=acc; acc+=t; }
  }
}
__global__ void k_scan3(const int* __restrict__ incl, const int* __restrict__ bsum,
                        int* __restrict__ rowptr, int n){
  int i = blockIdx.x*256 + threadIdx.x;
  if (i<n) rowptr[i+1] = incl[i] + bsum[i>>10];
  if (i==0) rowptr[0] = 0;
}
// scatter CSR-sorted edge metadata (removes eids indirection from hot loops)
__global__ void k_fill(const int* __restrict__ src, const int* __restrict__ dst,
                       const int* __restrict__ rel, const float* __restrict__ ew,
                       const int* __restrict__ rowptr, int* __restrict__ fill,
                       int* __restrict__ src_s, int* __restrict__ rel_s, float* __restrict__ w_s,
                       int E){
  int e = blockIdx.x*256 + threadIdx.x;
  if (e<E){
    int d = dst[e];
    int pos = rowptr[d] + atomicAdd(&fill[d],1);
    src_s[pos] = src[e];
    rel_s[pos] = rel[e];
    w_s[pos]   = ew[e];
  }
}

// ---------- loop_feat[n] = (sum_in w_e * base[rel_e]) / max(deg,1) ----------
__global__ void k_loopfeat(const int* __restrict__ rowptr, const int* __restrict__ rel_s,
                           const float* __restrict__ w_s,
                           const float* __restrict__ base, float* __restrict__ lf, int N){
  int gid = blockIdx.x*256 + threadIdx.x;
  int n = gid >> 5; int k = gid & 31;
  if (n >= N) return;
  int beg = rowptr[n], end = rowptr[n+1];
  float s = 0.f;
  for (int p=beg;p<end;p++){
    s += w_s[p]*base[rel_s[p]*EDIM + k];
  }
  int c = end - beg;
  lf[n*EDIM + k] = s / (float)max(c,1);
}

// ---------- fp32 tiled GEMM: C[M,N] = A[M,K] @ B[K,N] + bias ----------
__global__ __launch_bounds__(256) void k_gemm(const float* __restrict__ A, const float* __restrict__ B,
                        const float* __restrict__ bias, float* __restrict__ C,
                        int M, int N, int K){
  const int BM=64, BN=64, BK=16;
  __shared__ float As[BK][BM];
  __shared__ float Bs[BK][BN];
  int bm = blockIdx.y*BM, bn = blockIdx.x*BN;
  int tid = threadIdx.x;
  int tx = tid & 15, ty = tid >> 4;
  float acc[4][4] = {};
  for (int k0=0;k0<K;k0+=BK){
    #pragma unroll
    for (int i=tid;i<BM*BK;i+=256){
      int r = i>>4, c = i&15;
      int gr = bm + r;
      As[c][r] = (gr<M)? A[(size_t)gr*K + k0 + c] : 0.f;
    }
    #pragma unroll
    for (int i=tid;i<BK*BN;i+=256){
      int r = i>>6, c = i&63;
      Bs[r][c] = B[(size_t)(k0+r)*N + bn + c];
    }
    __syncthreads();
    #pragma unroll
    for (int kk=0;kk<BK;kk++){
      float a[4], bb[4];
      #pragma unroll
      for (int i=0;i<4;i++) a[i] = As[kk][ty*4+i];
      #pragma unroll
      for (int j=0;j<4;j++) bb[j] = Bs[kk][tx*4+j];
      #pragma unroll
      for (int i=0;i<4;i++)
        #pragma unroll
        for (int j=0;j<4;j++) acc[i][j] += a[i]*bb[j];
    }
    __syncthreads();
  }
  #pragma unroll
  for (int i=0;i<4;i++){
    int gr = bm + ty*4 + i;
    if (gr < M){
      #pragma unroll
      for (int j=0;j<4;j++){
        int gc = bn + tx*4 + j;
        C[(size_t)gr*N + gc] = acc[i][j] + bias[gc];
      }
    }
  }
}

// ---------- fused GATv2 layer 1: H=2, C=128 ; one wave per node, online softmax ----------
__global__ __launch_bounds__(256) void k_attn1(
  const float* __restrict__ xl, const float* __restrict__ xr, const float* __restrict__ xskip,
  const float* __restrict__ lf, const float* __restrict__ We1,
  const float* __restrict__ att, const float* __restrict__ bias,
  const float* __restrict__ efb1,
  const int* __restrict__ rowptr,
  const int* __restrict__ src_s, const int* __restrict__ rel_s, const float* __restrict__ w_s,
  float* __restrict__ h1, int N)
{
  int wv = threadIdx.x >> 6, lane = threadIdx.x & 63;
  int n = blockIdx.x*4 + wv;
  if (n >= N) return;
  float xrr[4], av[4], xln[4], efs[4];
  #pragma unroll
  for (int j=0;j<4;j++){
    int idx = lane + 64*j;
    xrr[j] = xr[(size_t)n*256 + idx];
    xln[j] = xl[(size_t)n*256 + idx];
    av[j]  = att[idx];
    efs[j] = 0.f;
  }
  #pragma unroll
  for (int k=0;k<EDIM;k++){
    float l = lf[n*EDIM + k];
    #pragma unroll
    for (int j=0;j<4;j++) efs[j] += l*We1[k*256 + lane + 64*j];
  }
  // self-loop term initializes the online-softmax state
  float s0=0.f, s1=0.f;
  #pragma unroll
  for (int j=0;j<4;j++){
    float m = xln[j] + xrr[j] + efs[j];
    m = (m>0.f)? m : 0.2f*m;
    float t = av[j]*m;
    if (j<2) s0 += t; else s1 += t;
  }
  #pragma unroll
  for (int off=32; off>0; off>>=1){
    s0 += __shfl_xor(s0, off, 64);
    s1 += __shfl_xor(s1, off, 64);
  }
  float m0 = s0, m1 = s1;
  float den0 = 1.f, den1 = 1.f;
  float acc[4] = {xln[0], xln[1], xln[2], xln[3]};

  int beg = rowptr[n], end = rowptr[n+1];
  int p = beg;
  for (; p+4 <= end; p+=4){
    int   s4[4]; float w4[4]; int r4[4];
    #pragma unroll
    for (int q=0;q<4;q++){ s4[q]=src_s[p+q]; w4[q]=w_s[p+q]; r4[q]=rel_s[p+q]; }
    float xlv[4][4], sc0[4], sc1[4];
    #pragma unroll
    for (int q=0;q<4;q++){
      float p0=0.f, p1=0.f;
      #pragma unroll
      for (int j=0;j<4;j++){
        int idx = lane + 64*j;
        float v = xl[(size_t)s4[q]*256 + idx];
        xlv[q][j] = v;
        float m = v + xrr[j] + w4[q]*efb1[r4[q]*256 + idx];
        m = (m>0.f)? m : 0.2f*m;
        float t = av[j]*m;
        if (j<2) p0 += t; else p1 += t;
      }
      sc0[q]=p0; sc1[q]=p1;
    }
    #pragma unroll
    for (int off=32; off>0; off>>=1){
      #pragma unroll
      for (int q=0;q<4;q++){
        sc0[q] += __shfl_xor(sc0[q], off, 64);
        sc1[q] += __shfl_xor(sc1[q], off, 64);
      }
    }
    #pragma unroll
    for (int q=0;q<4;q++){
      float nm0 = fmaxf(m0, sc0[q]);
      float nm1 = fmaxf(m1, sc1[q]);
      float f0 = __expf(m0-nm0), f1 = __expf(m1-nm1);
      float e0 = __expf(sc0[q]-nm0), e1 = __expf(sc1[q]-nm1);
      den0 = den0*f0 + e0; den1 = den1*f1 + e1;
      acc[0] = acc[0]*f0 + e0*xlv[q][0];
      acc[1] = acc[1]*f0 + e0*xlv[q][1];
      acc[2] = acc[2]*f1 + e1*xlv[q][2];
      acc[3] = acc[3]*f1 + e1*xlv[q][3];
      m0 = nm0; m1 = nm1;
    }
  }
  for (; p<end; p++){
    int s = src_s[p]; float w = w_s[p]; int r = rel_s[p];
    float xlv[4]; float p0=0.f, p1=0.f;
    #pragma unroll
    for (int j=0;j<4;j++){
      int idx = lane + 64*j;
      float v = xl[(size_t)s*256 + idx];
      xlv[j] = v;
      float m = v + xrr[j] + w*efb1[r*256 + idx];
      m = (m>0.f)? m : 0.2f*m;
      float t = av[j]*m;
      if (j<2) p0 += t; else p1 += t;
    }
    #pragma unroll
    for (int off=32; off>0; off>>=1){
      p0 += __shfl_xor(p0, off, 64);
      p1 += __shfl_xor(p1, off, 64);
    }
    float nm0 = fmaxf(m0, p0);
    float nm1 = fmaxf(m1, p1);
    float f0 = __expf(m0-nm0), f1 = __expf(m1-nm1);
    float e0 = __expf(p0-nm0), e1 = __expf(p1-nm1);
    den0 = den0*f0 + e0; den1 = den1*f1 + e1;
    acc[0] = acc[0]*f0 + e0*xlv[0];
    acc[1] = acc[1]*f0 + e0*xlv[1];
    acc[2] = acc[2]*f1 + e1*xlv[2];
    acc[3] = acc[3]*f1 + e1*xlv[3];
    m0 = nm0; m1 = nm1;
  }
  float i0 = 1.f/(den0+1e-16f), i1 = 1.f/(den1+1e-16f);
  #pragma unroll
  for (int jj=0;jj<2;jj++){
    int c = lane + 64*jj;
    float v = 0.5f*(acc[jj]*i0 + acc[jj+2]*i1) + bias[c] + xskip[(size_t)n*128 + c];
    h1[(size_t)n*128 + c] = fmaxf(v, 0.f);
  }
}

// ---------- fused GATv2 layer 2: H=1, C=128 ; online softmax ----------
__global__ __launch_bounds__(256) void k_attn2(
  const float* __restrict__ xl, const float* __restrict__ xr,
  const float* __restrict__ lf, const float* __restrict__ We2,
  const float* __restrict__ att, const float* __restrict__ bias,
  const float* __restrict__ efb2,
  const int* __restrict__ rowptr,
  const int* __restrict__ src_s, const int* __restrict__ rel_s, const float* __restrict__ w_s,
  float* __restrict__ h2, int N)
{
  int wv = threadIdx.x >> 6, lane = threadIdx.x & 63;
  int n = blockIdx.x*4 + wv;
  if (n >= N) return;
  float xrr[2], av[2], xln[2], efs[2];
  #pragma unroll
  for (int j=0;j<2;j++){
    int idx = lane + 64*j;
    xrr[j] = xr[(size_t)n*128 + idx];
    xln[j] = xl[(size_t)n*128 + idx];
    av[j]  = att[idx];
    efs[j] = 0.f;
  }
  #pragma unroll
  for (int k=0;k<EDIM;k++){
    float l = lf[n*EDIM + k];
    #pragma unroll
    for (int j=0;j<2;j++) efs[j] += l*We2[k*128 + lane + 64*j];
  }
  float ss = 0.f;
  #pragma unroll
  for (int j=0;j<2;j++){
    float m = xln[j] + xrr[j] + efs[j];
    m = (m>0.f)? m : 0.2f*m;
    ss += av[j]*m;
  }
  #pragma unroll
  for (int off=32; off>0; off>>=1) ss += __shfl_xor(ss, off, 64);
  float mx = ss, den = 1.f;
  float acc[2] = {xln[0], xln[1]};

  int beg = rowptr[n], end = rowptr[n+1];
  int p = beg;
  for (; p+4 <= end; p+=4){
    int s4[4]; float w4[4]; int r4[4];
    #pragma unroll
    for (int q=0;q<4;q++){ s4[q]=src_s[p+q]; w4[q]=w_s[p+q]; r4[q]=rel_s[p+q]; }
    float xlv[4][2], sc[4];
    #pragma unroll
    for (int q=0;q<4;q++){
      float pp=0.f;
      #pragma unroll
      for (int j=0;j<2;j++){
        int idx = lane + 64*j;
        float v = xl[(size_t)s4[q]*128 + idx];
        xlv[q][j] = v;
        float m = v + xrr[j] + w4[q]*efb2[r4[q]*128 + idx];
        m = (m>0.f)? m : 0.2f*m;
        pp += av[j]*m;
      }
      sc[q]=pp;
    }
    #pragma unroll
    for (int off=32; off>0; off>>=1){
      #pragma unroll
      for (int q=0;q<4;q++) sc[q] += __shfl_xor(sc[q], off, 64);
    }
    #pragma unroll
    for (int q=0;q<4;q++){
      float nm = fmaxf(mx, sc[q]);
      float f = __expf(mx-nm), e0 = __expf(sc[q]-nm);
      den = den*f + e0;
      acc[0] = acc[0]*f + e0*xlv[q][0];
      acc[1] = acc[1]*f + e0*xlv[q][1];
      mx = nm;
    }
  }
  for (; p<end; p++){
    int s = src_s[p]; float w = w_s[p]; int r = rel_s[p];
    float xlv[2]; float pp=0.f;
    #pragma unroll
    for (int j=0;j<2;j++){
      int idx = lane + 64*j;
      float v = xl[(size_t)s*128 + idx];
      xlv[j] = v;
      float m = v + xrr[j] + w*efb2[r*128 + idx];
      m = (m>0.f)? m : 0.2f*m;
      pp += av[j]*m;
    }
    #pragma unroll
    for (int off=32; off>0; off>>=1) pp += __shfl_xor(pp, off, 64);
    float nm = fmaxf(mx, pp);
    float f = __expf(mx-nm), e0 = __expf(pp-nm);
    den = den*f + e0;
    acc[0] = acc[0]*f + e0*xlv[0];
    acc[1] = acc[1]*f + e0*xlv[1];
    mx = nm;
  }
  float inv = 1.f/(den + 1e-16f);
  #pragma unroll
  for (int j=0;j<2;j++){
    int c = lane + 64*j;
    h2[(size_t)n*128 + c] = fmaxf(acc[j]*inv + bias[c], 0.f);
  }
}

// ---------- graph boundaries (batch sorted) ----------
__global__ void k_start(const int* __restrict__ batch, int* __restrict__ start, int N){
  int i = blockIdx.x*256 + threadIdx.x;
  if (i >= N) return;
  int b = batch[i];
  int pb = (i==0)? -1 : batch[i-1];
  for (int g=pb+1; g<=b; g++) start[g] = i;
  if (i == N-1){ for (int g=b+1; g<=NG; g++) start[g] = N; }
}

// ---------- pooling: jk=[x,h1,h2] -> [max(512) | mean(512)] per graph ----------
__global__ __launch_bounds__(256) void k_pool(const float* __restrict__ x, const float* __restrict__ h1,
                       const float* __restrict__ h2, const int* __restrict__ start,
                       float* __restrict__ xpool){
  int g = blockIdx.x; int f = blockIdx.y*256 + threadIdx.x; // f in [0,512)
  int beg = start[g], end = start[g+1];
  float mx = -1e30f, sm = 0.f;
  for (int i=beg;i<end;i++){
    float v;
    if (f < 256)      v = x[(size_t)i*256 + f];
    else if (f < 384) v = h1[(size_t)i*128 + f-256];
    else              v = h2[(size_t)i*128 + f-384];
    mx = fmaxf(mx, v); sm += v;
  }
  int c = end - beg;
  xpool[g*1024 + f]       = (c>0)? mx : 0.f;
  xpool[g*1024 + 512 + f] = sm / (float)max(c,1);
}

__global__ void k_mlp1(const float* __restrict__ xpool, const float* __restrict__ W1,
                       const float* __restrict__ b1, float* __restrict__ hmid){
  int g = blockIdx.x; int c = threadIdx.x; // 128
  float a = b1[c];
  for (int k=0;k<1024;k++) a += xpool[g*1024+k]*W1[k*128+c];
  hmid[g*128+c] = fmaxf(a, 0.f);
}
__global__ void k_mlp2(const float* __restrict__ hmid, const float* __restrict__ W2,
                       const float* __restrict__ b2, float* __restrict__ out){
  int g = threadIdx.x; if (g >= NG) return;
  float a = b2[0];
  for (int k=0;k<128;k++) a += hmid[g*128+k]*W2[k];
  out[g] = a;
}

extern "C" void kernel_launch(void* const* d_in, const int* in_sizes, int n_in,
                              void* d_out, int out_size, void* d_ws, size_t ws_size,
                              hipStream_t stream) {
  const float* x     = (const float*)d_in[0];
  const int*   eidx  = (const int*)d_in[1];
  const int*   eattr = (const int*)d_in[2];
  const float* ew    = (const float*)d_in[3];
  const int*   batch = (const int*)d_in[4];
  const float* irf   = (const float*)d_in[5];
  const float* emb   = (const float*)d_in[6];
  const float* Wl1   = (const float*)d_in[7];
  const float* bl1   = (const float*)d_in[8];
  const float* Wr1   = (const float*)d_in[9];
  const float* br1   = (const float*)d_in[10];
  const float* We1   = (const float*)d_in[11];
  const float* att1  = (const float*)d_in[12];
  const float* bias1 = (const float*)d_in[13];
  const float* Wl2   = (const float*)d_in[14];
  const float* bl2   = (const float*)d_in[15];
  const float* Wr2   = (const float*)d_in[16];
  const float* br2   = (const float*)d_in[17];
  const float* We2   = (const float*)d_in[18];
  const float* att2  = (const float*)d_in[19];
  const float* bias2 = (const float*)d_in[20];
  const float* skipW = (const float*)d_in[21];
  const float* skipb = (const float*)d_in[22];
  const float* W1    = (const float*)d_in[23];
  const float* b1    = (const float*)d_in[24];
  const float* W2    = (const float*)d_in[25];
  const float* b2    = (const float*)d_in[26];

  const int N = in_sizes[4];        // 50000
  const int E = in_sizes[3];        // 800000
  const int* srcp = eidx;
  const int* dstp = eidx + E;

  // ---- workspace carve ----
  char* w = (char*)d_ws;
  size_t off = 0;
  auto alloc = [&](size_t bytes)->void*{
    size_t o = off; off = (off + bytes + 255) & ~(size_t)255; return (void*)(w + o);
  };
  float* base  = (float*)alloc((size_t)40*EDIM*4);
  float* efb1  = (float*)alloc((size_t)40*256*4);
  float* efb2  = (float*)alloc((size_t)40*128*4);
  int*   cnt   = (int*)alloc((size_t)N*4);
  int*   fillc = (int*)alloc((size_t)N*4);
  int*   rowptr= (int*)alloc((size_t)(N+1)*4);
  int*   incl  = (int*)alloc((size_t)N*4);
  int*   bsum  = (int*)alloc((size_t)64*4);
  int*   src_s = (int*)alloc((size_t)E*4);
  int*   rel_s = (int*)alloc((size_t)E*4);
  float* w_s   = (float*)alloc((size_t)E*4);
  float* lf    = (float*)alloc((size_t)N*EDIM*4);
  float* xl1   = (float*)alloc((size_t)N*256*4);
  float* xr1   = (float*)alloc((size_t)N*256*4);
  float* xskip = (float*)alloc((size_t)N*128*4);
  float* h1    = (float*)alloc((size_t)N*128*4);
  int*   start = (int*)alloc((size_t)(NG+1)*4);
  float* xpool = (float*)alloc((size_t)NG*1024*4);
  float* hmid  = (float*)alloc((size_t)NG*128*4);
  float* xl2 = xl1;   // reuse after layer-1 attention
  float* xr2 = xr1;

  float* outp  = (float*)d_out;        // (64,1)
  float* h2out = (float*)d_out + NG;   // (N,128)

  hipMemsetAsync(cnt,   0, (size_t)N*4, stream);
  hipMemsetAsync(fillc, 0, (size_t)N*4, stream);

  k_rel<<<40, 256, 0, stream>>>(emb, irf, We1, We2, base, efb1, efb2);
  k_count<<<(E+255)/256, 256, 0, stream>>>(dstp, cnt, E);
  int nb = (N + 1023)/1024;
  k_scan1<<<nb, 1024, 0, stream>>>(cnt, incl, bsum, N);
  k_scan2<<<1, 64, 0, stream>>>(bsum, nb);
  k_scan3<<<(N+255)/256, 256, 0, stream>>>(incl, bsum, rowptr, N);
  k_fill<<<(E+255)/256, 256, 0, stream>>>(srcp, dstp, eattr, ew, rowptr, fillc,
                                          src_s, rel_s, w_s, E);
  k_loopfeat<<<((size_t)N*32+255)/256, 256, 0, stream>>>(rowptr, rel_s, w_s, base, lf, N);

  int gy = (N + 63)/64;
  k_gemm<<<dim3(4, gy), 256, 0, stream>>>(x, Wl1, bl1, xl1, N, 256, 256);
  k_gemm<<<dim3(4, gy), 256, 0, stream>>>(x, Wr1, br1, xr1, N, 256, 256);
  k_gemm<<<dim3(2, gy), 256, 0, stream>>>(x, skipW, skipb, xskip, N, 128, 256);

  k_attn1<<<(N+3)/4, 256, 0, stream>>>(xl1, xr1, xskip, lf, We1, att1, bias1, efb1,
                                       rowptr, src_s, rel_s, w_s, h1, N);

  k_gemm<<<dim3(2, gy), 256, 0, stream>>>(h1, Wl2, bl2, xl2, N, 128, 128);
  k_gemm<<<dim3(2, gy), 256, 0, stream>>>(h1, Wr2, br2, xr2, N, 128, 128);

  k_attn2<<<(N+3)/4, 256, 0, stream>>>(xl2, xr2, lf, We2, att2, bias2, efb2,
                                       rowptr, src_s, rel_s, w_s, h2out, N);

  k_start<<<(N+255)/256, 256, 0, stream>>>(batch, start, N);
  k_pool<<<dim3(NG, 2), 256, 0, stream>>>(x, h1, h2out, start, xpool);
  k_mlp1<<<NG, 128, 0, stream>>>(xpool, W1, b1, hmid);
  k_mlp2<<<1, 64, 0, stream>>>(hmid, W2, b2, outp);
  (void)n_in; (void)out_size; (void)ws_size;
}

// Round 3
// 827.066 us; speedup vs baseline: 3.2003x; 1.3251x over previous
//
#include <hip/hip_runtime.h>
#include <math.h>

#define EDIM 32
#define NG 64

__device__ inline unsigned enc_f(float f){
  unsigned b = __float_as_uint(f);
  return (b & 0x80000000u) ? ~b : (b | 0x80000000u);
}
__device__ inline float dec_f(unsigned u){
  unsigned b = (u & 0x80000000u) ? (u & 0x7FFFFFFFu) : ~u;
  return __uint_as_float(b);
}

// ---------- relation table precompute: base[r]=emb/||emb||*irf ; efb = base @ We ----------
__global__ void k_rel(const float* __restrict__ emb, const float* __restrict__ irf,
                      const float* __restrict__ We1, const float* __restrict__ We2,
                      float* __restrict__ base, float* __restrict__ efb1, float* __restrict__ efb2){
  int r = blockIdx.x; int t = threadIdx.x;       // 256 threads
  __shared__ float b[EDIM];
  if (t < EDIM){
    float v = emb[r*EDIM + t];
    float ss = v*v;
    #pragma unroll
    for (int off=16; off>0; off>>=1) ss += __shfl_xor(ss, off, 64);
    float nrm = sqrtf(ss);
    float bb = v / fmaxf(nrm, 1e-12f) * irf[r];
    b[t] = bb;
    base[r*EDIM + t] = bb;
  }
  __syncthreads();
  float a1 = 0.f;
  #pragma unroll
  for (int k=0;k<EDIM;k++) a1 += b[k]*We1[k*256 + t];
  efb1[r*256 + t] = a1;
  if (t < 128){
    float a2 = 0.f;
    #pragma unroll
    for (int k=0;k<EDIM;k++) a2 += b[k]*We2[k*128 + t];
    efb2[r*128 + t] = a2;
  }
}

// ---------- CSR build ----------
__global__ void k_count(const int* __restrict__ dst, int* __restrict__ cnt, int E){
  int e = blockIdx.x*256 + threadIdx.x;
  if (e < E) atomicAdd(&cnt[dst[e]], 1);
}

__global__ __launch_bounds__(1024) void k_scan1(const int* __restrict__ cnt, int* __restrict__ incl,
                                                int* __restrict__ bsum, int n){
  __shared__ int s[1024];
  int i = blockIdx.x*1024 + threadIdx.x;
  int v = (i<n)? cnt[i] : 0;
  s[threadIdx.x] = v; __syncthreads();
  for (int off=1; off<1024; off<<=1){
    int add = (threadIdx.x>=(unsigned)off)? s[threadIdx.x-off] : 0;
    __syncthreads();
    s[threadIdx.x] += add;
    __syncthreads();
  }
  if (i<n) incl[i] = s[threadIdx.x];
  if (threadIdx.x==1023) bsum[blockIdx.x] = s[1023];
}
__global__ void k_scan2(int* __restrict__ bsum, int nb){
  if (threadIdx.x==0 && blockIdx.x==0){
    int acc=0;
    for (int b=0;b<nb;b++){ int t=bsum[b]; bsum[b]=acc; acc+=t; }
  }
}
__global__ void k_scan3(const int* __restrict__ incl, const int* __restrict__ bsum,
                        int* __restrict__ rowptr, int n){
  int i = blockIdx.x*256 + threadIdx.x;
  if (i<n) rowptr[i+1] = incl[i] + bsum[i>>10];
  if (i==0) rowptr[0] = 0;
}
// scatter CSR-sorted edge metadata (removes eids indirection from hot loops)
__global__ void k_fill(const int* __restrict__ src, const int* __restrict__ dst,
                       const int* __restrict__ rel, const float* __restrict__ ew,
                       const int* __restrict__ rowptr, int* __restrict__ fill,
                       int* __restrict__ src_s, int* __restrict__ rel_s, float* __restrict__ w_s,
                       int E){
  int e = blockIdx.x*256 + threadIdx.x;
  if (e<E){
    int d = dst[e];
    int pos = rowptr[d] + atomicAdd(&fill[d],1);
    src_s[pos] = src[e];
    rel_s[pos] = rel[e];
    w_s[pos]   = ew[e];
  }
}

// ---------- loop_feat[n] = (sum_in w_e * base[rel_e]) / max(deg,1) ----------
__global__ void k_loopfeat(const int* __restrict__ rowptr, const int* __restrict__ rel_s,
                           const float* __restrict__ w_s,
                           const float* __restrict__ base, float* __restrict__ lf, int N){
  int gid = blockIdx.x*256 + threadIdx.x;
  int n = gid >> 5; int k = gid & 31;
  if (n >= N) return;
  int beg = rowptr[n], end = rowptr[n+1];
  float s = 0.f;
  for (int p=beg;p<end;p++){
    s += w_s[p]*base[rel_s[p]*EDIM + k];
  }
  int c = end - beg;
  lf[n*EDIM + k] = s / (float)max(c,1);
}

// ---------- fp32 tiled GEMM: C[M,N] = A[M,K] @ B[K,N] + bias ----------
// 128x128 tile, 8x8 microtile (4+4 split), BK=16. K,N multiples of 16/128.
__global__ __launch_bounds__(256) void k_gemm(const float* __restrict__ A, const float* __restrict__ B,
                        const float* __restrict__ bias, float* __restrict__ C,
                        int M, int N, int K){
  const int BK=16;
  __shared__ float As[BK][132];   // As[k][m], +4 pad
  __shared__ float Bs[BK][132];   // Bs[k][n], +4 pad
  int bm = blockIdx.y*128, bn = blockIdx.x*128;
  int tid = threadIdx.x;
  int tx = tid & 15, ty = tid >> 4;
  float acc[8][8] = {};
  int ar = tid>>2, ac4 = (tid&3)*4;
  int br = tid>>5, bc4 = (tid&31)*4;
  for (int k0=0;k0<K;k0+=BK){
    #pragma unroll
    for (int it=0; it<2; it++){
      int row = ar + it*64;
      int gr = bm + row;
      float4 v = make_float4(0.f,0.f,0.f,0.f);
      if (gr < M) v = *(const float4*)&A[(size_t)gr*K + k0 + ac4];
      As[ac4+0][row]=v.x; As[ac4+1][row]=v.y; As[ac4+2][row]=v.z; As[ac4+3][row]=v.w;
    }
    #pragma unroll
    for (int it=0; it<2; it++){
      int row = br + it*8;
      float4 v = *(const float4*)&B[(size_t)(k0+row)*N + bn + bc4];
      *(float4*)&Bs[row][bc4] = v;
    }
    __syncthreads();
    #pragma unroll
    for (int kk=0;kk<BK;kk++){
      float4 a0 = *(const float4*)&As[kk][ty*4];
      float4 a1 = *(const float4*)&As[kk][64+ty*4];
      float4 b0 = *(const float4*)&Bs[kk][tx*4];
      float4 b1 = *(const float4*)&Bs[kk][64+tx*4];
      float a[8] = {a0.x,a0.y,a0.z,a0.w,a1.x,a1.y,a1.z,a1.w};
      float bb[8] = {b0.x,b0.y,b0.z,b0.w,b1.x,b1.y,b1.z,b1.w};
      #pragma unroll
      for (int i=0;i<8;i++)
        #pragma unroll
        for (int j=0;j<8;j++) acc[i][j] += a[i]*bb[j];
    }
    __syncthreads();
  }
  #pragma unroll
  for (int i=0;i<8;i++){
    int row = (i<4) ? (ty*4+i) : (64+ty*4+(i-4));
    int gr = bm + row;
    if (gr < M){
      #pragma unroll
      for (int jb=0;jb<2;jb++){
        int cb = jb*64 + tx*4;
        float4 o;
        o.x = acc[i][jb*4+0] + bias[bn+cb+0];
        o.y = acc[i][jb*4+1] + bias[bn+cb+1];
        o.z = acc[i][jb*4+2] + bias[bn+cb+2];
        o.w = acc[i][jb*4+3] + bias[bn+cb+3];
        *(float4*)&C[(size_t)gr*N + bn + cb] = o;
      }
    }
  }
}

// ---------- fused GATv2 layer 1: H=2, C=128 ; one wave per node, online softmax ----------
__global__ __launch_bounds__(256) void k_attn1(
  const float* __restrict__ xl, const float* __restrict__ xr, const float* __restrict__ xskip,
  const float* __restrict__ lf, const float* __restrict__ We1,
  const float* __restrict__ att, const float* __restrict__ bias,
  const float* __restrict__ efb1,
  const int* __restrict__ rowptr,
  const int* __restrict__ src_s, const int* __restrict__ rel_s, const float* __restrict__ w_s,
  float* __restrict__ h1, int N)
{
  int wv = threadIdx.x >> 6, lane = threadIdx.x & 63;
  int n = blockIdx.x*4 + wv;
  if (n >= N) return;
  float xrr[4], av[4], xln[4], efs[4];
  #pragma unroll
  for (int j=0;j<4;j++){
    int idx = lane + 64*j;
    xrr[j] = xr[(size_t)n*256 + idx];
    xln[j] = xl[(size_t)n*256 + idx];
    av[j]  = att[idx];
    efs[j] = 0.f;
  }
  #pragma unroll
  for (int k=0;k<EDIM;k++){
    float l = lf[n*EDIM + k];
    #pragma unroll
    for (int j=0;j<4;j++) efs[j] += l*We1[k*256 + lane + 64*j];
  }
  // self-loop term initializes the online-softmax state
  float s0=0.f, s1=0.f;
  #pragma unroll
  for (int j=0;j<4;j++){
    float m = xln[j] + xrr[j] + efs[j];
    m = (m>0.f)? m : 0.2f*m;
    float t = av[j]*m;
    if (j<2) s0 += t; else s1 += t;
  }
  #pragma unroll
  for (int off=32; off>0; off>>=1){
    s0 += __shfl_xor(s0, off, 64);
    s1 += __shfl_xor(s1, off, 64);
  }
  float m0 = s0, m1 = s1;
  float den0 = 1.f, den1 = 1.f;
  float acc[4] = {xln[0], xln[1], xln[2], xln[3]};

  int beg = rowptr[n], end = rowptr[n+1];
  int p = beg;
  for (; p+4 <= end; p+=4){
    int   s4[4]; float w4[4]; int r4[4];
    #pragma unroll
    for (int q=0;q<4;q++){ s4[q]=src_s[p+q]; w4[q]=w_s[p+q]; r4[q]=rel_s[p+q]; }
    float xlv[4][4], sc0[4], sc1[4];
    #pragma unroll
    for (int q=0;q<4;q++){
      float p0=0.f, p1=0.f;
      #pragma unroll
      for (int j=0;j<4;j++){
        int idx = lane + 64*j;
        float v = xl[(size_t)s4[q]*256 + idx];
        xlv[q][j] = v;
        float m = v + xrr[j] + w4[q]*efb1[r4[q]*256 + idx];
        m = (m>0.f)? m : 0.2f*m;
        float t = av[j]*m;
        if (j<2) p0 += t; else p1 += t;
      }
      sc0[q]=p0; sc1[q]=p1;
    }
    #pragma unroll
    for (int off=32; off>0; off>>=1){
      #pragma unroll
      for (int q=0;q<4;q++){
        sc0[q] += __shfl_xor(sc0[q], off, 64);
        sc1[q] += __shfl_xor(sc1[q], off, 64);
      }
    }
    #pragma unroll
    for (int q=0;q<4;q++){
      float nm0 = fmaxf(m0, sc0[q]);
      float nm1 = fmaxf(m1, sc1[q]);
      float f0 = __expf(m0-nm0), f1 = __expf(m1-nm1);
      float e0 = __expf(sc0[q]-nm0), e1 = __expf(sc1[q]-nm1);
      den0 = den0*f0 + e0; den1 = den1*f1 + e1;
      acc[0] = acc[0]*f0 + e0*xlv[q][0];
      acc[1] = acc[1]*f0 + e0*xlv[q][1];
      acc[2] = acc[2]*f1 + e1*xlv[q][2];
      acc[3] = acc[3]*f1 + e1*xlv[q][3];
      m0 = nm0; m1 = nm1;
    }
  }
  for (; p<end; p++){
    int s = src_s[p]; float w = w_s[p]; int r = rel_s[p];
    float xlv[4]; float p0=0.f, p1=0.f;
    #pragma unroll
    for (int j=0;j<4;j++){
      int idx = lane + 64*j;
      float v = xl[(size_t)s*256 + idx];
      xlv[j] = v;
      float m = v + xrr[j] + w*efb1[r*256 + idx];
      m = (m>0.f)? m : 0.2f*m;
      float t = av[j]*m;
      if (j<2) p0 += t; else p1 += t;
    }
    #pragma unroll
    for (int off=32; off>0; off>>=1){
      p0 += __shfl_xor(p0, off, 64);
      p1 += __shfl_xor(p1, off, 64);
    }
    float nm0 = fmaxf(m0, p0);
    float nm1 = fmaxf(m1, p1);
    float f0 = __expf(m0-nm0), f1 = __expf(m1-nm1);
    float e0 = __expf(p0-nm0), e1 = __expf(p1-nm1);
    den0 = den0*f0 + e0; den1 = den1*f1 + e1;
    acc[0] = acc[0]*f0 + e0*xlv[0];
    acc[1] = acc[1]*f0 + e0*xlv[1];
    acc[2] = acc[2]*f1 + e1*xlv[2];
    acc[3] = acc[3]*f1 + e1*xlv[3];
    m0 = nm0; m1 = nm1;
  }
  float i0 = 1.f/(den0+1e-16f), i1 = 1.f/(den1+1e-16f);
  #pragma unroll
  for (int jj=0;jj<2;jj++){
    int c = lane + 64*jj;
    float v = 0.5f*(acc[jj]*i0 + acc[jj+2]*i1) + bias[c] + xskip[(size_t)n*128 + c];
    h1[(size_t)n*128 + c] = fmaxf(v, 0.f);
  }
}

// ---------- fused GATv2 layer 2: H=1, C=128 ; online softmax ----------
__global__ __launch_bounds__(256) void k_attn2(
  const float* __restrict__ xl, const float* __restrict__ xr,
  const float* __restrict__ lf, const float* __restrict__ We2,
  const float* __restrict__ att, const float* __restrict__ bias,
  const float* __restrict__ efb2,
  const int* __restrict__ rowptr,
  const int* __restrict__ src_s, const int* __restrict__ rel_s, const float* __restrict__ w_s,
  float* __restrict__ h2, int N)
{
  int wv = threadIdx.x >> 6, lane = threadIdx.x & 63;
  int n = blockIdx.x*4 + wv;
  if (n >= N) return;
  float xrr[2], av[2], xln[2], efs[2];
  #pragma unroll
  for (int j=0;j<2;j++){
    int idx = lane + 64*j;
    xrr[j] = xr[(size_t)n*128 + idx];
    xln[j] = xl[(size_t)n*128 + idx];
    av[j]  = att[idx];
    efs[j] = 0.f;
  }
  #pragma unroll
  for (int k=0;k<EDIM;k++){
    float l = lf[n*EDIM + k];
    #pragma unroll
    for (int j=0;j<2;j++) efs[j] += l*We2[k*128 + lane + 64*j];
  }
  float ss = 0.f;
  #pragma unroll
  for (int j=0;j<2;j++){
    float m = xln[j] + xrr[j] + efs[j];
    m = (m>0.f)? m : 0.2f*m;
    ss += av[j]*m;
  }
  #pragma unroll
  for (int off=32; off>0; off>>=1) ss += __shfl_xor(ss, off, 64);
  float mx = ss, den = 1.f;
  float acc[2] = {xln[0], xln[1]};

  int beg = rowptr[n], end = rowptr[n+1];
  int p = beg;
  for (; p+4 <= end; p+=4){
    int s4[4]; float w4[4]; int r4[4];
    #pragma unroll
    for (int q=0;q<4;q++){ s4[q]=src_s[p+q]; w4[q]=w_s[p+q]; r4[q]=rel_s[p+q]; }
    float xlv[4][2], sc[4];
    #pragma unroll
    for (int q=0;q<4;q++){
      float pp=0.f;
      #pragma unroll
      for (int j=0;j<2;j++){
        int idx = lane + 64*j;
        float v = xl[(size_t)s4[q]*128 + idx];
        xlv[q][j] = v;
        float m = v + xrr[j] + w4[q]*efb2[r4[q]*128 + idx];
        m = (m>0.f)? m : 0.2f*m;
        pp += av[j]*m;
      }
      sc[q]=pp;
    }
    #pragma unroll
    for (int off=32; off>0; off>>=1){
      #pragma unroll
      for (int q=0;q<4;q++) sc[q] += __shfl_xor(sc[q], off, 64);
    }
    #pragma unroll
    for (int q=0;q<4;q++){
      float nm = fmaxf(mx, sc[q]);
      float f = __expf(mx-nm), e0 = __expf(sc[q]-nm);
      den = den*f + e0;
      acc[0] = acc[0]*f + e0*xlv[q][0];
      acc[1] = acc[1]*f + e0*xlv[q][1];
      mx = nm;
    }
  }
  for (; p<end; p++){
    int s = src_s[p]; float w = w_s[p]; int r = rel_s[p];
    float xlv[2]; float pp=0.f;
    #pragma unroll
    for (int j=0;j<2;j++){
      int idx = lane + 64*j;
      float v = xl[(size_t)s*128 + idx];
      xlv[j] = v;
      float m = v + xrr[j] + w*efb2[r*128 + idx];
      m = (m>0.f)? m : 0.2f*m;
      pp += av[j]*m;
    }
    #pragma unroll
    for (int off=32; off>0; off>>=1) pp += __shfl_xor(pp, off, 64);
    float nm = fmaxf(mx, pp);
    float f = __expf(mx-nm), e0 = __expf(pp-nm);
    den = den*f + e0;
    acc[0] = acc[0]*f + e0*xlv[0];
    acc[1] = acc[1]*f + e0*xlv[1];
    mx = nm;
  }
  float inv = 1.f/(den + 1e-16f);
  #pragma unroll
  for (int j=0;j<2;j++){
    int c = lane + 64*j;
    h2[(size_t)n*128 + c] = fmaxf(acc[j]*inv + bias[c], 0.f);
  }
}

// ---------- graph boundaries (batch sorted) ----------
__global__ void k_start(const int* __restrict__ batch, int* __restrict__ start, int N){
  int i = blockIdx.x*256 + threadIdx.x;
  if (i >= N) return;
  int b = batch[i];
  int pb = (i==0)? -1 : batch[i-1];
  for (int g=pb+1; g<=b; g++) start[g] = i;
  if (i == N-1){ for (int g=b+1; g<=NG; g++) start[g] = N; }
}

// ---------- pooling stage A: per-chunk partial max/sum with atomic combine ----------
#define PCHUNK 64
__global__ __launch_bounds__(256) void k_pool_part(const float* __restrict__ x, const float* __restrict__ h1,
                       const float* __restrict__ h2, const int* __restrict__ batch,
                       unsigned* __restrict__ umax, float* __restrict__ fsum, int N){
  int c0 = blockIdx.x * PCHUNK;
  int c1 = min(c0 + PCHUNK, N);
  if (c0 >= N) return;
  int t = threadIdx.x;       // handles features t (x) and 256+t (h1/h2)
  float mx0 = -INFINITY, sm0 = 0.f, mx1 = -INFINITY, sm1 = 0.f;
  int bcur = batch[c0];
  for (int i=c0;i<c1;i++){
    int b = batch[i];
    if (b != bcur){
      atomicMax(&umax[bcur*512 + t], enc_f(mx0));
      atomicAdd(&fsum[bcur*512 + t], sm0);
      atomicMax(&umax[bcur*512 + 256 + t], enc_f(mx1));
      atomicAdd(&fsum[bcur*512 + 256 + t], sm1);
      mx0 = mx1 = -INFINITY; sm0 = sm1 = 0.f; bcur = b;
    }
    float v0 = x[(size_t)i*256 + t];
    float v1 = (t<128) ? h1[(size_t)i*128 + t] : h2[(size_t)i*128 + (t-128)];
    mx0 = fmaxf(mx0, v0); sm0 += v0;
    mx1 = fmaxf(mx1, v1); sm1 += v1;
  }
  atomicMax(&umax[bcur*512 + t], enc_f(mx0));
  atomicAdd(&fsum[bcur*512 + t], sm0);
  atomicMax(&umax[bcur*512 + 256 + t], enc_f(mx1));
  atomicAdd(&fsum[bcur*512 + 256 + t], sm1);
}

// ---------- pooling stage B: decode + mean ----------
__global__ void k_pool_final(const unsigned* __restrict__ umax, const float* __restrict__ fsum,
                             const int* __restrict__ start, float* __restrict__ xpool){
  int g = blockIdx.x; int f = blockIdx.y*256 + threadIdx.x;  // f in [0,512)
  float m = dec_f(umax[g*512 + f]);
  if (!isfinite(m)) m = 0.f;
  int cnt = start[g+1] - start[g];
  xpool[g*1024 + f]       = m;
  xpool[g*1024 + 512 + f] = fsum[g*512 + f] / (float)max(cnt,1);
}

__global__ void k_mlp1(const float* __restrict__ xpool, const float* __restrict__ W1,
                       const float* __restrict__ b1, float* __restrict__ hmid){
  int g = blockIdx.x; int c = threadIdx.x; // 128
  float a = b1[c];
  for (int k=0;k<1024;k++) a += xpool[g*1024+k]*W1[k*128+c];
  hmid[g*128+c] = fmaxf(a, 0.f);
}
__global__ void k_mlp2(const float* __restrict__ hmid, const float* __restrict__ W2,
                       const float* __restrict__ b2, float* __restrict__ out){
  int g = threadIdx.x; if (g >= NG) return;
  float a = b2[0];
  for (int k=0;k<128;k++) a += hmid[g*128+k]*W2[k];
  out[g] = a;
}

extern "C" void kernel_launch(void* const* d_in, const int* in_sizes, int n_in,
                              void* d_out, int out_size, void* d_ws, size_t ws_size,
                              hipStream_t stream) {
  const float* x     = (const float*)d_in[0];
  const int*   eidx  = (const int*)d_in[1];
  const int*   eattr = (const int*)d_in[2];
  const float* ew    = (const float*)d_in[3];
  const int*   batch = (const int*)d_in[4];
  const float* irf   = (const float*)d_in[5];
  const float* emb   = (const float*)d_in[6];
  const float* Wl1   = (const float*)d_in[7];
  const float* bl1   = (const float*)d_in[8];
  const float* Wr1   = (const float*)d_in[9];
  const float* br1   = (const float*)d_in[10];
  const float* We1   = (const float*)d_in[11];
  const float* att1  = (const float*)d_in[12];
  const float* bias1 = (const float*)d_in[13];
  const float* Wl2   = (const float*)d_in[14];
  const float* bl2   = (const float*)d_in[15];
  const float* Wr2   = (const float*)d_in[16];
  const float* br2   = (const float*)d_in[17];
  const float* We2   = (const float*)d_in[18];
  const float* att2  = (const float*)d_in[19];
  const float* bias2 = (const float*)d_in[20];
  const float* skipW = (const float*)d_in[21];
  const float* skipb = (const float*)d_in[22];
  const float* W1    = (const float*)d_in[23];
  const float* b1    = (const float*)d_in[24];
  const float* W2    = (const float*)d_in[25];
  const float* b2    = (const float*)d_in[26];

  const int N = in_sizes[4];        // 50000
  const int E = in_sizes[3];        // 800000
  const int* srcp = eidx;
  const int* dstp = eidx + E;

  // ---- workspace carve ----
  char* w = (char*)d_ws;
  size_t off = 0;
  auto alloc = [&](size_t bytes)->void*{
    size_t o = off; off = (off + bytes + 255) & ~(size_t)255; return (void*)(w + o);
  };
  float* base  = (float*)alloc((size_t)40*EDIM*4);
  float* efb1  = (float*)alloc((size_t)40*256*4);
  float* efb2  = (float*)alloc((size_t)40*128*4);
  int*   cnt   = (int*)alloc((size_t)N*4);
  int*   fillc = (int*)alloc((size_t)N*4);
  int*   rowptr= (int*)alloc((size_t)(N+1)*4);
  int*   incl  = (int*)alloc((size_t)N*4);
  int*   bsum  = (int*)alloc((size_t)64*4);
  int*   src_s = (int*)alloc((size_t)E*4);
  int*   rel_s = (int*)alloc((size_t)E*4);
  float* w_s   = (float*)alloc((size_t)E*4);
  float* lf    = (float*)alloc((size_t)N*EDIM*4);
  float* xl1   = (float*)alloc((size_t)N*256*4);
  float* xr1   = (float*)alloc((size_t)N*256*4);
  float* xskip = (float*)alloc((size_t)N*128*4);
  float* h1    = (float*)alloc((size_t)N*128*4);
  int*   start = (int*)alloc((size_t)(NG+1)*4);
  unsigned* umax = (unsigned*)alloc((size_t)NG*512*4);
  float* fsum  = (float*)alloc((size_t)NG*512*4);
  float* xpool = (float*)alloc((size_t)NG*1024*4);
  float* hmid  = (float*)alloc((size_t)NG*128*4);
  float* xl2 = xl1;   // reuse after layer-1 attention
  float* xr2 = xr1;

  float* outp  = (float*)d_out;        // (64,1)
  float* h2out = (float*)d_out + NG;   // (N,128)

  hipMemsetAsync(cnt,   0, (size_t)N*4, stream);
  hipMemsetAsync(fillc, 0, (size_t)N*4, stream);
  hipMemsetAsync(umax,  0, (size_t)NG*512*4, stream);
  hipMemsetAsync(fsum,  0, (size_t)NG*512*4, stream);

  k_rel<<<40, 256, 0, stream>>>(emb, irf, We1, We2, base, efb1, efb2);
  k_count<<<(E+255)/256, 256, 0, stream>>>(dstp, cnt, E);
  int nb = (N + 1023)/1024;
  k_scan1<<<nb, 1024, 0, stream>>>(cnt, incl, bsum, N);
  k_scan2<<<1, 64, 0, stream>>>(bsum, nb);
  k_scan3<<<(N+255)/256, 256, 0, stream>>>(incl, bsum, rowptr, N);
  k_fill<<<(E+255)/256, 256, 0, stream>>>(srcp, dstp, eattr, ew, rowptr, fillc,
                                          src_s, rel_s, w_s, E);
  k_loopfeat<<<((size_t)N*32+255)/256, 256, 0, stream>>>(rowptr, rel_s, w_s, base, lf, N);

  int gy = (N + 127)/128;
  k_gemm<<<dim3(2, gy), 256, 0, stream>>>(x, Wl1, bl1, xl1, N, 256, 256);
  k_gemm<<<dim3(2, gy), 256, 0, stream>>>(x, Wr1, br1, xr1, N, 256, 256);
  k_gemm<<<dim3(1, gy), 256, 0, stream>>>(x, skipW, skipb, xskip, N, 128, 256);

  k_attn1<<<(N+3)/4, 256, 0, stream>>>(xl1, xr1, xskip, lf, We1, att1, bias1, efb1,
                                       rowptr, src_s, rel_s, w_s, h1, N);

  k_gemm<<<dim3(1, gy), 256, 0, stream>>>(h1, Wl2, bl2, xl2, N, 128, 128);
  k_gemm<<<dim3(1, gy), 256, 0, stream>>>(h1, Wr2, br2, xr2, N, 128, 128);

  k_attn2<<<(N+3)/4, 256, 0, stream>>>(xl2, xr2, lf, We2, att2, bias2, efb2,
                                       rowptr, src_s, rel_s, w_s, h2out, N);

  k_start<<<(N+255)/256, 256, 0, stream>>>(batch, start, N);
  k_pool_part<<<(N+PCHUNK-1)/PCHUNK, 256, 0, stream>>>(x, h1, h2out, batch, umax, fsum, N);
  k_pool_final<<<dim3(NG,2), 256, 0, stream>>>(umax, fsum, start, xpool);
  k_mlp1<<<NG, 128, 0, stream>>>(xpool, W1, b1, hmid);
  k_mlp2<<<1, 64, 0, stream>>>(hmid, W2, b2, outp);
  (void)n_in; (void)out_size; (void)ws_size;
}

// Round 6
// 638.361 us; speedup vs baseline: 4.1463x; 1.2956x over previous
//
#include <hip/hip_runtime.h>
#include <math.h>

#define EDIM 32
#define NG 64

typedef __attribute__((ext_vector_type(8))) __bf16 bf16x8;
typedef __attribute__((ext_vector_type(4))) __bf16 bf16x4;
typedef __attribute__((ext_vector_type(4))) float f32x4;

__device__ inline unsigned enc_f(float f){
  unsigned b = __float_as_uint(f);
  return (b & 0x80000000u) ? ~b : (b | 0x80000000u);
}
__device__ inline float dec_f(unsigned u){
  unsigned b = (u & 0x80000000u) ? (u & 0x7FFFFFFFu) : ~u;
  return __uint_as_float(b);
}

// ---------- relation table precompute ----------
__global__ void k_rel(const float* __restrict__ emb, const float* __restrict__ irf,
                      const float* __restrict__ We1, const float* __restrict__ We2,
                      float* __restrict__ base, float* __restrict__ efb1, float* __restrict__ efb2){
  int r = blockIdx.x; int t = threadIdx.x;       // 256 threads
  __shared__ float b[EDIM];
  if (t < EDIM){
    float v = emb[r*EDIM + t];
    float ss = v*v;
    #pragma unroll
    for (int off=16; off>0; off>>=1) ss += __shfl_xor(ss, off, 64);
    float nrm = sqrtf(ss);
    float bb = v / fmaxf(nrm, 1e-12f) * irf[r];
    b[t] = bb;
    base[r*EDIM + t] = bb;
  }
  __syncthreads();
  float a1 = 0.f;
  #pragma unroll
  for (int k=0;k<EDIM;k++) a1 += b[k]*We1[k*256 + t];
  efb1[r*256 + t] = a1;
  if (t < 128){
    float a2 = 0.f;
    #pragma unroll
    for (int k=0;k<EDIM;k++) a2 += b[k]*We2[k*128 + t];
    efb2[r*128 + t] = a2;
  }
}

// ---------- weight transpose + split-bf16: W[K][N] fp32 -> WtH/WtL[N][K] ----------
__global__ void k_wcvt(const float* __restrict__ W, __bf16* __restrict__ WtH,
                       __bf16* __restrict__ WtL, int K, int nshift){
  int i = blockIdx.x*256 + threadIdx.x;
  int Nn = 1<<nshift;
  if (i < K*Nn){
    int k = i >> nshift, n = i & (Nn-1);
    float x = W[i];
    __bf16 h = (__bf16)x;
    __bf16 l = (__bf16)(x - (float)h);
    WtH[(size_t)n*K + k] = h;
    WtL[(size_t)n*K + k] = l;
  }
}

// ---------- CSR build ----------
__global__ void k_count(const int* __restrict__ dst, int* __restrict__ cnt, int E){
  int e = blockIdx.x*256 + threadIdx.x;
  if (e < E) atomicAdd(&cnt[dst[e]], 1);
}

__global__ __launch_bounds__(1024) void k_scan1(const int* __restrict__ cnt, int* __restrict__ incl,
                                                int* __restrict__ bsum, int n){
  __shared__ int s[1024];
  int i = blockIdx.x*1024 + threadIdx.x;
  int v = (i<n)? cnt[i] : 0;
  s[threadIdx.x] = v; __syncthreads();
  for (int off=1; off<1024; off<<=1){
    int add = (threadIdx.x>=(unsigned)off)? s[threadIdx.x-off] : 0;
    __syncthreads();
    s[threadIdx.x] += add;
    __syncthreads();
  }
  if (i<n) incl[i] = s[threadIdx.x];
  if (threadIdx.x==1023) bsum[blockIdx.x] = s[1023];
}
__global__ void k_scan2(int* __restrict__ bsum, int nb){
  if (threadIdx.x==0 && blockIdx.x==0){
    int acc=0;
    for (int b=0;b<nb;b++){ int t=bsum[b]; bsum[b]=acc; acc+=t; }
  }
}
__global__ void k_scan3(const int* __restrict__ incl, const int* __restrict__ bsum,
                        int* __restrict__ rowptr, int n){
  int i = blockIdx.x*256 + threadIdx.x;
  if (i<n) rowptr[i+1] = incl[i] + bsum[i>>10];
  if (i==0) rowptr[0] = 0;
}
__global__ void k_fill(const int* __restrict__ src, const int* __restrict__ dst,
                       const int* __restrict__ rel, const float* __restrict__ ew,
                       const int* __restrict__ rowptr, int* __restrict__ fill,
                       int* __restrict__ src_s, int* __restrict__ rel_s, float* __restrict__ w_s,
                       int E){
  int e = blockIdx.x*256 + threadIdx.x;
  if (e<E){
    int d = dst[e];
    int pos = rowptr[d] + atomicAdd(&fill[d],1);
    src_s[pos] = src[e];
    rel_s[pos] = rel[e];
    w_s[pos]   = ew[e];
  }
}

// ---------- loop_feat ----------
__global__ void k_loopfeat(const int* __restrict__ rowptr, const int* __restrict__ rel_s,
                           const float* __restrict__ w_s,
                           const float* __restrict__ base, float* __restrict__ lf, int N){
  int gid = blockIdx.x*256 + threadIdx.x;
  int n = gid >> 5; int k = gid & 31;
  if (n >= N) return;
  int beg = rowptr[n], end = rowptr[n+1];
  float s = 0.f;
  for (int p=beg;p<end;p++){
    s += w_s[p]*base[rel_s[p]*EDIM + k];
  }
  int c = end - beg;
  lf[n*EDIM + k] = s / (float)max(c,1);
}

// ---------- split-bf16 MFMA GEMM: C[M,N] = A[M,K](fp32) @ Bt[N,K]^T + bias ----------
// A split hi/lo in-kernel during staging; 3 MFMAs per fragment (HH + LH + HL).
// tile 128x128, 4 waves 2x2, BK=32, 16x16x32 mfma
__global__ __launch_bounds__(256) void k_gemm_split(
    const float* __restrict__ A,
    const __bf16* __restrict__ BtH, const __bf16* __restrict__ BtL,
    const float* __restrict__ bias, float* __restrict__ C,
    int M, int N, int K)
{
  __shared__ __attribute__((aligned(16))) __bf16 AsH[128][40];
  __shared__ __attribute__((aligned(16))) __bf16 AsL[128][40];
  __shared__ __attribute__((aligned(16))) __bf16 BsH[128][40];
  __shared__ __attribute__((aligned(16))) __bf16 BsL[128][40];
  int tid = threadIdx.x;
  int wid = tid>>6, lane = tid&63;
  int wm = (wid>>1)*64, wn = (wid&1)*64;
  int bm = blockIdx.y*128, bn = blockIdx.x*128;
  f32x4 acc[4][4] = {};
  int arow = tid>>3, ac4 = (tid&7)*4;      // A: 32 rows/iter, 8 float4 per row
  int brow = tid>>2, bsg = (tid&3)*8;      // B: 64 rows/iter, 4 bf16x8 per row
  int frow = lane&15, fk = (lane>>4)*8;
  for (int k0=0;k0<K;k0+=32){
    #pragma unroll
    for (int it=0;it<4;it++){
      int row = arow + it*32;
      int gr = bm + row;
      float4 v = make_float4(0.f,0.f,0.f,0.f);
      if (gr < M) v = *(const float4*)&A[(size_t)gr*K + k0 + ac4];
      bf16x4 h4, l4;
      float xs[4] = {v.x, v.y, v.z, v.w};
      #pragma unroll
      for (int z=0;z<4;z++){
        __bf16 h = (__bf16)xs[z];
        h4[z] = h;
        l4[z] = (__bf16)(xs[z] - (float)h);
      }
      *(bf16x4*)&AsH[row][ac4] = h4;
      *(bf16x4*)&AsL[row][ac4] = l4;
    }
    #pragma unroll
    for (int it=0;it<2;it++){
      int row = brow + it*64;
      bf16x8 h = *(const bf16x8*)&BtH[(size_t)(bn+row)*K + k0 + bsg];
      bf16x8 l = *(const bf16x8*)&BtL[(size_t)(bn+row)*K + k0 + bsg];
      *(bf16x8*)&BsH[row][bsg] = h;
      *(bf16x8*)&BsL[row][bsg] = l;
    }
    __syncthreads();
    bf16x8 aH[4], aL[4], bH[4], bL[4];
    #pragma unroll
    for (int i=0;i<4;i++){
      aH[i] = *(bf16x8*)&AsH[wm + i*16 + frow][fk];
      aL[i] = *(bf16x8*)&AsL[wm + i*16 + frow][fk];
    }
    #pragma unroll
    for (int j=0;j<4;j++){
      bH[j] = *(bf16x8*)&BsH[wn + j*16 + frow][fk];
      bL[j] = *(bf16x8*)&BsL[wn + j*16 + frow][fk];
    }
    #pragma unroll
    for (int i=0;i<4;i++)
      #pragma unroll
      for (int j=0;j<4;j++){
        acc[i][j] = __builtin_amdgcn_mfma_f32_16x16x32_bf16(aH[i], bH[j], acc[i][j], 0,0,0);
        acc[i][j] = __builtin_amdgcn_mfma_f32_16x16x32_bf16(aL[i], bH[j], acc[i][j], 0,0,0);
        acc[i][j] = __builtin_amdgcn_mfma_f32_16x16x32_bf16(aH[i], bL[j], acc[i][j], 0,0,0);
      }
    __syncthreads();
  }
  int cl = lane&15, rq = (lane>>4)*4;
  #pragma unroll
  for (int i=0;i<4;i++){
    #pragma unroll
    for (int r4=0;r4<4;r4++){
      int gr = bm + wm + i*16 + rq + r4;
      if (gr < M){
        #pragma unroll
        for (int j=0;j<4;j++){
          int gc = bn + wn + j*16 + cl;
          C[(size_t)gr*N + gc] = acc[i][j][r4] + bias[gc];
        }
      }
    }
  }
}

// ---------- fused GATv2 layer 1: H=2, C=128 ; one wave per node, online softmax ----------
__global__ __launch_bounds__(256) void k_attn1(
  const float* __restrict__ xl, const float* __restrict__ xr, const float* __restrict__ xskip,
  const float* __restrict__ lf, const float* __restrict__ We1,
  const float* __restrict__ att, const float* __restrict__ bias,
  const float* __restrict__ efb1,
  const int* __restrict__ rowptr,
  const int* __restrict__ src_s, const int* __restrict__ rel_s, const float* __restrict__ w_s,
  float* __restrict__ h1, int N)
{
  int wv = threadIdx.x >> 6, lane = threadIdx.x & 63;
  int n = blockIdx.x*4 + wv;
  if (n >= N) return;
  float xrr[4], av[4], xln[4], efs[4];
  #pragma unroll
  for (int j=0;j<4;j++){
    int idx = lane + 64*j;
    xrr[j] = xr[(size_t)n*256 + idx];
    xln[j] = xl[(size_t)n*256 + idx];
    av[j]  = att[idx];
    efs[j] = 0.f;
  }
  #pragma unroll
  for (int k=0;k<EDIM;k++){
    float l = lf[n*EDIM + k];
    #pragma unroll
    for (int j=0;j<4;j++) efs[j] += l*We1[k*256 + lane + 64*j];
  }
  // self-loop initializes state
  float s0=0.f, s1=0.f;
  #pragma unroll
  for (int j=0;j<4;j++){
    float m = xln[j] + xrr[j] + efs[j];
    m = (m>0.f)? m : 0.2f*m;
    float t = av[j]*m;
    if (j<2) s0 += t; else s1 += t;
  }
  #pragma unroll
  for (int off=32; off>0; off>>=1){
    s0 += __shfl_xor(s0, off, 64);
    s1 += __shfl_xor(s1, off, 64);
  }
  float m0 = s0, m1 = s1;
  float den0 = 1.f, den1 = 1.f;
  float acc[4] = {xln[0], xln[1], xln[2], xln[3]};

  int beg = rowptr[n], end = rowptr[n+1];
  int p = beg;
  for (; p+4 <= end; p+=4){
    int   s4[4]; float w4[4]; int r4[4];
    #pragma unroll
    for (int q=0;q<4;q++){ s4[q]=src_s[p+q]; w4[q]=w_s[p+q]; r4[q]=rel_s[p+q]; }
    float xlv[4][4], sc0[4], sc1[4];
    #pragma unroll
    for (int q=0;q<4;q++){
      float p0=0.f, p1=0.f;
      #pragma unroll
      for (int j=0;j<4;j++){
        int idx = lane + 64*j;
        float v = xl[(size_t)s4[q]*256 + idx];
        xlv[q][j] = v;
        float m = v + xrr[j] + w4[q]*efb1[r4[q]*256 + idx];
        m = (m>0.f)? m : 0.2f*m;
        float t = av[j]*m;
        if (j<2) p0 += t; else p1 += t;
      }
      sc0[q]=p0; sc1[q]=p1;
    }
    #pragma unroll
    for (int off=32; off>0; off>>=1){
      #pragma unroll
      for (int q=0;q<4;q++){
        sc0[q] += __shfl_xor(sc0[q], off, 64);
        sc1[q] += __shfl_xor(sc1[q], off, 64);
      }
    }
    // grouped online update (one rescale per 4 edges)
    float g0 = fmaxf(fmaxf(sc0[0],sc0[1]), fmaxf(sc0[2],sc0[3]));
    float g1 = fmaxf(fmaxf(sc1[0],sc1[1]), fmaxf(sc1[2],sc1[3]));
    float nm0 = fmaxf(m0, g0), nm1 = fmaxf(m1, g1);
    float f0 = __expf(m0-nm0), f1 = __expf(m1-nm1);
    float e0q[4], e1q[4];
    #pragma unroll
    for (int q=0;q<4;q++){ e0q[q]=__expf(sc0[q]-nm0); e1q[q]=__expf(sc1[q]-nm1); }
    den0 = den0*f0 + ((e0q[0]+e0q[1])+(e0q[2]+e0q[3]));
    den1 = den1*f1 + ((e1q[0]+e1q[1])+(e1q[2]+e1q[3]));
    #pragma unroll
    for (int j=0;j<2;j++){
      float a = acc[j]*f0;
      #pragma unroll
      for (int q=0;q<4;q++) a += e0q[q]*xlv[q][j];
      acc[j] = a;
    }
    #pragma unroll
    for (int j=2;j<4;j++){
      float a = acc[j]*f1;
      #pragma unroll
      for (int q=0;q<4;q++) a += e1q[q]*xlv[q][j];
      acc[j] = a;
    }
    m0 = nm0; m1 = nm1;
  }
  for (; p<end; p++){
    int s = src_s[p]; float w = w_s[p]; int r = rel_s[p];
    float xlv[4]; float p0=0.f, p1=0.f;
    #pragma unroll
    for (int j=0;j<4;j++){
      int idx = lane + 64*j;
      float v = xl[(size_t)s*256 + idx];
      xlv[j] = v;
      float m = v + xrr[j] + w*efb1[r*256 + idx];
      m = (m>0.f)? m : 0.2f*m;
      float t = av[j]*m;
      if (j<2) p0 += t; else p1 += t;
    }
    #pragma unroll
    for (int off=32; off>0; off>>=1){
      p0 += __shfl_xor(p0, off, 64);
      p1 += __shfl_xor(p1, off, 64);
    }
    float nm0 = fmaxf(m0, p0);
    float nm1 = fmaxf(m1, p1);
    float f0 = __expf(m0-nm0), f1 = __expf(m1-nm1);
    float e0 = __expf(p0-nm0), e1 = __expf(p1-nm1);
    den0 = den0*f0 + e0; den1 = den1*f1 + e1;
    acc[0] = acc[0]*f0 + e0*xlv[0];
    acc[1] = acc[1]*f0 + e0*xlv[1];
    acc[2] = acc[2]*f1 + e1*xlv[2];
    acc[3] = acc[3]*f1 + e1*xlv[3];
    m0 = nm0; m1 = nm1;
  }
  float i0 = 1.f/(den0+1e-16f), i1 = 1.f/(den1+1e-16f);
  #pragma unroll
  for (int jj=0;jj<2;jj++){
    int c = lane + 64*jj;
    float v = 0.5f*(acc[jj]*i0 + acc[jj+2]*i1) + bias[c] + xskip[(size_t)n*128 + c];
    h1[(size_t)n*128 + c] = fmaxf(v, 0.f);
  }
}

// ---------- fused GATv2 layer 2: H=1, C=128 ; online softmax ----------
__global__ __launch_bounds__(256) void k_attn2(
  const float* __restrict__ xl, const float* __restrict__ xr,
  const float* __restrict__ lf, const float* __restrict__ We2,
  const float* __restrict__ att, const float* __restrict__ bias,
  const float* __restrict__ efb2,
  const int* __restrict__ rowptr,
  const int* __restrict__ src_s, const int* __restrict__ rel_s, const float* __restrict__ w_s,
  float* __restrict__ h2, int N)
{
  int wv = threadIdx.x >> 6, lane = threadIdx.x & 63;
  int n = blockIdx.x*4 + wv;
  if (n >= N) return;
  float xrr[2], av[2], xln[2], efs[2];
  #pragma unroll
  for (int j=0;j<2;j++){
    int idx = lane + 64*j;
    xrr[j] = xr[(size_t)n*128 + idx];
    xln[j] = xl[(size_t)n*128 + idx];
    av[j]  = att[idx];
    efs[j] = 0.f;
  }
  #pragma unroll
  for (int k=0;k<EDIM;k++){
    float l = lf[n*EDIM + k];
    #pragma unroll
    for (int j=0;j<2;j++) efs[j] += l*We2[k*128 + lane + 64*j];
  }
  float ss = 0.f;
  #pragma unroll
  for (int j=0;j<2;j++){
    float m = xln[j] + xrr[j] + efs[j];
    m = (m>0.f)? m : 0.2f*m;
    ss += av[j]*m;
  }
  #pragma unroll
  for (int off=32; off>0; off>>=1) ss += __shfl_xor(ss, off, 64);
  float mx = ss, den = 1.f;
  float acc[2] = {xln[0], xln[1]};

  int beg = rowptr[n], end = rowptr[n+1];
  int p = beg;
  for (; p+4 <= end; p+=4){
    int s4[4]; float w4[4]; int r4[4];
    #pragma unroll
    for (int q=0;q<4;q++){ s4[q]=src_s[p+q]; w4[q]=w_s[p+q]; r4[q]=rel_s[p+q]; }
    float xlv[4][2], sc[4];
    #pragma unroll
    for (int q=0;q<4;q++){
      float pp=0.f;
      #pragma unroll
      for (int j=0;j<2;j++){
        int idx = lane + 64*j;
        float v = xl[(size_t)s4[q]*128 + idx];
        xlv[q][j] = v;
        float m = v + xrr[j] + w4[q]*efb2[r4[q]*128 + idx];
        m = (m>0.f)? m : 0.2f*m;
        pp += av[j]*m;
      }
      sc[q]=pp;
    }
    #pragma unroll
    for (int off=32; off>0; off>>=1){
      #pragma unroll
      for (int q=0;q<4;q++) sc[q] += __shfl_xor(sc[q], off, 64);
    }
    float g = fmaxf(fmaxf(sc[0],sc[1]), fmaxf(sc[2],sc[3]));
    float nm = fmaxf(mx, g);
    float f = __expf(mx-nm);
    float eq[4];
    #pragma unroll
    for (int q=0;q<4;q++) eq[q] = __expf(sc[q]-nm);
    den = den*f + ((eq[0]+eq[1])+(eq[2]+eq[3]));
    #pragma unroll
    for (int j=0;j<2;j++){
      float a = acc[j]*f;
      #pragma unroll
      for (int q=0;q<4;q++) a += eq[q]*xlv[q][j];
      acc[j] = a;
    }
    mx = nm;
  }
  for (; p<end; p++){
    int s = src_s[p]; float w = w_s[p]; int r = rel_s[p];
    float xlv[2]; float pp=0.f;
    #pragma unroll
    for (int j=0;j<2;j++){
      int idx = lane + 64*j;
      float v = xl[(size_t)s*128 + idx];
      xlv[j] = v;
      float m = v + xrr[j] + w*efb2[r*128 + idx];
      m = (m>0.f)? m : 0.2f*m;
      pp += av[j]*m;
    }
    #pragma unroll
    for (int off=32; off>0; off>>=1) pp += __shfl_xor(pp, off, 64);
    float nm = fmaxf(mx, pp);
    float f = __expf(mx-nm), e0 = __expf(pp-nm);
    den = den*f + e0;
    acc[0] = acc[0]*f + e0*xlv[0];
    acc[1] = acc[1]*f + e0*xlv[1];
    mx = nm;
  }
  float inv = 1.f/(den + 1e-16f);
  #pragma unroll
  for (int j=0;j<2;j++){
    int c = lane + 64*j;
    h2[(size_t)n*128 + c] = fmaxf(acc[j]*inv + bias[c], 0.f);
  }
}

// ---------- graph boundaries ----------
__global__ void k_start(const int* __restrict__ batch, int* __restrict__ start, int N){
  int i = blockIdx.x*256 + threadIdx.x;
  if (i >= N) return;
  int b = batch[i];
  int pb = (i==0)? -1 : batch[i-1];
  for (int g=pb+1; g<=b; g++) start[g] = i;
  if (i == N-1){ for (int g=b+1; g<=NG; g++) start[g] = N; }
}

// ---------- pooling stage A ----------
#define PCHUNK 64
__global__ __launch_bounds__(256) void k_pool_part(const float* __restrict__ x, const float* __restrict__ h1,
                       const float* __restrict__ h2, const int* __restrict__ batch,
                       unsigned* __restrict__ umax, float* __restrict__ fsum, int N){
  int c0 = blockIdx.x * PCHUNK;
  int c1 = min(c0 + PCHUNK, N);
  if (c0 >= N) return;
  int t = threadIdx.x;
  float mx0 = -INFINITY, sm0 = 0.f, mx1 = -INFINITY, sm1 = 0.f;
  int bcur = batch[c0];
  for (int i=c0;i<c1;i++){
    int b = batch[i];
    if (b != bcur){
      atomicMax(&umax[bcur*512 + t], enc_f(mx0));
      atomicAdd(&fsum[bcur*512 + t], sm0);
      atomicMax(&umax[bcur*512 + 256 + t], enc_f(mx1));
      atomicAdd(&fsum[bcur*512 + 256 + t], sm1);
      mx0 = mx1 = -INFINITY; sm0 = sm1 = 0.f; bcur = b;
    }
    float v0 = x[(size_t)i*256 + t];
    float v1 = (t<128) ? h1[(size_t)i*128 + t] : h2[(size_t)i*128 + (t-128)];
    mx0 = fmaxf(mx0, v0); sm0 += v0;
    mx1 = fmaxf(mx1, v1); sm1 += v1;
  }
  atomicMax(&umax[bcur*512 + t], enc_f(mx0));
  atomicAdd(&fsum[bcur*512 + t], sm0);
  atomicMax(&umax[bcur*512 + 256 + t], enc_f(mx1));
  atomicAdd(&fsum[bcur*512 + 256 + t], sm1);
}

// ---------- pooling stage B ----------
__global__ void k_pool_final(const unsigned* __restrict__ umax, const float* __restrict__ fsum,
                             const int* __restrict__ start, float* __restrict__ xpool){
  int g = blockIdx.x; int f = blockIdx.y*256 + threadIdx.x;
  float m = dec_f(umax[g*512 + f]);
  if (!isfinite(m)) m = 0.f;
  int cnt = start[g+1] - start[g];
  xpool[g*1024 + f]       = m;
  xpool[g*1024 + 512 + f] = fsum[g*512 + f] / (float)max(cnt,1);
}

__global__ __launch_bounds__(256) void k_mlp1(const float* __restrict__ xpool, const float* __restrict__ W1,
                       const float* __restrict__ b1, float* __restrict__ hmid){
  __shared__ float part[256];
  int g = blockIdx.x; int c = threadIdx.x & 127; int half = threadIdx.x >> 7;
  float a0=0.f,a1=0.f,a2=0.f,a3=0.f;
  int kb = half*512;
  #pragma unroll 4
  for (int k=0;k<512;k+=4){
    a0 += xpool[g*1024+kb+k+0]*W1[(kb+k+0)*128+c];
    a1 += xpool[g*1024+kb+k+1]*W1[(kb+k+1)*128+c];
    a2 += xpool[g*1024+kb+k+2]*W1[(kb+k+2)*128+c];
    a3 += xpool[g*1024+kb+k+3]*W1[(kb+k+3)*128+c];
  }
  part[threadIdx.x] = (a0+a1)+(a2+a3);
  __syncthreads();
  if (half==0){
    float a = part[c] + part[128+c] + b1[c];
    hmid[g*128+c] = fmaxf(a, 0.f);
  }
}
__global__ void k_mlp2(const float* __restrict__ hmid, const float* __restrict__ W2,
                       const float* __restrict__ b2, float* __restrict__ out){
  int g = threadIdx.x; if (g >= NG) return;
  float a = b2[0];
  for (int k=0;k<128;k++) a += hmid[g*128+k]*W2[k];
  out[g] = a;
}

extern "C" void kernel_launch(void* const* d_in, const int* in_sizes, int n_in,
                              void* d_out, int out_size, void* d_ws, size_t ws_size,
                              hipStream_t stream) {
  const float* x     = (const float*)d_in[0];
  const int*   eidx  = (const int*)d_in[1];
  const int*   eattr = (const int*)d_in[2];
  const float* ew    = (const float*)d_in[3];
  const int*   batch = (const int*)d_in[4];
  const float* irf   = (const float*)d_in[5];
  const float* emb   = (const float*)d_in[6];
  const float* Wl1   = (const float*)d_in[7];
  const float* bl1   = (const float*)d_in[8];
  const float* Wr1   = (const float*)d_in[9];
  const float* br1   = (const float*)d_in[10];
  const float* We1   = (const float*)d_in[11];
  const float* att1  = (const float*)d_in[12];
  const float* bias1 = (const float*)d_in[13];
  const float* Wl2   = (const float*)d_in[14];
  const float* bl2   = (const float*)d_in[15];
  const float* Wr2   = (const float*)d_in[16];
  const float* br2   = (const float*)d_in[17];
  const float* We2   = (const float*)d_in[18];
  const float* att2  = (const float*)d_in[19];
  const float* bias2 = (const float*)d_in[20];
  const float* skipW = (const float*)d_in[21];
  const float* skipb = (const float*)d_in[22];
  const float* W1    = (const float*)d_in[23];
  const float* b1    = (const float*)d_in[24];
  const float* W2    = (const float*)d_in[25];
  const float* b2    = (const float*)d_in[26];

  const int N = in_sizes[4];        // 50000
  const int E = in_sizes[3];        // 800000
  const int* srcp = eidx;
  const int* dstp = eidx + E;

  // ---- workspace carve ----
  char* w = (char*)d_ws;
  size_t off = 0;
  auto alloc = [&](size_t bytes)->void*{
    size_t o = off; off = (off + bytes + 255) & ~(size_t)255; return (void*)(w + o);
  };
  float* base  = (float*)alloc((size_t)40*EDIM*4);
  float* efb1  = (float*)alloc((size_t)40*256*4);
  float* efb2  = (float*)alloc((size_t)40*128*4);
  __bf16* Wl1H = (__bf16*)alloc((size_t)256*256*2);
  __bf16* Wl1L = (__bf16*)alloc((size_t)256*256*2);
  __bf16* Wr1H = (__bf16*)alloc((size_t)256*256*2);
  __bf16* Wr1L = (__bf16*)alloc((size_t)256*256*2);
  __bf16* skWH = (__bf16*)alloc((size_t)128*256*2);
  __bf16* skWL = (__bf16*)alloc((size_t)128*256*2);
  __bf16* Wl2H = (__bf16*)alloc((size_t)128*128*2);
  __bf16* Wl2L = (__bf16*)alloc((size_t)128*128*2);
  __bf16* Wr2H = (__bf16*)alloc((size_t)128*128*2);
  __bf16* Wr2L = (__bf16*)alloc((size_t)128*128*2);
  int*   cnt   = (int*)alloc((size_t)N*4);
  int*   fillc = (int*)alloc((size_t)N*4);
  int*   rowptr= (int*)alloc((size_t)(N+1)*4);
  int*   incl  = (int*)alloc((size_t)N*4);
  int*   bsum  = (int*)alloc((size_t)64*4);
  int*   src_s = (int*)alloc((size_t)E*4);
  int*   rel_s = (int*)alloc((size_t)E*4);
  float* w_s   = (float*)alloc((size_t)E*4);
  float* lf    = (float*)alloc((size_t)N*EDIM*4);
  float* xl1   = (float*)alloc((size_t)N*256*4);
  float* xr1   = (float*)alloc((size_t)N*256*4);
  float* xskip = (float*)alloc((size_t)N*128*4);
  float* h1    = (float*)alloc((size_t)N*128*4);
  int*   start = (int*)alloc((size_t)(NG+1)*4);
  unsigned* umax = (unsigned*)alloc((size_t)NG*512*4);
  float* fsum  = (float*)alloc((size_t)NG*512*4);
  float* xpool = (float*)alloc((size_t)NG*1024*4);
  float* hmid  = (float*)alloc((size_t)NG*128*4);
  float* xl2 = xl1;       // reuse after layer-1 attention
  float* xr2 = xr1;

  float* outp  = (float*)d_out;        // (64,1)
  float* h2out = (float*)d_out + NG;   // (N,128)

  hipMemsetAsync(cnt,   0, (size_t)N*4, stream);
  hipMemsetAsync(fillc, 0, (size_t)N*4, stream);
  hipMemsetAsync(umax,  0, (size_t)NG*512*4, stream);
  hipMemsetAsync(fsum,  0, (size_t)NG*512*4, stream);

  k_rel<<<40, 256, 0, stream>>>(emb, irf, We1, We2, base, efb1, efb2);
  k_wcvt<<<256, 256, 0, stream>>>(Wl1, Wl1H, Wl1L, 256, 8);
  k_wcvt<<<256, 256, 0, stream>>>(Wr1, Wr1H, Wr1L, 256, 8);
  k_wcvt<<<128, 256, 0, stream>>>(skipW, skWH, skWL, 256, 7);
  k_wcvt<<<64, 256, 0, stream>>>(Wl2, Wl2H, Wl2L, 128, 7);
  k_wcvt<<<64, 256, 0, stream>>>(Wr2, Wr2H, Wr2L, 128, 7);

  k_count<<<(E+255)/256, 256, 0, stream>>>(dstp, cnt, E);
  int nb = (N + 1023)/1024;
  k_scan1<<<nb, 1024, 0, stream>>>(cnt, incl, bsum, N);
  k_scan2<<<1, 64, 0, stream>>>(bsum, nb);
  k_scan3<<<(N+255)/256, 256, 0, stream>>>(incl, bsum, rowptr, N);
  k_fill<<<(E+255)/256, 256, 0, stream>>>(srcp, dstp, eattr, ew, rowptr, fillc,
                                          src_s, rel_s, w_s, E);
  k_loopfeat<<<((size_t)N*32+255)/256, 256, 0, stream>>>(rowptr, rel_s, w_s, base, lf, N);

  int gy = (N + 127)/128;
  k_gemm_split<<<dim3(2, gy), 256, 0, stream>>>(x, Wl1H, Wl1L, bl1, xl1, N, 256, 256);
  k_gemm_split<<<dim3(2, gy), 256, 0, stream>>>(x, Wr1H, Wr1L, br1, xr1, N, 256, 256);
  k_gemm_split<<<dim3(1, gy), 256, 0, stream>>>(x, skWH, skWL, skipb, xskip, N, 128, 256);

  k_attn1<<<(N+3)/4, 256, 0, stream>>>(xl1, xr1, xskip, lf, We1, att1, bias1, efb1,
                                       rowptr, src_s, rel_s, w_s, h1, N);

  k_gemm_split<<<dim3(1, gy), 256, 0, stream>>>(h1, Wl2H, Wl2L, bl2, xl2, N, 128, 128);
  k_gemm_split<<<dim3(1, gy), 256, 0, stream>>>(h1, Wr2H, Wr2L, br2, xr2, N, 128, 128);

  k_attn2<<<(N+3)/4, 256, 0, stream>>>(xl2, xr2, lf, We2, att2, bias2, efb2,
                                       rowptr, src_s, rel_s, w_s, h2out, N);

  k_start<<<(N+255)/256, 256, 0, stream>>>(batch, start, N);
  k_pool_part<<<(N+PCHUNK-1)/PCHUNK, 256, 0, stream>>>(x, h1, h2out, batch, umax, fsum, N);
  k_pool_final<<<dim3(NG,2), 256, 0, stream>>>(umax, fsum, start, xpool);
  k_mlp1<<<NG, 256, 0, stream>>>(xpool, W1, b1, hmid);
  k_mlp2<<<1, 64, 0, stream>>>(hmid, W2, b2, outp);
  (void)n_in; (void)out_size; (void)ws_size;
}

// Round 7
// 572.328 us; speedup vs baseline: 4.6247x; 1.1154x over previous
//
#include <hip/hip_runtime.h>
#include <math.h>

#define EDIM 32
#define NG 64

typedef __attribute__((ext_vector_type(8))) _Float16 f16x8;
typedef __attribute__((ext_vector_type(4))) _Float16 f16x4;
typedef __attribute__((ext_vector_type(4))) float f32x4;

__device__ inline unsigned enc_f(float f){
  unsigned b = __float_as_uint(f);
  return (b & 0x80000000u) ? ~b : (b | 0x80000000u);
}
__device__ inline float dec_f(unsigned u){
  unsigned b = (u & 0x80000000u) ? (u & 0x7FFFFFFFu) : ~u;
  return __uint_as_float(b);
}
__device__ inline float redux32(float v){
  #pragma unroll
  for (int off=1; off<32; off<<=1) v += __shfl_xor(v, off, 64);
  return v;
}

// ---------- relation table precompute ----------
__global__ void k_rel(const float* __restrict__ emb, const float* __restrict__ irf,
                      const float* __restrict__ We1, const float* __restrict__ We2,
                      float* __restrict__ base, float* __restrict__ efb1, float* __restrict__ efb2){
  int r = blockIdx.x; int t = threadIdx.x;       // 256 threads
  __shared__ float b[EDIM];
  if (t < EDIM){
    float v = emb[r*EDIM + t];
    float ss = v*v;
    #pragma unroll
    for (int off=16; off>0; off>>=1) ss += __shfl_xor(ss, off, 64);
    float nrm = sqrtf(ss);
    float bb = v / fmaxf(nrm, 1e-12f) * irf[r];
    b[t] = bb;
    base[r*EDIM + t] = bb;
  }
  __syncthreads();
  float a1 = 0.f;
  #pragma unroll
  for (int k=0;k<EDIM;k++) a1 += b[k]*We1[k*256 + t];
  efb1[r*256 + t] = a1;
  if (t < 128){
    float a2 = 0.f;
    #pragma unroll
    for (int k=0;k<EDIM;k++) a2 += b[k]*We2[k*128 + t];
    efb2[r*128 + t] = a2;
  }
}

// ---------- weight transpose + fp16 convert: W[K][N] fp32 -> Wt[N][K] fp16 ----------
__global__ void k_wcvt(const float* __restrict__ W, _Float16* __restrict__ Wt,
                       int K, int nshift){
  int i = blockIdx.x*256 + threadIdx.x;
  int Nn = 1<<nshift;
  if (i < K*Nn){
    int k = i >> nshift, n = i & (Nn-1);
    Wt[(size_t)n*K + k] = (_Float16)W[i];
  }
}

// ---------- bias concat + zeros ----------
__global__ void k_bcat(const float* __restrict__ bl1, const float* __restrict__ br1,
                       const float* __restrict__ skipb, const float* __restrict__ bl2,
                       const float* __restrict__ br2,
                       float* __restrict__ bcat1, float* __restrict__ bcat2){
  int t = blockIdx.x*256 + threadIdx.x;
  if (t < 256) bcat1[t] = bl1[t];
  else if (t < 512) bcat1[t] = br1[t-256];
  else if (t < 640) bcat1[t] = skipb[t-512];
  if (t < 128) bcat2[t] = bl2[t];
  else if (t < 256) bcat2[t] = br2[t-128];
}

// ---------- CSR build ----------
__global__ void k_count(const int* __restrict__ dst, int* __restrict__ cnt, int E){
  int e = blockIdx.x*256 + threadIdx.x;
  if (e < E) atomicAdd(&cnt[dst[e]], 1);
}

__global__ __launch_bounds__(1024) void k_scan1(const int* __restrict__ cnt, int* __restrict__ incl,
                                                int* __restrict__ bsum, int n){
  __shared__ int s[1024];
  int i = blockIdx.x*1024 + threadIdx.x;
  int v = (i<n)? cnt[i] : 0;
  s[threadIdx.x] = v; __syncthreads();
  for (int off=1; off<1024; off<<=1){
    int add = (threadIdx.x>=(unsigned)off)? s[threadIdx.x-off] : 0;
    __syncthreads();
    s[threadIdx.x] += add;
    __syncthreads();
  }
  if (i<n) incl[i] = s[threadIdx.x];
  if (threadIdx.x==1023) bsum[blockIdx.x] = s[1023];
}
__global__ void k_scan2(int* __restrict__ bsum, int nb){
  if (threadIdx.x==0 && blockIdx.x==0){
    int acc=0;
    for (int b=0;b<nb;b++){ int t=bsum[b]; bsum[b]=acc; acc+=t; }
  }
}
__global__ void k_scan3(const int* __restrict__ incl, const int* __restrict__ bsum,
                        int* __restrict__ rowptr, int n){
  int i = blockIdx.x*256 + threadIdx.x;
  if (i<n) rowptr[i+1] = incl[i] + bsum[i>>10];
  if (i==0) rowptr[0] = 0;
}
__global__ void k_fill(const int* __restrict__ src, const int* __restrict__ dst,
                       const int* __restrict__ rel, const float* __restrict__ ew,
                       const int* __restrict__ rowptr, int* __restrict__ fill,
                       int* __restrict__ src_s, int* __restrict__ rel_s, float* __restrict__ w_s,
                       int E){
  int e = blockIdx.x*256 + threadIdx.x;
  if (e<E){
    int d = dst[e];
    int pos = rowptr[d] + atomicAdd(&fill[d],1);
    src_s[pos] = src[e];
    rel_s[pos] = rel[e];
    w_s[pos]   = ew[e];
  }
}

// ---------- loop_feat ----------
__global__ void k_loopfeat(const int* __restrict__ rowptr, const int* __restrict__ rel_s,
                           const float* __restrict__ w_s,
                           const float* __restrict__ base, float* __restrict__ lf, int N){
  int gid = blockIdx.x*256 + threadIdx.x;
  int n = gid >> 5; int k = gid & 31;
  if (n >= N) return;
  int beg = rowptr[n], end = rowptr[n+1];
  float s = 0.f;
  for (int p=beg;p<end;p++){
    s += w_s[p]*base[rel_s[p]*EDIM + k];
  }
  int c = end - beg;
  lf[n*EDIM + k] = s / (float)max(c,1);
}

// ---------- fp16 MFMA GEMM: C[M,N] = A[M,K](fp32, cvt in staging) @ Bt[N,K]^T + bias ----------
// tile 128x128, 4 waves 2x2, BK=32, 16x16x32 f16 mfma
__global__ __launch_bounds__(256) void k_gemm_f16(
    const float* __restrict__ A, const _Float16* __restrict__ Bt,
    const float* __restrict__ bias, float* __restrict__ C,
    int M, int N, int K)
{
  __shared__ __attribute__((aligned(16))) _Float16 As[128][40];
  __shared__ __attribute__((aligned(16))) _Float16 Bs[128][40];
  int tid = threadIdx.x;
  int wid = tid>>6, lane = tid&63;
  int wm = (wid>>1)*64, wn = (wid&1)*64;
  int bm = blockIdx.y*128, bn = blockIdx.x*128;
  f32x4 acc[4][4] = {};
  int arow = tid>>3, ac4 = (tid&7)*4;
  int brow = tid>>2, bsg = (tid&3)*8;
  int frow = lane&15, fk = (lane>>4)*8;
  for (int k0=0;k0<K;k0+=32){
    #pragma unroll
    for (int it=0;it<4;it++){
      int row = arow + it*32;
      int gr = bm + row;
      float4 v = make_float4(0.f,0.f,0.f,0.f);
      if (gr < M) v = *(const float4*)&A[(size_t)gr*K + k0 + ac4];
      f16x4 h4;
      h4[0]=(_Float16)v.x; h4[1]=(_Float16)v.y; h4[2]=(_Float16)v.z; h4[3]=(_Float16)v.w;
      *(f16x4*)&As[row][ac4] = h4;
    }
    #pragma unroll
    for (int it=0;it<2;it++){
      int row = brow + it*64;
      f16x8 u = *(const f16x8*)&Bt[(size_t)(bn+row)*K + k0 + bsg];
      *(f16x8*)&Bs[row][bsg] = u;
    }
    __syncthreads();
    f16x8 af[4], bfr[4];
    #pragma unroll
    for (int i=0;i<4;i++) af[i]  = *(f16x8*)&As[wm + i*16 + frow][fk];
    #pragma unroll
    for (int j=0;j<4;j++) bfr[j] = *(f16x8*)&Bs[wn + j*16 + frow][fk];
    #pragma unroll
    for (int i=0;i<4;i++)
      #pragma unroll
      for (int j=0;j<4;j++)
        acc[i][j] = __builtin_amdgcn_mfma_f32_16x16x32_f16(af[i], bfr[j], acc[i][j], 0,0,0);
    __syncthreads();
  }
  int cl = lane&15, rq = (lane>>4)*4;
  #pragma unroll
  for (int i=0;i<4;i++){
    #pragma unroll
    for (int r4=0;r4<4;r4++){
      int gr = bm + wm + i*16 + rq + r4;
      if (gr < M){
        #pragma unroll
        for (int j=0;j<4;j++){
          int gc = bn + wn + j*16 + cl;
          C[(size_t)gr*N + gc] = acc[i][j][r4] + bias[gc];
        }
      }
    }
  }
}

// ---------- fused GATv2 layer 1: H=2, head-split halves, float4, online softmax ----------
// xg: [N][640] = xl(0..255) | xr(256..511) | xskip(512..639)
__global__ __launch_bounds__(256) void k_attn1(
  const float* __restrict__ xg, const float* __restrict__ lf, const float* __restrict__ We1,
  const float* __restrict__ att, const float* __restrict__ bias,
  const float* __restrict__ efb1,
  const int* __restrict__ rowptr,
  const int* __restrict__ src_s, const int* __restrict__ rel_s, const float* __restrict__ w_s,
  float* __restrict__ h1, int N)
{
  int wv = threadIdx.x >> 6, lane = threadIdx.x & 63;
  int n = blockIdx.x*4 + wv;
  if (n >= N) return;
  int half = lane >> 5, l5 = lane & 31;
  int ch = half*128 + l5*4;
  f32x4 xr4  = *(const f32x4*)&xg[(size_t)n*640 + 256 + ch];
  f32x4 xln4 = *(const f32x4*)&xg[(size_t)n*640 + ch];
  f32x4 av4  = *(const f32x4*)&att[ch];
  f32x4 ef4 = {0.f,0.f,0.f,0.f};
  #pragma unroll
  for (int k=0;k<EDIM;k++){
    float l = lf[n*EDIM + k];
    f32x4 wv4 = *(const f32x4*)&We1[k*256 + ch];
    #pragma unroll
    for (int z=0;z<4;z++) ef4[z] += l*wv4[z];
  }
  // self-loop
  float s = 0.f;
  #pragma unroll
  for (int z=0;z<4;z++){
    float m = xln4[z] + xr4[z] + ef4[z];
    m = fmaxf(m, 0.2f*m);
    s += av4[z]*m;
  }
  s = redux32(s);
  float mx = s, den = 1.f;
  f32x4 acc4 = xln4;

  int beg = rowptr[n], end = rowptr[n+1];
  int p = beg;
  for (; p+4 <= end; p+=4){
    int s4[4]; float w4[4]; int r4[4];
    #pragma unroll
    for (int q=0;q<4;q++){ s4[q]=src_s[p+q]; w4[q]=w_s[p+q]; r4[q]=rel_s[p+q]; }
    f32x4 xv[4]; float sc[4];
    #pragma unroll
    for (int q=0;q<4;q++){
      xv[q] = *(const f32x4*)&xg[(size_t)s4[q]*640 + ch];
      f32x4 e4 = *(const f32x4*)&efb1[r4[q]*256 + ch];
      float t = 0.f;
      #pragma unroll
      for (int z=0;z<4;z++){
        float m = xv[q][z] + xr4[z] + w4[q]*e4[z];
        m = fmaxf(m, 0.2f*m);
        t += av4[z]*m;
      }
      sc[q] = t;
    }
    #pragma unroll
    for (int off=1; off<32; off<<=1){
      #pragma unroll
      for (int q=0;q<4;q++) sc[q] += __shfl_xor(sc[q], off, 64);
    }
    float g = fmaxf(fmaxf(sc[0],sc[1]), fmaxf(sc[2],sc[3]));
    float nm = fmaxf(mx, g);
    float f = __expf(mx-nm);
    float e0=__expf(sc[0]-nm), e1=__expf(sc[1]-nm), e2=__expf(sc[2]-nm), e3=__expf(sc[3]-nm);
    den = den*f + ((e0+e1)+(e2+e3));
    #pragma unroll
    for (int z=0;z<4;z++)
      acc4[z] = acc4[z]*f + e0*xv[0][z] + e1*xv[1][z] + e2*xv[2][z] + e3*xv[3][z];
    mx = nm;
  }
  for (; p<end; p++){
    int sE = src_s[p]; float wE = w_s[p]; int rE = rel_s[p];
    f32x4 xv = *(const f32x4*)&xg[(size_t)sE*640 + ch];
    f32x4 e4 = *(const f32x4*)&efb1[rE*256 + ch];
    float t = 0.f;
    #pragma unroll
    for (int z=0;z<4;z++){
      float m = xv[z] + xr4[z] + wE*e4[z];
      m = fmaxf(m, 0.2f*m);
      t += av4[z]*m;
    }
    t = redux32(t);
    float nm = fmaxf(mx, t);
    float f = __expf(mx-nm), ev = __expf(t-nm);
    den = den*f + ev;
    #pragma unroll
    for (int z=0;z<4;z++) acc4[z] = acc4[z]*f + ev*xv[z];
    mx = nm;
  }
  float inv = 1.f/(den + 1e-16f);
  float res[4];
  #pragma unroll
  for (int z=0;z<4;z++){
    float v = acc4[z]*inv;
    float o = __shfl_xor(v, 32, 64);
    res[z] = 0.5f*(v + o);
  }
  if (half == 0){
    f32x4 sk = *(const f32x4*)&xg[(size_t)n*640 + 512 + l5*4];
    f32x4 b4 = *(const f32x4*)&bias[l5*4];
    f32x4 o;
    #pragma unroll
    for (int z=0;z<4;z++) o[z] = fmaxf(res[z] + b4[z] + sk[z], 0.f);
    *(f32x4*)&h1[(size_t)n*128 + l5*4] = o;
  }
}

// ---------- fused GATv2 layer 2: H=1, edge-pair halves, float4, online softmax ----------
// xg2: [N][256] = xl2(0..127) | xr2(128..255)
__global__ __launch_bounds__(256) void k_attn2(
  const float* __restrict__ xg2, const float* __restrict__ lf, const float* __restrict__ We2,
  const float* __restrict__ att, const float* __restrict__ bias,
  const float* __restrict__ efb2,
  const int* __restrict__ rowptr,
  const int* __restrict__ src_s, const int* __restrict__ rel_s, const float* __restrict__ w_s,
  float* __restrict__ h2, int N)
{
  int wv = threadIdx.x >> 6, lane = threadIdx.x & 63;
  int n = blockIdx.x*4 + wv;
  if (n >= N) return;
  int half = lane >> 5, l5 = lane & 31;
  int ch = l5*4;
  f32x4 xr4  = *(const f32x4*)&xg2[(size_t)n*256 + 128 + ch];
  f32x4 xln4 = *(const f32x4*)&xg2[(size_t)n*256 + ch];
  f32x4 av4  = *(const f32x4*)&att[ch];
  f32x4 ef4 = {0.f,0.f,0.f,0.f};
  #pragma unroll
  for (int k=0;k<EDIM;k++){
    float l = lf[n*EDIM + k];
    f32x4 wv4 = *(const f32x4*)&We2[k*128 + ch];
    #pragma unroll
    for (int z=0;z<4;z++) ef4[z] += l*wv4[z];
  }
  float s = 0.f;
  #pragma unroll
  for (int z=0;z<4;z++){
    float m = xln4[z] + xr4[z] + ef4[z];
    m = fmaxf(m, 0.2f*m);
    s += av4[z]*m;
  }
  s = redux32(s);
  float mx, den;
  f32x4 acc4;
  if (half == 0){ mx = s; den = 1.f; acc4 = xln4; }
  else { mx = -1e30f; den = 0.f; acc4 = (f32x4){0.f,0.f,0.f,0.f}; }

  int beg = rowptr[n], end = rowptr[n+1];
  int cntE = end - beg;
  int nfull = cntE & ~7;
  for (int q8=0; q8<nfull; q8+=8){
    int base = beg + q8;
    int s4[4]; float w4[4]; int r4[4];
    #pragma unroll
    for (int q=0;q<4;q++){
      int e = base + 2*q + half;
      s4[q]=src_s[e]; w4[q]=w_s[e]; r4[q]=rel_s[e];
    }
    f32x4 xv[4]; float sc[4];
    #pragma unroll
    for (int q=0;q<4;q++){
      xv[q] = *(const f32x4*)&xg2[(size_t)s4[q]*256 + ch];
      f32x4 e4 = *(const f32x4*)&efb2[r4[q]*128 + ch];
      float t = 0.f;
      #pragma unroll
      for (int z=0;z<4;z++){
        float m = xv[q][z] + xr4[z] + w4[q]*e4[z];
        m = fmaxf(m, 0.2f*m);
        t += av4[z]*m;
      }
      sc[q] = t;
    }
    #pragma unroll
    for (int off=1; off<32; off<<=1){
      #pragma unroll
      for (int q=0;q<4;q++) sc[q] += __shfl_xor(sc[q], off, 64);
    }
    float g = fmaxf(fmaxf(sc[0],sc[1]), fmaxf(sc[2],sc[3]));
    float nm = fmaxf(mx, g);
    float f = __expf(mx-nm);
    float e0=__expf(sc[0]-nm), e1=__expf(sc[1]-nm), e2=__expf(sc[2]-nm), e3=__expf(sc[3]-nm);
    den = den*f + ((e0+e1)+(e2+e3));
    #pragma unroll
    for (int z=0;z<4;z++)
      acc4[z] = acc4[z]*f + e0*xv[0][z] + e1*xv[1][z] + e2*xv[2][z] + e3*xv[3][z];
    mx = nm;
  }
  for (int t0 = beg + nfull; t0 < end; t0 += 2){
    int e = t0 + half;
    if (e < end){
      int sE = src_s[e]; float wE = w_s[e]; int rE = rel_s[e];
      f32x4 xv = *(const f32x4*)&xg2[(size_t)sE*256 + ch];
      f32x4 e4 = *(const f32x4*)&efb2[rE*128 + ch];
      float t = 0.f;
      #pragma unroll
      for (int z=0;z<4;z++){
        float m = xv[z] + xr4[z] + wE*e4[z];
        m = fmaxf(m, 0.2f*m);
        t += av4[z]*m;
      }
      t = redux32(t);
      float nm = fmaxf(mx, t);
      float f = __expf(mx-nm), ev = __expf(t-nm);
      den = den*f + ev;
      #pragma unroll
      for (int z=0;z<4;z++) acc4[z] = acc4[z]*f + ev*xv[z];
      mx = nm;
    }
  }
  // merge the two halves' online states
  float mo = __shfl_xor(mx, 32, 64);
  float deno = __shfl_xor(den, 32, 64);
  f32x4 acco;
  #pragma unroll
  for (int z=0;z<4;z++) acco[z] = __shfl_xor(acc4[z], 32, 64);
  float mt = fmaxf(mx, mo);
  float fs = __expf(mx - mt), fo = __expf(mo - mt);
  den = den*fs + deno*fo;
  #pragma unroll
  for (int z=0;z<4;z++) acc4[z] = acc4[z]*fs + acco[z]*fo;
  float inv = 1.f/(den + 1e-16f);
  if (half == 0){
    f32x4 b4 = *(const f32x4*)&bias[ch];
    f32x4 o;
    #pragma unroll
    for (int z=0;z<4;z++) o[z] = fmaxf(acc4[z]*inv + b4[z], 0.f);
    *(f32x4*)&h2[(size_t)n*128 + ch] = o;
  }
}

// ---------- graph boundaries ----------
__global__ void k_start(const int* __restrict__ batch, int* __restrict__ start, int N){
  int i = blockIdx.x*256 + threadIdx.x;
  if (i >= N) return;
  int b = batch[i];
  int pb = (i==0)? -1 : batch[i-1];
  for (int g=pb+1; g<=b; g++) start[g] = i;
  if (i == N-1){ for (int g=b+1; g<=NG; g++) start[g] = N; }
}

// ---------- pooling stage A ----------
#define PCHUNK 64
__global__ __launch_bounds__(256) void k_pool_part(const float* __restrict__ x, const float* __restrict__ h1,
                       const float* __restrict__ h2, const int* __restrict__ batch,
                       unsigned* __restrict__ umax, float* __restrict__ fsum, int N){
  int c0 = blockIdx.x * PCHUNK;
  int c1 = min(c0 + PCHUNK, N);
  if (c0 >= N) return;
  int t = threadIdx.x;
  float mx0 = -INFINITY, sm0 = 0.f, mx1 = -INFINITY, sm1 = 0.f;
  int bcur = batch[c0];
  for (int i=c0;i<c1;i++){
    int b = batch[i];
    if (b != bcur){
      atomicMax(&umax[bcur*512 + t], enc_f(mx0));
      atomicAdd(&fsum[bcur*512 + t], sm0);
      atomicMax(&umax[bcur*512 + 256 + t], enc_f(mx1));
      atomicAdd(&fsum[bcur*512 + 256 + t], sm1);
      mx0 = mx1 = -INFINITY; sm0 = sm1 = 0.f; bcur = b;
    }
    float v0 = x[(size_t)i*256 + t];
    float v1 = (t<128) ? h1[(size_t)i*128 + t] : h2[(size_t)i*128 + (t-128)];
    mx0 = fmaxf(mx0, v0); sm0 += v0;
    mx1 = fmaxf(mx1, v1); sm1 += v1;
  }
  atomicMax(&umax[bcur*512 + t], enc_f(mx0));
  atomicAdd(&fsum[bcur*512 + t], sm0);
  atomicMax(&umax[bcur*512 + 256 + t], enc_f(mx1));
  atomicAdd(&fsum[bcur*512 + 256 + t], sm1);
}

// ---------- pooling stage B ----------
__global__ void k_pool_final(const unsigned* __restrict__ umax, const float* __restrict__ fsum,
                             const int* __restrict__ start, float* __restrict__ xpool){
  int g = blockIdx.x; int f = blockIdx.y*256 + threadIdx.x;
  float m = dec_f(umax[g*512 + f]);
  if (!isfinite(m)) m = 0.f;
  int cnt = start[g+1] - start[g];
  xpool[g*1024 + f]       = m;
  xpool[g*1024 + 512 + f] = fsum[g*512 + f] / (float)max(cnt,1);
}

__global__ __launch_bounds__(256) void k_mlp1(const float* __restrict__ xpool, const float* __restrict__ W1,
                       const float* __restrict__ b1, float* __restrict__ hmid){
  __shared__ float part[256];
  int g = blockIdx.x; int c = threadIdx.x & 127; int half = threadIdx.x >> 7;
  float a0=0.f,a1=0.f,a2=0.f,a3=0.f;
  int kb = half*512;
  #pragma unroll 4
  for (int k=0;k<512;k+=4){
    a0 += xpool[g*1024+kb+k+0]*W1[(kb+k+0)*128+c];
    a1 += xpool[g*1024+kb+k+1]*W1[(kb+k+1)*128+c];
    a2 += xpool[g*1024+kb+k+2]*W1[(kb+k+2)*128+c];
    a3 += xpool[g*1024+kb+k+3]*W1[(kb+k+3)*128+c];
  }
  part[threadIdx.x] = (a0+a1)+(a2+a3);
  __syncthreads();
  if (half==0){
    float a = part[c] + part[128+c] + b1[c];
    hmid[g*128+c] = fmaxf(a, 0.f);
  }
}
__global__ void k_mlp2(const float* __restrict__ hmid, const float* __restrict__ W2,
                       const float* __restrict__ b2, float* __restrict__ out){
  int g = threadIdx.x; if (g >= NG) return;
  float a = b2[0];
  for (int k=0;k<128;k++) a += hmid[g*128+k]*W2[k];
  out[g] = a;
}

extern "C" void kernel_launch(void* const* d_in, const int* in_sizes, int n_in,
                              void* d_out, int out_size, void* d_ws, size_t ws_size,
                              hipStream_t stream) {
  const float* x     = (const float*)d_in[0];
  const int*   eidx  = (const int*)d_in[1];
  const int*   eattr = (const int*)d_in[2];
  const float* ew    = (const float*)d_in[3];
  const int*   batch = (const int*)d_in[4];
  const float* irf   = (const float*)d_in[5];
  const float* emb   = (const float*)d_in[6];
  const float* Wl1   = (const float*)d_in[7];
  const float* bl1   = (const float*)d_in[8];
  const float* Wr1   = (const float*)d_in[9];
  const float* br1   = (const float*)d_in[10];
  const float* We1   = (const float*)d_in[11];
  const float* att1  = (const float*)d_in[12];
  const float* bias1 = (const float*)d_in[13];
  const float* Wl2   = (const float*)d_in[14];
  const float* bl2   = (const float*)d_in[15];
  const float* Wr2   = (const float*)d_in[16];
  const float* br2   = (const float*)d_in[17];
  const float* We2   = (const float*)d_in[18];
  const float* att2  = (const float*)d_in[19];
  const float* bias2 = (const float*)d_in[20];
  const float* skipW = (const float*)d_in[21];
  const float* skipb = (const float*)d_in[22];
  const float* W1    = (const float*)d_in[23];
  const float* b1    = (const float*)d_in[24];
  const float* W2    = (const float*)d_in[25];
  const float* b2    = (const float*)d_in[26];

  const int N = in_sizes[4];        // 50000
  const int E = in_sizes[3];        // 800000
  const int* srcp = eidx;
  const int* dstp = eidx + E;

  // ---- workspace carve ----
  char* w = (char*)d_ws;
  size_t off = 0;
  auto alloc = [&](size_t bytes)->void*{
    size_t o = off; off = (off + bytes + 255) & ~(size_t)255; return (void*)(w + o);
  };
  float* base  = (float*)alloc((size_t)40*EDIM*4);
  float* efb1  = (float*)alloc((size_t)40*256*4);
  float* efb2  = (float*)alloc((size_t)40*128*4);
  _Float16* W1cat = (_Float16*)alloc((size_t)640*256*2);   // [Wl1|Wr1|skipW]^T
  _Float16* W2cat = (_Float16*)alloc((size_t)256*128*2);   // [Wl2|Wr2]^T
  float* bcat1 = (float*)alloc((size_t)640*4);
  float* bcat2 = (float*)alloc((size_t)256*4);
  // zero-init region start
  size_t zoff0 = off;
  int*   cnt   = (int*)alloc((size_t)N*4);
  int*   fillc = (int*)alloc((size_t)N*4);
  unsigned* umax = (unsigned*)alloc((size_t)NG*512*4);
  float* fsum  = (float*)alloc((size_t)NG*512*4);
  size_t zlen = off - zoff0;
  int*   rowptr= (int*)alloc((size_t)(N+1)*4);
  int*   incl  = (int*)alloc((size_t)N*4);
  int*   bsum  = (int*)alloc((size_t)64*4);
  int*   src_s = (int*)alloc((size_t)E*4);
  int*   rel_s = (int*)alloc((size_t)E*4);
  float* w_s   = (float*)alloc((size_t)E*4);
  float* lf    = (float*)alloc((size_t)N*EDIM*4);
  float* xg    = (float*)alloc((size_t)N*640*4);   // layer1 projections; later aliased by xg2
  float* h1    = (float*)alloc((size_t)N*128*4);
  int*   start = (int*)alloc((size_t)(NG+1)*4);
  float* xpool = (float*)alloc((size_t)NG*1024*4);
  float* hmid  = (float*)alloc((size_t)NG*128*4);
  float* xg2 = xg;       // reuse: xg dead after attn1

  float* outp  = (float*)d_out;        // (64,1)
  float* h2out = (float*)d_out + NG;   // (N,128)

  hipMemsetAsync((char*)d_ws + zoff0, 0, zlen, stream);

  k_rel<<<40, 256, 0, stream>>>(emb, irf, We1, We2, base, efb1, efb2);
  k_wcvt<<<256, 256, 0, stream>>>(Wl1,   W1cat,           256, 8);
  k_wcvt<<<256, 256, 0, stream>>>(Wr1,   W1cat + 256*256, 256, 8);
  k_wcvt<<<128, 256, 0, stream>>>(skipW, W1cat + 512*256, 256, 7);
  k_wcvt<<<64, 256, 0, stream>>>(Wl2,    W2cat,           128, 7);
  k_wcvt<<<64, 256, 0, stream>>>(Wr2,    W2cat + 128*128, 128, 7);
  k_bcat<<<3, 256, 0, stream>>>(bl1, br1, skipb, bl2, br2, bcat1, bcat2);

  k_count<<<(E+255)/256, 256, 0, stream>>>(dstp, cnt, E);
  int nb = (N + 1023)/1024;
  k_scan1<<<nb, 1024, 0, stream>>>(cnt, incl, bsum, N);
  k_scan2<<<1, 64, 0, stream>>>(bsum, nb);
  k_scan3<<<(N+255)/256, 256, 0, stream>>>(incl, bsum, rowptr, N);
  k_fill<<<(E+255)/256, 256, 0, stream>>>(srcp, dstp, eattr, ew, rowptr, fillc,
                                          src_s, rel_s, w_s, E);
  k_loopfeat<<<((size_t)N*32+255)/256, 256, 0, stream>>>(rowptr, rel_s, w_s, base, lf, N);

  int gy = (N + 127)/128;
  k_gemm_f16<<<dim3(5, gy), 256, 0, stream>>>(x, W1cat, bcat1, xg, N, 640, 256);

  k_attn1<<<(N+3)/4, 256, 0, stream>>>(xg, lf, We1, att1, bias1, efb1,
                                       rowptr, src_s, rel_s, w_s, h1, N);

  k_gemm_f16<<<dim3(2, gy), 256, 0, stream>>>(h1, W2cat, bcat2, xg2, N, 256, 128);

  k_attn2<<<(N+3)/4, 256, 0, stream>>>(xg2, lf, We2, att2, bias2, efb2,
                                       rowptr, src_s, rel_s, w_s, h2out, N);

  k_start<<<(N+255)/256, 256, 0, stream>>>(batch, start, N);
  k_pool_part<<<(N+PCHUNK-1)/PCHUNK, 256, 0, stream>>>(x, h1, h2out, batch, umax, fsum, N);
  k_pool_final<<<dim3(NG,2), 256, 0, stream>>>(umax, fsum, start, xpool);
  k_mlp1<<<NG, 256, 0, stream>>>(xpool, W1, b1, hmid);
  k_mlp2<<<1, 64, 0, stream>>>(hmid, W2, b2, outp);
  (void)n_in; (void)out_size; (void)ws_size;
}

// Round 8
// 516.127 us; speedup vs baseline: 5.1283x; 1.1089x over previous
//
#include <hip/hip_runtime.h>
#include <math.h>
#include <type_traits>

#define EDIM 32
#define NG 64

typedef __attribute__((ext_vector_type(8))) _Float16 f16x8;
typedef __attribute__((ext_vector_type(4))) _Float16 f16x4;
typedef __attribute__((ext_vector_type(4))) float f32x4;

__device__ inline unsigned enc_f(float f){
  unsigned b = __float_as_uint(f);
  return (b & 0x80000000u) ? ~b : (b | 0x80000000u);
}
__device__ inline float dec_f(unsigned u){
  unsigned b = (u & 0x80000000u) ? (u & 0x7FFFFFFFu) : ~u;
  return __uint_as_float(b);
}
__device__ inline float redux32(float v){
  #pragma unroll
  for (int off=1; off<32; off<<=1) v += __shfl_xor(v, off, 64);
  return v;
}

// ---------- relation table precompute ----------
__global__ void k_rel(const float* __restrict__ emb, const float* __restrict__ irf,
                      const float* __restrict__ We1, const float* __restrict__ We2,
                      float* __restrict__ base, float* __restrict__ efb1, float* __restrict__ efb2){
  int r = blockIdx.x; int t = threadIdx.x;       // 256 threads
  __shared__ float b[EDIM];
  if (t < EDIM){
    float v = emb[r*EDIM + t];
    float ss = v*v;
    #pragma unroll
    for (int off=16; off>0; off>>=1) ss += __shfl_xor(ss, off, 64);
    float nrm = sqrtf(ss);
    float bb = v / fmaxf(nrm, 1e-12f) * irf[r];
    b[t] = bb;
    base[r*EDIM + t] = bb;
  }
  __syncthreads();
  float a1 = 0.f;
  #pragma unroll
  for (int k=0;k<EDIM;k++) a1 += b[k]*We1[k*256 + t];
  efb1[r*256 + t] = a1;
  if (t < 128){
    float a2 = 0.f;
    #pragma unroll
    for (int k=0;k<EDIM;k++) a2 += b[k]*We2[k*128 + t];
    efb2[r*128 + t] = a2;
  }
}

// ---------- weight transpose + fp16 convert: W[K][N] fp32 -> Wt[N][K] fp16 ----------
__global__ void k_wcvt(const float* __restrict__ W, _Float16* __restrict__ Wt,
                       int K, int nshift){
  int i = blockIdx.x*256 + threadIdx.x;
  int Nn = 1<<nshift;
  if (i < K*Nn){
    int k = i >> nshift, n = i & (Nn-1);
    Wt[(size_t)n*K + k] = (_Float16)W[i];
  }
}

// ---------- bias concat ----------
__global__ void k_bcat(const float* __restrict__ bl1, const float* __restrict__ br1,
                       const float* __restrict__ skipb, const float* __restrict__ bl2,
                       const float* __restrict__ br2,
                       float* __restrict__ bcat1, float* __restrict__ bcat2){
  int t = blockIdx.x*256 + threadIdx.x;
  if (t < 256) bcat1[t] = bl1[t];
  else if (t < 512) bcat1[t] = br1[t-256];
  else if (t < 640) bcat1[t] = skipb[t-512];
  if (t < 128) bcat2[t] = bl2[t];
  else if (t < 256) bcat2[t] = br2[t-128];
}

// ---------- CSR build ----------
__global__ void k_count(const int* __restrict__ dst, int* __restrict__ cnt, int E){
  int e = blockIdx.x*256 + threadIdx.x;
  if (e < E) atomicAdd(&cnt[dst[e]], 1);
}

__global__ __launch_bounds__(1024) void k_scan1(const int* __restrict__ cnt, int* __restrict__ incl,
                                                int* __restrict__ bsum, int n){
  __shared__ int s[1024];
  int i = blockIdx.x*1024 + threadIdx.x;
  int v = (i<n)? cnt[i] : 0;
  s[threadIdx.x] = v; __syncthreads();
  for (int off=1; off<1024; off<<=1){
    int add = (threadIdx.x>=(unsigned)off)? s[threadIdx.x-off] : 0;
    __syncthreads();
    s[threadIdx.x] += add;
    __syncthreads();
  }
  if (i<n) incl[i] = s[threadIdx.x];
  if (threadIdx.x==1023) bsum[blockIdx.x] = s[1023];
}
__global__ void k_scan2(int* __restrict__ bsum, int nb){
  if (threadIdx.x==0 && blockIdx.x==0){
    int acc=0;
    for (int b=0;b<nb;b++){ int t=bsum[b]; bsum[b]=acc; acc+=t; }
  }
}
__global__ void k_scan3(const int* __restrict__ incl, const int* __restrict__ bsum,
                        int* __restrict__ rowptr, int n){
  int i = blockIdx.x*256 + threadIdx.x;
  if (i<n) rowptr[i+1] = incl[i] + bsum[i>>10];
  if (i==0) rowptr[0] = 0;
}
__global__ void k_fill(const int* __restrict__ src, const int* __restrict__ dst,
                       const int* __restrict__ rel, const float* __restrict__ ew,
                       const int* __restrict__ rowptr, int* __restrict__ fill,
                       int* __restrict__ src_s, int* __restrict__ rel_s, float* __restrict__ w_s,
                       int E){
  int e = blockIdx.x*256 + threadIdx.x;
  if (e<E){
    int d = dst[e];
    int pos = rowptr[d] + atomicAdd(&fill[d],1);
    src_s[pos] = src[e];
    rel_s[pos] = rel[e];
    w_s[pos]   = ew[e];
  }
}

// ---------- loop_feat ----------
__global__ void k_loopfeat(const int* __restrict__ rowptr, const int* __restrict__ rel_s,
                           const float* __restrict__ w_s,
                           const float* __restrict__ base, float* __restrict__ lf, int N){
  int gid = blockIdx.x*256 + threadIdx.x;
  int n = gid >> 5; int k = gid & 31;
  if (n >= N) return;
  int beg = rowptr[n], end = rowptr[n+1];
  float s = 0.f;
  for (int p=beg;p<end;p++){
    s += w_s[p]*base[rel_s[p]*EDIM + k];
  }
  int c = end - beg;
  lf[n*EDIM + k] = s / (float)max(c,1);
}

// ---------- fp16 MFMA GEMM: C[M,N](fp16) = A[M,K] @ Bt[N,K]^T + bias ----------
// A is fp32 (cvt in staging) or fp16 (direct). tile 128x128, 4 waves 2x2, BK=32.
template<typename AT>
__global__ __launch_bounds__(256) void k_gemm_f16(
    const AT* __restrict__ A, const _Float16* __restrict__ Bt,
    const float* __restrict__ bias, _Float16* __restrict__ C,
    int M, int N, int K)
{
  __shared__ __attribute__((aligned(16))) _Float16 As[128][40];
  __shared__ __attribute__((aligned(16))) _Float16 Bs[128][40];
  int tid = threadIdx.x;
  int wid = tid>>6, lane = tid&63;
  int wm = (wid>>1)*64, wn = (wid&1)*64;
  int bm = blockIdx.y*128, bn = blockIdx.x*128;
  f32x4 acc[4][4] = {};
  int arow = tid>>3, ac4 = (tid&7)*4;
  int brow = tid>>2, bsg = (tid&3)*8;
  int frow = lane&15, fk = (lane>>4)*8;
  for (int k0=0;k0<K;k0+=32){
    #pragma unroll
    for (int it=0;it<4;it++){
      int row = arow + it*32;
      int gr = bm + row;
      f16x4 h4;
      if constexpr (std::is_same<AT,float>::value){
        float4 v = make_float4(0.f,0.f,0.f,0.f);
        if (gr < M) v = *(const float4*)&A[(size_t)gr*K + k0 + ac4];
        h4[0]=(_Float16)v.x; h4[1]=(_Float16)v.y; h4[2]=(_Float16)v.z; h4[3]=(_Float16)v.w;
      } else {
        if (gr < M) h4 = *(const f16x4*)&A[(size_t)gr*K + k0 + ac4];
        else { h4[0]=(_Float16)0.f; h4[1]=(_Float16)0.f; h4[2]=(_Float16)0.f; h4[3]=(_Float16)0.f; }
      }
      *(f16x4*)&As[row][ac4] = h4;
    }
    #pragma unroll
    for (int it=0;it<2;it++){
      int row = brow + it*64;
      f16x8 u = *(const f16x8*)&Bt[(size_t)(bn+row)*K + k0 + bsg];
      *(f16x8*)&Bs[row][bsg] = u;
    }
    __syncthreads();
    f16x8 af[4], bfr[4];
    #pragma unroll
    for (int i=0;i<4;i++) af[i]  = *(f16x8*)&As[wm + i*16 + frow][fk];
    #pragma unroll
    for (int j=0;j<4;j++) bfr[j] = *(f16x8*)&Bs[wn + j*16 + frow][fk];
    #pragma unroll
    for (int i=0;i<4;i++)
      #pragma unroll
      for (int j=0;j<4;j++)
        acc[i][j] = __builtin_amdgcn_mfma_f32_16x16x32_f16(af[i], bfr[j], acc[i][j], 0,0,0);
    __syncthreads();
  }
  int cl = lane&15, rq = (lane>>4)*4;
  #pragma unroll
  for (int i=0;i<4;i++){
    #pragma unroll
    for (int r4=0;r4<4;r4++){
      int gr = bm + wm + i*16 + rq + r4;
      if (gr < M){
        #pragma unroll
        for (int j=0;j<4;j++){
          int gc = bn + wn + j*16 + cl;
          C[(size_t)gr*N + gc] = (_Float16)(acc[i][j][r4] + bias[gc]);
        }
      }
    }
  }
}

// ---------- fused GATv2 layer 1: H=2, head-split halves, fp16 table, online softmax ----------
// xg: fp16 [N][640] = xl(0..255) | xr(256..511) | xskip(512..639)
__global__ __launch_bounds__(256) void k_attn1(
  const _Float16* __restrict__ xg, const float* __restrict__ lf, const float* __restrict__ We1,
  const float* __restrict__ att, const float* __restrict__ bias,
  const float* __restrict__ efb1,
  const int* __restrict__ rowptr,
  const int* __restrict__ src_s, const int* __restrict__ rel_s, const float* __restrict__ w_s,
  _Float16* __restrict__ h1, int N)
{
  int wv = threadIdx.x >> 6, lane = threadIdx.x & 63;
  int n = blockIdx.x*4 + wv;
  if (n >= N) return;
  int half = lane >> 5, l5 = lane & 31;
  int ch = half*128 + l5*4;
  f16x4 xrh  = *(const f16x4*)&xg[(size_t)n*640 + 256 + ch];
  f16x4 xlh  = *(const f16x4*)&xg[(size_t)n*640 + ch];
  f32x4 xr4, xln4;
  #pragma unroll
  for (int z=0;z<4;z++){ xr4[z]=(float)xrh[z]; xln4[z]=(float)xlh[z]; }
  f32x4 av4  = *(const f32x4*)&att[ch];
  f32x4 ef4 = {0.f,0.f,0.f,0.f};
  #pragma unroll
  for (int k=0;k<EDIM;k++){
    float l = lf[n*EDIM + k];
    f32x4 wv4 = *(const f32x4*)&We1[k*256 + ch];
    #pragma unroll
    for (int z=0;z<4;z++) ef4[z] += l*wv4[z];
  }
  // self-loop
  float s = 0.f;
  #pragma unroll
  for (int z=0;z<4;z++){
    float m = xln4[z] + xr4[z] + ef4[z];
    m = fmaxf(m, 0.2f*m);
    s += av4[z]*m;
  }
  s = redux32(s);
  float mx = s, den = 1.f;
  f32x4 acc4 = xln4;

  int beg = rowptr[n], end = rowptr[n+1];
  int p = beg;
  for (; p+4 <= end; p+=4){
    int s4[4]; float w4[4]; int r4[4];
    #pragma unroll
    for (int q=0;q<4;q++){ s4[q]=src_s[p+q]; w4[q]=w_s[p+q]; r4[q]=rel_s[p+q]; }
    f32x4 xv[4]; float sc[4];
    #pragma unroll
    for (int q=0;q<4;q++){
      f16x4 xvh = *(const f16x4*)&xg[(size_t)s4[q]*640 + ch];
      f32x4 e4 = *(const f32x4*)&efb1[r4[q]*256 + ch];
      float t = 0.f;
      #pragma unroll
      for (int z=0;z<4;z++){
        float v = (float)xvh[z];
        xv[q][z] = v;
        float m = v + xr4[z] + w4[q]*e4[z];
        m = fmaxf(m, 0.2f*m);
        t += av4[z]*m;
      }
      sc[q] = t;
    }
    #pragma unroll
    for (int off=1; off<32; off<<=1){
      #pragma unroll
      for (int q=0;q<4;q++) sc[q] += __shfl_xor(sc[q], off, 64);
    }
    float g = fmaxf(fmaxf(sc[0],sc[1]), fmaxf(sc[2],sc[3]));
    float nm = fmaxf(mx, g);
    float f = __expf(mx-nm);
    float e0=__expf(sc[0]-nm), e1=__expf(sc[1]-nm), e2=__expf(sc[2]-nm), e3=__expf(sc[3]-nm);
    den = den*f + ((e0+e1)+(e2+e3));
    #pragma unroll
    for (int z=0;z<4;z++)
      acc4[z] = acc4[z]*f + e0*xv[0][z] + e1*xv[1][z] + e2*xv[2][z] + e3*xv[3][z];
    mx = nm;
  }
  for (; p<end; p++){
    int sE = src_s[p]; float wE = w_s[p]; int rE = rel_s[p];
    f16x4 xvh = *(const f16x4*)&xg[(size_t)sE*640 + ch];
    f32x4 e4 = *(const f32x4*)&efb1[rE*256 + ch];
    f32x4 xv; float t = 0.f;
    #pragma unroll
    for (int z=0;z<4;z++){
      float v = (float)xvh[z];
      xv[z] = v;
      float m = v + xr4[z] + wE*e4[z];
      m = fmaxf(m, 0.2f*m);
      t += av4[z]*m;
    }
    t = redux32(t);
    float nm = fmaxf(mx, t);
    float f = __expf(mx-nm), ev = __expf(t-nm);
    den = den*f + ev;
    #pragma unroll
    for (int z=0;z<4;z++) acc4[z] = acc4[z]*f + ev*xv[z];
    mx = nm;
  }
  float inv = 1.f/(den + 1e-16f);
  float res[4];
  #pragma unroll
  for (int z=0;z<4;z++){
    float v = acc4[z]*inv;
    float o = __shfl_xor(v, 32, 64);
    res[z] = 0.5f*(v + o);
  }
  if (half == 0){
    f16x4 skh = *(const f16x4*)&xg[(size_t)n*640 + 512 + l5*4];
    f32x4 b4 = *(const f32x4*)&bias[l5*4];
    f16x4 o;
    #pragma unroll
    for (int z=0;z<4;z++) o[z] = (_Float16)fmaxf(res[z] + b4[z] + (float)skh[z], 0.f);
    *(f16x4*)&h1[(size_t)n*128 + l5*4] = o;
  }
}

// ---------- fused GATv2 layer 2: H=1, edge-pair halves, fp16 table, online softmax ----------
// xg2: fp16 [N][256] = xl2(0..127) | xr2(128..255)
__global__ __launch_bounds__(256) void k_attn2(
  const _Float16* __restrict__ xg2, const float* __restrict__ lf, const float* __restrict__ We2,
  const float* __restrict__ att, const float* __restrict__ bias,
  const float* __restrict__ efb2,
  const int* __restrict__ rowptr,
  const int* __restrict__ src_s, const int* __restrict__ rel_s, const float* __restrict__ w_s,
  float* __restrict__ h2, int N)
{
  int wv = threadIdx.x >> 6, lane = threadIdx.x & 63;
  int n = blockIdx.x*4 + wv;
  if (n >= N) return;
  int half = lane >> 5, l5 = lane & 31;
  int ch = l5*4;
  f16x4 xrh  = *(const f16x4*)&xg2[(size_t)n*256 + 128 + ch];
  f16x4 xlh  = *(const f16x4*)&xg2[(size_t)n*256 + ch];
  f32x4 xr4, xln4;
  #pragma unroll
  for (int z=0;z<4;z++){ xr4[z]=(float)xrh[z]; xln4[z]=(float)xlh[z]; }
  f32x4 av4  = *(const f32x4*)&att[ch];
  f32x4 ef4 = {0.f,0.f,0.f,0.f};
  #pragma unroll
  for (int k=0;k<EDIM;k++){
    float l = lf[n*EDIM + k];
    f32x4 wv4 = *(const f32x4*)&We2[k*128 + ch];
    #pragma unroll
    for (int z=0;z<4;z++) ef4[z] += l*wv4[z];
  }
  float s = 0.f;
  #pragma unroll
  for (int z=0;z<4;z++){
    float m = xln4[z] + xr4[z] + ef4[z];
    m = fmaxf(m, 0.2f*m);
    s += av4[z]*m;
  }
  s = redux32(s);
  float mx, den;
  f32x4 acc4;
  if (half == 0){ mx = s; den = 1.f; acc4 = xln4; }
  else { mx = -1e30f; den = 0.f; acc4 = (f32x4){0.f,0.f,0.f,0.f}; }

  int beg = rowptr[n], end = rowptr[n+1];
  int cntE = end - beg;
  int nfull = cntE & ~7;
  for (int q8=0; q8<nfull; q8+=8){
    int base = beg + q8;
    int s4[4]; float w4[4]; int r4[4];
    #pragma unroll
    for (int q=0;q<4;q++){
      int e = base + 2*q + half;
      s4[q]=src_s[e]; w4[q]=w_s[e]; r4[q]=rel_s[e];
    }
    f32x4 xv[4]; float sc[4];
    #pragma unroll
    for (int q=0;q<4;q++){
      f16x4 xvh = *(const f16x4*)&xg2[(size_t)s4[q]*256 + ch];
      f32x4 e4 = *(const f32x4*)&efb2[r4[q]*128 + ch];
      float t = 0.f;
      #pragma unroll
      for (int z=0;z<4;z++){
        float v = (float)xvh[z];
        xv[q][z] = v;
        float m = v + xr4[z] + w4[q]*e4[z];
        m = fmaxf(m, 0.2f*m);
        t += av4[z]*m;
      }
      sc[q] = t;
    }
    #pragma unroll
    for (int off=1; off<32; off<<=1){
      #pragma unroll
      for (int q=0;q<4;q++) sc[q] += __shfl_xor(sc[q], off, 64);
    }
    float g = fmaxf(fmaxf(sc[0],sc[1]), fmaxf(sc[2],sc[3]));
    float nm = fmaxf(mx, g);
    float f = __expf(mx-nm);
    float e0=__expf(sc[0]-nm), e1=__expf(sc[1]-nm), e2=__expf(sc[2]-nm), e3=__expf(sc[3]-nm);
    den = den*f + ((e0+e1)+(e2+e3));
    #pragma unroll
    for (int z=0;z<4;z++)
      acc4[z] = acc4[z]*f + e0*xv[0][z] + e1*xv[1][z] + e2*xv[2][z] + e3*xv[3][z];
    mx = nm;
  }
  for (int t0 = beg + nfull; t0 < end; t0 += 2){
    int e = t0 + half;
    if (e < end){
      int sE = src_s[e]; float wE = w_s[e]; int rE = rel_s[e];
      f16x4 xvh = *(const f16x4*)&xg2[(size_t)sE*256 + ch];
      f32x4 e4 = *(const f32x4*)&efb2[rE*128 + ch];
      f32x4 xv; float t = 0.f;
      #pragma unroll
      for (int z=0;z<4;z++){
        float v = (float)xvh[z];
        xv[z] = v;
        float m = v + xr4[z] + wE*e4[z];
        m = fmaxf(m, 0.2f*m);
        t += av4[z]*m;
      }
      t = redux32(t);
      float nm = fmaxf(mx, t);
      float f = __expf(mx-nm), ev = __expf(t-nm);
      den = den*f + ev;
      #pragma unroll
      for (int z=0;z<4;z++) acc4[z] = acc4[z]*f + ev*xv[z];
      mx = nm;
    }
  }
  // merge halves
  float mo = __shfl_xor(mx, 32, 64);
  float deno = __shfl_xor(den, 32, 64);
  f32x4 acco;
  #pragma unroll
  for (int z=0;z<4;z++) acco[z] = __shfl_xor(acc4[z], 32, 64);
  float mt = fmaxf(mx, mo);
  float fs = __expf(mx - mt), fo = __expf(mo - mt);
  den = den*fs + deno*fo;
  #pragma unroll
  for (int z=0;z<4;z++) acc4[z] = acc4[z]*fs + acco[z]*fo;
  float inv = 1.f/(den + 1e-16f);
  if (half == 0){
    f32x4 b4 = *(const f32x4*)&bias[ch];
    f32x4 o;
    #pragma unroll
    for (int z=0;z<4;z++) o[z] = fmaxf(acc4[z]*inv + b4[z], 0.f);
    *(f32x4*)&h2[(size_t)n*128 + ch] = o;
  }
}

// ---------- graph boundaries ----------
__global__ void k_start(const int* __restrict__ batch, int* __restrict__ start, int N){
  int i = blockIdx.x*256 + threadIdx.x;
  if (i >= N) return;
  int b = batch[i];
  int pb = (i==0)? -1 : batch[i-1];
  for (int g=pb+1; g<=b; g++) start[g] = i;
  if (i == N-1){ for (int g=b+1; g<=NG; g++) start[g] = N; }
}

// ---------- pooling stage A ----------
#define PCHUNK 32
__global__ __launch_bounds__(256) void k_pool_part(const float* __restrict__ x, const _Float16* __restrict__ h1,
                       const float* __restrict__ h2, const int* __restrict__ batch,
                       unsigned* __restrict__ umax, float* __restrict__ fsum, int N){
  int c0 = blockIdx.x * PCHUNK;
  int c1 = min(c0 + PCHUNK, N);
  if (c0 >= N) return;
  int t = threadIdx.x;
  float mx0 = -INFINITY, sm0 = 0.f, mx1 = -INFINITY, sm1 = 0.f;
  int bcur = batch[c0];
  for (int i=c0;i<c1;i++){
    int b = batch[i];
    if (b != bcur){
      atomicMax(&umax[bcur*512 + t], enc_f(mx0));
      atomicAdd(&fsum[bcur*512 + t], sm0);
      atomicMax(&umax[bcur*512 + 256 + t], enc_f(mx1));
      atomicAdd(&fsum[bcur*512 + 256 + t], sm1);
      mx0 = mx1 = -INFINITY; sm0 = sm1 = 0.f; bcur = b;
    }
    float v0 = x[(size_t)i*256 + t];
    float v1 = (t<128) ? (float)h1[(size_t)i*128 + t] : h2[(size_t)i*128 + (t-128)];
    mx0 = fmaxf(mx0, v0); sm0 += v0;
    mx1 = fmaxf(mx1, v1); sm1 += v1;
  }
  atomicMax(&umax[bcur*512 + t], enc_f(mx0));
  atomicAdd(&fsum[bcur*512 + t], sm0);
  atomicMax(&umax[bcur*512 + 256 + t], enc_f(mx1));
  atomicAdd(&fsum[bcur*512 + 256 + t], sm1);
}

// ---------- pooling stage B ----------
__global__ void k_pool_final(const unsigned* __restrict__ umax, const float* __restrict__ fsum,
                             const int* __restrict__ start, float* __restrict__ xpool){
  int g = blockIdx.x; int f = blockIdx.y*256 + threadIdx.x;
  float m = dec_f(umax[g*512 + f]);
  if (!isfinite(m)) m = 0.f;
  int cnt = start[g+1] - start[g];
  xpool[g*1024 + f]       = m;
  xpool[g*1024 + 512 + f] = fsum[g*512 + f] / (float)max(cnt,1);
}

__global__ __launch_bounds__(256) void k_mlp1(const float* __restrict__ xpool, const float* __restrict__ W1,
                       const float* __restrict__ b1, float* __restrict__ hmid){
  __shared__ float part[256];
  int g = blockIdx.x; int c = threadIdx.x & 127; int half = threadIdx.x >> 7;
  float a0=0.f,a1=0.f,a2=0.f,a3=0.f;
  int kb = half*512;
  #pragma unroll 4
  for (int k=0;k<512;k+=4){
    a0 += xpool[g*1024+kb+k+0]*W1[(kb+k+0)*128+c];
    a1 += xpool[g*1024+kb+k+1]*W1[(kb+k+1)*128+c];
    a2 += xpool[g*1024+kb+k+2]*W1[(kb+k+2)*128+c];
    a3 += xpool[g*1024+kb+k+3]*W1[(kb+k+3)*128+c];
  }
  part[threadIdx.x] = (a0+a1)+(a2+a3);
  __syncthreads();
  if (half==0){
    float a = part[c] + part[128+c] + b1[c];
    hmid[g*128+c] = fmaxf(a, 0.f);
  }
}
__global__ void k_mlp2(const float* __restrict__ hmid, const float* __restrict__ W2,
                       const float* __restrict__ b2, float* __restrict__ out){
  int g = threadIdx.x; if (g >= NG) return;
  float a = b2[0];
  for (int k=0;k<128;k++) a += hmid[g*128+k]*W2[k];
  out[g] = a;
}

extern "C" void kernel_launch(void* const* d_in, const int* in_sizes, int n_in,
                              void* d_out, int out_size, void* d_ws, size_t ws_size,
                              hipStream_t stream) {
  const float* x     = (const float*)d_in[0];
  const int*   eidx  = (const int*)d_in[1];
  const int*   eattr = (const int*)d_in[2];
  const float* ew    = (const float*)d_in[3];
  const int*   batch = (const int*)d_in[4];
  const float* irf   = (const float*)d_in[5];
  const float* emb   = (const float*)d_in[6];
  const float* Wl1   = (const float*)d_in[7];
  const float* bl1   = (const float*)d_in[8];
  const float* Wr1   = (const float*)d_in[9];
  const float* br1   = (const float*)d_in[10];
  const float* We1   = (const float*)d_in[11];
  const float* att1  = (const float*)d_in[12];
  const float* bias1 = (const float*)d_in[13];
  const float* Wl2   = (const float*)d_in[14];
  const float* bl2   = (const float*)d_in[15];
  const float* Wr2   = (const float*)d_in[16];
  const float* br2   = (const float*)d_in[17];
  const float* We2   = (const float*)d_in[18];
  const float* att2  = (const float*)d_in[19];
  const float* bias2 = (const float*)d_in[20];
  const float* skipW = (const float*)d_in[21];
  const float* skipb = (const float*)d_in[22];
  const float* W1    = (const float*)d_in[23];
  const float* b1    = (const float*)d_in[24];
  const float* W2    = (const float*)d_in[25];
  const float* b2    = (const float*)d_in[26];

  const int N = in_sizes[4];        // 50000
  const int E = in_sizes[3];        // 800000
  const int* srcp = eidx;
  const int* dstp = eidx + E;

  // ---- workspace carve ----
  char* w = (char*)d_ws;
  size_t off = 0;
  auto alloc = [&](size_t bytes)->void*{
    size_t o = off; off = (off + bytes + 255) & ~(size_t)255; return (void*)(w + o);
  };
  float* base  = (float*)alloc((size_t)40*EDIM*4);
  float* efb1  = (float*)alloc((size_t)40*256*4);
  float* efb2  = (float*)alloc((size_t)40*128*4);
  _Float16* W1cat = (_Float16*)alloc((size_t)640*256*2);   // [Wl1|Wr1|skipW]^T
  _Float16* W2cat = (_Float16*)alloc((size_t)256*128*2);   // [Wl2|Wr2]^T
  float* bcat1 = (float*)alloc((size_t)640*4);
  float* bcat2 = (float*)alloc((size_t)256*4);
  // zero-init region start
  size_t zoff0 = off;
  int*   cnt   = (int*)alloc((size_t)N*4);
  int*   fillc = (int*)alloc((size_t)N*4);
  unsigned* umax = (unsigned*)alloc((size_t)NG*512*4);
  float* fsum  = (float*)alloc((size_t)NG*512*4);
  size_t zlen = off - zoff0;
  int*   rowptr= (int*)alloc((size_t)(N+1)*4);
  int*   incl  = (int*)alloc((size_t)N*4);
  int*   bsum  = (int*)alloc((size_t)64*4);
  int*   src_s = (int*)alloc((size_t)E*4);
  int*   rel_s = (int*)alloc((size_t)E*4);
  float* w_s   = (float*)alloc((size_t)E*4);
  float* lf    = (float*)alloc((size_t)N*EDIM*4);
  _Float16* xg = (_Float16*)alloc((size_t)N*640*2);   // layer1 projections; later aliased by xg2
  _Float16* h1 = (_Float16*)alloc((size_t)N*128*2);
  int*   start = (int*)alloc((size_t)(NG+1)*4);
  float* xpool = (float*)alloc((size_t)NG*1024*4);
  float* hmid  = (float*)alloc((size_t)NG*128*4);
  _Float16* xg2 = xg;       // reuse: xg dead after attn1

  float* outp  = (float*)d_out;        // (64,1)
  float* h2out = (float*)d_out + NG;   // (N,128)

  hipMemsetAsync((char*)d_ws + zoff0, 0, zlen, stream);

  k_rel<<<40, 256, 0, stream>>>(emb, irf, We1, We2, base, efb1, efb2);
  k_wcvt<<<256, 256, 0, stream>>>(Wl1,   W1cat,           256, 8);
  k_wcvt<<<256, 256, 0, stream>>>(Wr1,   W1cat + 256*256, 256, 8);
  k_wcvt<<<128, 256, 0, stream>>>(skipW, W1cat + 512*256, 256, 7);
  k_wcvt<<<64, 256, 0, stream>>>(Wl2,    W2cat,           128, 7);
  k_wcvt<<<64, 256, 0, stream>>>(Wr2,    W2cat + 128*128, 128, 7);
  k_bcat<<<3, 256, 0, stream>>>(bl1, br1, skipb, bl2, br2, bcat1, bcat2);

  k_count<<<(E+255)/256, 256, 0, stream>>>(dstp, cnt, E);
  int nb = (N + 1023)/1024;
  k_scan1<<<nb, 1024, 0, stream>>>(cnt, incl, bsum, N);
  k_scan2<<<1, 64, 0, stream>>>(bsum, nb);
  k_scan3<<<(N+255)/256, 256, 0, stream>>>(incl, bsum, rowptr, N);
  k_fill<<<(E+255)/256, 256, 0, stream>>>(srcp, dstp, eattr, ew, rowptr, fillc,
                                          src_s, rel_s, w_s, E);
  k_loopfeat<<<((size_t)N*32+255)/256, 256, 0, stream>>>(rowptr, rel_s, w_s, base, lf, N);

  int gy = (N + 127)/128;
  k_gemm_f16<float><<<dim3(5, gy), 256, 0, stream>>>(x, W1cat, bcat1, xg, N, 640, 256);

  k_attn1<<<(N+3)/4, 256, 0, stream>>>(xg, lf, We1, att1, bias1, efb1,
                                       rowptr, src_s, rel_s, w_s, h1, N);

  k_gemm_f16<_Float16><<<dim3(2, gy), 256, 0, stream>>>(h1, W2cat, bcat2, xg2, N, 256, 128);

  k_attn2<<<(N+3)/4, 256, 0, stream>>>(xg2, lf, We2, att2, bias2, efb2,
                                       rowptr, src_s, rel_s, w_s, h2out, N);

  k_start<<<(N+255)/256, 256, 0, stream>>>(batch, start, N);
  k_pool_part<<<(N+PCHUNK-1)/PCHUNK, 256, 0, stream>>>(x, h1, h2out, batch, umax, fsum, N);
  k_pool_final<<<dim3(NG,2), 256, 0, stream>>>(umax, fsum, start, xpool);
  k_mlp1<<<NG, 256, 0, stream>>>(xpool, W1, b1, hmid);
  k_mlp2<<<1, 64, 0, stream>>>(hmid, W2, b2, outp);
  (void)n_in; (void)out_size; (void)ws_size;
}

// Round 9
// 425.312 us; speedup vs baseline: 6.2233x; 1.2135x over previous
//
#include <hip/hip_runtime.h>
#include <math.h>
#include <type_traits>

#define EDIM 32
#define NG 64

typedef __attribute__((ext_vector_type(8))) _Float16 f16x8;
typedef __attribute__((ext_vector_type(4))) _Float16 f16x4;
typedef __attribute__((ext_vector_type(2))) _Float16 f16x2;
typedef __attribute__((ext_vector_type(4))) float f32x4;

#if __has_builtin(__builtin_amdgcn_fdot2)
#define USE_FDOT2 1
#else
#define USE_FDOT2 0
#endif

__device__ inline unsigned enc_f(float f){
  unsigned b = __float_as_uint(f);
  return (b & 0x80000000u) ? ~b : (b | 0x80000000u);
}
__device__ inline float dec_f(unsigned u){
  unsigned b = (u & 0x80000000u) ? (u & 0x7FFFFFFFu) : ~u;
  return __uint_as_float(b);
}
__device__ inline float redux16(float v){
  #pragma unroll
  for (int off=1; off<16; off<<=1) v += __shfl_xor(v, off, 64);
  return v;
}
// leaky-relu(m) . att  over 8 f16 channels
__device__ inline float dot_leaky(f16x8 m8, f16x8 a8){
#if __has_builtin(__builtin_elementwise_max)
  f16x8 lm = __builtin_elementwise_max(m8, m8*(_Float16)0.2f);
#else
  f16x8 lm;
  #pragma unroll
  for (int z=0;z<8;z++){ _Float16 v=m8[z]; lm[z] = (v>(_Float16)0)? v : v*(_Float16)0.2f; }
#endif
  float s = 0.f;
#if USE_FDOT2
  #pragma unroll
  for (int z=0;z<4;z++){
    f16x2 u; u[0]=lm[2*z]; u[1]=lm[2*z+1];
    f16x2 w2; w2[0]=a8[2*z]; w2[1]=a8[2*z+1];
    s = __builtin_amdgcn_fdot2(u, w2, s, false);
  }
#else
  #pragma unroll
  for (int z=0;z<8;z++) s += (float)lm[z]*(float)a8[z];
#endif
  return s;
}

// ---------- fused setup: rel tables + weight transposes + bias/att concat ----------
__global__ __launch_bounds__(256) void k_setup(
    const float* __restrict__ emb, const float* __restrict__ irf,
    const float* __restrict__ We1, const float* __restrict__ We2,
    const float* __restrict__ Wl1, const float* __restrict__ Wr1, const float* __restrict__ skipW,
    const float* __restrict__ Wl2, const float* __restrict__ Wr2,
    const float* __restrict__ bl1, const float* __restrict__ br1, const float* __restrict__ skipb,
    const float* __restrict__ bl2, const float* __restrict__ br2,
    const float* __restrict__ att1, const float* __restrict__ att2,
    float* __restrict__ base, _Float16* __restrict__ efb1h, _Float16* __restrict__ efb2h,
    _Float16* __restrict__ W1cat, _Float16* __restrict__ W2cat, _Float16* __restrict__ Wecat,
    float* __restrict__ bcat1, float* __restrict__ bcat2,
    _Float16* __restrict__ att1h, _Float16* __restrict__ att2h)
{
  int b = blockIdx.x, t = threadIdx.x;
  if (b < 40){
    __shared__ float bb[EDIM];
    int r = b;
    if (t < 32){
      float v = emb[r*EDIM + t];
      float ss = v*v;
      #pragma unroll
      for (int off=16; off>0; off>>=1) ss += __shfl_xor(ss, off, 64);
      float nrm = sqrtf(ss);
      float w = v / fmaxf(nrm, 1e-12f) * irf[r];
      bb[t] = w;
      base[r*EDIM + t] = w;
    }
    __syncthreads();
    float a1 = 0.f;
    #pragma unroll
    for (int k=0;k<EDIM;k++) a1 += bb[k]*We1[k*256 + t];
    efb1h[r*256 + t] = (_Float16)a1;
    if (t < 128){
      float a2 = 0.f;
      #pragma unroll
      for (int k=0;k<EDIM;k++) a2 += bb[k]*We2[k*128 + t];
      efb2h[r*128 + t] = (_Float16)a2;
    }
  }
  else if (b < 296){ int idx=(b-40)*256+t;  int k=idx>>8, n2=idx&255; W1cat[n2*256+k]          = (_Float16)Wl1[idx]; }
  else if (b < 552){ int idx=(b-296)*256+t; int k=idx>>8, n2=idx&255; W1cat[65536+n2*256+k]    = (_Float16)Wr1[idx]; }
  else if (b < 680){ int idx=(b-552)*256+t; int k=idx>>7, n2=idx&127; W1cat[131072+n2*256+k]   = (_Float16)skipW[idx]; }
  else if (b < 744){ int idx=(b-680)*256+t; int k=idx>>7, n2=idx&127; W2cat[n2*128+k]          = (_Float16)Wl2[idx]; }
  else if (b < 808){ int idx=(b-744)*256+t; int k=idx>>7, n2=idx&127; W2cat[16384+n2*128+k]    = (_Float16)Wr2[idx]; }
  else if (b < 840){ int idx=(b-808)*256+t; int k=idx>>8, n2=idx&255; Wecat[n2*32+k]           = (_Float16)We1[idx]; }
  else if (b < 856){ int idx=(b-840)*256+t; int k=idx>>7, n2=idx&127; Wecat[8192+n2*32+k]      = (_Float16)We2[idx]; }
  else if (b == 856){ bcat1[t] = bl1[t]; }
  else if (b == 857){
    bcat1[256+t] = br1[t];
    if (t < 128) bcat1[512+t] = skipb[t];
    att1h[t] = (_Float16)att1[t];
  } else {
    if (t < 128){
      bcat2[t] = bl2[t];
      bcat2[128+t] = br2[t];
      att2h[t] = (_Float16)att2[t];
    }
  }
}

// ---------- CSR build ----------
__global__ void k_count(const int* __restrict__ dst, int* __restrict__ cnt, int E){
  int e = blockIdx.x*256 + threadIdx.x;
  if (e < E) atomicAdd(&cnt[dst[e]], 1);
}

__global__ __launch_bounds__(1024) void k_scan1(const int* __restrict__ cnt, int* __restrict__ incl,
                                                int* __restrict__ bsum, int n){
  __shared__ int s[1024];
  int i = blockIdx.x*1024 + threadIdx.x;
  int v = (i<n)? cnt[i] : 0;
  s[threadIdx.x] = v; __syncthreads();
  for (int off=1; off<1024; off<<=1){
    int add = (threadIdx.x>=(unsigned)off)? s[threadIdx.x-off] : 0;
    __syncthreads();
    s[threadIdx.x] += add;
    __syncthreads();
  }
  if (i<n) incl[i] = s[threadIdx.x];
  if (threadIdx.x==1023) bsum[blockIdx.x] = s[1023];
}
__global__ void k_scan2(int* __restrict__ bsum, int nb){
  if (threadIdx.x==0 && blockIdx.x==0){
    int acc=0;
    for (int b=0;b<nb;b++){ int t=bsum[b]; bsum[b]=acc; acc+=t; }
  }
}
__global__ void k_scan3(const int* __restrict__ incl, const int* __restrict__ bsum,
                        int* __restrict__ rowptr, int n){
  int i = blockIdx.x*256 + threadIdx.x;
  if (i<n) rowptr[i+1] = incl[i] + bsum[i>>10];
  if (i==0) rowptr[0] = 0;
}
// scatter CSR-sorted, pre-scaled edge metadata
__global__ void k_fill(const int* __restrict__ src, const int* __restrict__ dst,
                       const int* __restrict__ rel, const float* __restrict__ ew,
                       const int* __restrict__ rowptr, int* __restrict__ fill,
                       int* __restrict__ srcA, int* __restrict__ relA,
                       int* __restrict__ srcB, int* __restrict__ relB,
                       int* __restrict__ rel_s, float* __restrict__ w_s,
                       int E){
  int e = blockIdx.x*256 + threadIdx.x;
  if (e<E){
    int d = dst[e];
    int pos = rowptr[d] + atomicAdd(&fill[d],1);
    int s = src[e], r = rel[e];
    srcA[pos] = s*640;
    relA[pos] = r*256;
    srcB[pos] = s*256;
    relB[pos] = r*128;
    rel_s[pos] = r;
    w_s[pos]   = ew[e];
  }
}

// ---------- loop_feat ----------
__global__ void k_loopfeat(const int* __restrict__ rowptr, const int* __restrict__ rel_s,
                           const float* __restrict__ w_s,
                           const float* __restrict__ base, float* __restrict__ lf, int N){
  int gid = blockIdx.x*256 + threadIdx.x;
  int n = gid >> 5; int k = gid & 31;
  if (n >= N) return;
  int beg = rowptr[n], end = rowptr[n+1];
  float s = 0.f;
  for (int p=beg;p<end;p++){
    s += w_s[p]*base[rel_s[p]*EDIM + k];
  }
  int c = end - beg;
  lf[n*EDIM + k] = s / (float)max(c,1);
}

// ---------- fp16 MFMA GEMM: C[M,N](fp16) = A[M,K] @ Bt[N,K]^T + bias ----------
template<typename AT>
__global__ __launch_bounds__(256) void k_gemm_f16(
    const AT* __restrict__ A, const _Float16* __restrict__ Bt,
    const float* __restrict__ bias, _Float16* __restrict__ C,
    int M, int N, int K)
{
  __shared__ __attribute__((aligned(16))) _Float16 As[128][40];
  __shared__ __attribute__((aligned(16))) _Float16 Bs[128][40];
  int tid = threadIdx.x;
  int wid = tid>>6, lane = tid&63;
  int wm = (wid>>1)*64, wn = (wid&1)*64;
  int bm = blockIdx.y*128, bn = blockIdx.x*128;
  f32x4 acc[4][4] = {};
  int arow = tid>>3, ac4 = (tid&7)*4;
  int brow = tid>>2, bsg = (tid&3)*8;
  int frow = lane&15, fk = (lane>>4)*8;
  for (int k0=0;k0<K;k0+=32){
    #pragma unroll
    for (int it=0;it<4;it++){
      int row = arow + it*32;
      int gr = bm + row;
      f16x4 h4;
      if constexpr (std::is_same<AT,float>::value){
        float4 v = make_float4(0.f,0.f,0.f,0.f);
        if (gr < M) v = *(const float4*)&A[(size_t)gr*K + k0 + ac4];
        h4[0]=(_Float16)v.x; h4[1]=(_Float16)v.y; h4[2]=(_Float16)v.z; h4[3]=(_Float16)v.w;
      } else {
        if (gr < M) h4 = *(const f16x4*)&A[(size_t)gr*K + k0 + ac4];
        else { h4[0]=(_Float16)0.f; h4[1]=(_Float16)0.f; h4[2]=(_Float16)0.f; h4[3]=(_Float16)0.f; }
      }
      *(f16x4*)&As[row][ac4] = h4;
    }
    #pragma unroll
    for (int it=0;it<2;it++){
      int row = brow + it*64;
      f16x8 u = *(const f16x8*)&Bt[(size_t)(bn+row)*K + k0 + bsg];
      *(f16x8*)&Bs[row][bsg] = u;
    }
    __syncthreads();
    f16x8 af[4], bfr[4];
    #pragma unroll
    for (int i=0;i<4;i++) af[i]  = *(f16x8*)&As[wm + i*16 + frow][fk];
    #pragma unroll
    for (int j=0;j<4;j++) bfr[j] = *(f16x8*)&Bs[wn + j*16 + frow][fk];
    #pragma unroll
    for (int i=0;i<4;i++)
      #pragma unroll
      for (int j=0;j<4;j++)
        acc[i][j] = __builtin_amdgcn_mfma_f32_16x16x32_f16(af[i], bfr[j], acc[i][j], 0,0,0);
    __syncthreads();
  }
  int cl = lane&15, rq = (lane>>4)*4;
  #pragma unroll
  for (int i=0;i<4;i++){
    #pragma unroll
    for (int r4=0;r4<4;r4++){
      int gr = bm + wm + i*16 + rq + r4;
      if (gr < M){
        #pragma unroll
        for (int j=0;j<4;j++){
          int gc = bn + wn + j*16 + cl;
          C[(size_t)gr*N + gc] = (_Float16)(acc[i][j][r4] + bias[gc]);
        }
      }
    }
  }
}

// ---------- fused GATv2 layer 1: H=2; 4 groups = head x edge-parity; 8ch/lane ----------
// xg: fp16 [N][640] = xl | xr | xskip ; efsc: fp16 [N][384] (cols 0..255 layer1)
__global__ __launch_bounds__(256) void k_attn1(
  const _Float16* __restrict__ xg, const _Float16* __restrict__ efsc,
  const _Float16* __restrict__ efb1h, const _Float16* __restrict__ att1h,
  const float* __restrict__ bias1, const int* __restrict__ rowptr,
  const int* __restrict__ srcA, const int* __restrict__ relA, const float* __restrict__ w_s,
  _Float16* __restrict__ h1, int N)
{
  int wv = threadIdx.x>>6, lane = threadIdx.x&63;
  int n = blockIdx.x*4 + wv;
  if (n >= N) return;
  int sub = (lane>>4)&1, t16 = lane&15;
  int ch = (lane>>5)*128 + t16*8;
  f16x8 xrh = *(const f16x8*)&xg[(size_t)n*640 + 256 + ch];
  f16x8 xlh = *(const f16x8*)&xg[(size_t)n*640 + ch];
  f16x8 efh = *(const f16x8*)&efsc[(size_t)n*384 + ch];
  f16x8 ath = *(const f16x8*)&att1h[ch];
  float acc[8];
  #pragma unroll
  for (int z=0;z<8;z++) acc[z] = (sub==0)? (float)xlh[z] : 0.f;
  f16x8 mself = xlh + xrh + efh;
  float s = redux16(dot_leaky(mself, ath));
  float mx = (sub==0)? s : -1e30f;
  float den = (sub==0)? 1.f : 0.f;

  int beg=rowptr[n], end=rowptr[n+1], p=beg;
  for (; p+4<=end; p+=4){
    int eA=p+sub, eB=p+2+sub;
    int iA=srcA[eA], rA=relA[eA]; float wA=w_s[eA];
    int iB=srcA[eB], rB=relA[eB]; float wB=w_s[eB];
    f16x8 xvA = *(const f16x8*)&xg[(size_t)iA + ch];
    f16x8 eeA = *(const f16x8*)&efb1h[rA + ch];
    f16x8 xvB = *(const f16x8*)&xg[(size_t)iB + ch];
    f16x8 eeB = *(const f16x8*)&efb1h[rB + ch];
    _Float16 hA=(_Float16)wA, hB=(_Float16)wB;
    f16x8 wA8, wB8;
    #pragma unroll
    for (int z=0;z<8;z++){ wA8[z]=hA; wB8[z]=hB; }
    f16x8 mA = xvA + xrh + wA8*eeA;
    f16x8 mB = xvB + xrh + wB8*eeB;
    float sA = dot_leaky(mA, ath);
    float sB = dot_leaky(mB, ath);
    #pragma unroll
    for (int off=1; off<16; off<<=1){
      sA += __shfl_xor(sA, off, 64);
      sB += __shfl_xor(sB, off, 64);
    }
    float nm = fmaxf(mx, fmaxf(sA, sB));
    float f = __expf(mx-nm), gA = __expf(sA-nm), gB = __expf(sB-nm);
    den = den*f + gA + gB;
    #pragma unroll
    for (int z=0;z<8;z++)
      acc[z] = acc[z]*f + gA*(float)xvA[z] + gB*(float)xvB[z];
    mx = nm;
  }
  for (; p+2<=end; p+=2){
    int e = p + sub;
    int i0=srcA[e], r0=relA[e]; float w0=w_s[e];
    f16x8 xv = *(const f16x8*)&xg[(size_t)i0 + ch];
    f16x8 ee = *(const f16x8*)&efb1h[r0 + ch];
    _Float16 h0=(_Float16)w0;
    f16x8 w8;
    #pragma unroll
    for (int z=0;z<8;z++) w8[z]=h0;
    f16x8 m8 = xv + xrh + w8*ee;
    float sc = redux16(dot_leaky(m8, ath));
    float nm = fmaxf(mx, sc);
    float f = __expf(mx-nm), ge = __expf(sc-nm);
    den = den*f + ge;
    #pragma unroll
    for (int z=0;z<8;z++) acc[z] = acc[z]*f + ge*(float)xv[z];
    mx = nm;
  }
  if (p < end && sub == 0){
    int e = p;
    int i0=srcA[e], r0=relA[e]; float w0=w_s[e];
    f16x8 xv = *(const f16x8*)&xg[(size_t)i0 + ch];
    f16x8 ee = *(const f16x8*)&efb1h[r0 + ch];
    _Float16 h0=(_Float16)w0;
    f16x8 w8;
    #pragma unroll
    for (int z=0;z<8;z++) w8[z]=h0;
    f16x8 m8 = xv + xrh + w8*ee;
    float sc = redux16(dot_leaky(m8, ath));
    float nm = fmaxf(mx, sc);
    float f = __expf(mx-nm), ge = __expf(sc-nm);
    den = den*f + ge;
    #pragma unroll
    for (int z=0;z<8;z++) acc[z] = acc[z]*f + ge*(float)xv[z];
    mx = nm;
  }
  // merge the two edge-parity groups within each head
  {
    float mo = __shfl_xor(mx, 16, 64);
    float dn = __shfl_xor(den, 16, 64);
    float ao[8];
    #pragma unroll
    for (int z=0;z<8;z++) ao[z] = __shfl_xor(acc[z], 16, 64);
    float mt = fmaxf(mx, mo);
    float fs = __expf(mx-mt), fo = __expf(mo-mt);
    den = den*fs + dn*fo;
    #pragma unroll
    for (int z=0;z<8;z++) acc[z] = acc[z]*fs + ao[z]*fo;
  }
  float inv = 1.f/(den + 1e-16f);
  float res[8];
  #pragma unroll
  for (int z=0;z<8;z++){
    float v = acc[z]*inv;
    float o = __shfl_xor(v, 32, 64);
    res[z] = 0.5f*(v + o);
  }
  if (lane < 16){
    f16x8 skh = *(const f16x8*)&xg[(size_t)n*640 + 512 + t16*8];
    f32x4 b0 = *(const f32x4*)&bias1[t16*8];
    f32x4 b1 = *(const f32x4*)&bias1[t16*8 + 4];
    f16x8 o;
    #pragma unroll
    for (int z=0;z<4;z++) o[z]   = (_Float16)fmaxf(res[z]   + b0[z] + (float)skh[z],   0.f);
    #pragma unroll
    for (int z=0;z<4;z++) o[4+z] = (_Float16)fmaxf(res[4+z] + b1[z] + (float)skh[4+z], 0.f);
    *(f16x8*)&h1[(size_t)n*128 + t16*8] = o;
  }
}

// ---------- fused GATv2 layer 2: H=1; 4 edge groups; 8ch/lane ----------
// xg2: fp16 [N][256] = xl2 | xr2 ; efsc cols 256..383
__global__ __launch_bounds__(256) void k_attn2(
  const _Float16* __restrict__ xg2, const _Float16* __restrict__ efsc,
  const _Float16* __restrict__ efb2h, const _Float16* __restrict__ att2h,
  const float* __restrict__ bias2, const int* __restrict__ rowptr,
  const int* __restrict__ srcB, const int* __restrict__ relB, const float* __restrict__ w_s,
  float* __restrict__ h2, int N)
{
  int wv = threadIdx.x>>6, lane = threadIdx.x&63;
  int n = blockIdx.x*4 + wv;
  if (n >= N) return;
  int g = lane>>4, t16 = lane&15;
  int ch = t16*8;
  f16x8 xrh = *(const f16x8*)&xg2[(size_t)n*256 + 128 + ch];
  f16x8 xlh = *(const f16x8*)&xg2[(size_t)n*256 + ch];
  f16x8 efh = *(const f16x8*)&efsc[(size_t)n*384 + 256 + ch];
  f16x8 ath = *(const f16x8*)&att2h[ch];
  float acc[8];
  #pragma unroll
  for (int z=0;z<8;z++) acc[z] = (g==0)? (float)xlh[z] : 0.f;
  f16x8 mself = xlh + xrh + efh;
  float s = redux16(dot_leaky(mself, ath));
  float mx = (g==0)? s : -1e30f;
  float den = (g==0)? 1.f : 0.f;

  int beg=rowptr[n], end=rowptr[n+1], p=beg;
  for (; p+8<=end; p+=8){
    int eA=p+g, eB=p+4+g;
    int iA=srcB[eA], rA=relB[eA]; float wA=w_s[eA];
    int iB=srcB[eB], rB=relB[eB]; float wB=w_s[eB];
    f16x8 xvA = *(const f16x8*)&xg2[(size_t)iA + ch];
    f16x8 eeA = *(const f16x8*)&efb2h[rA + ch];
    f16x8 xvB = *(const f16x8*)&xg2[(size_t)iB + ch];
    f16x8 eeB = *(const f16x8*)&efb2h[rB + ch];
    _Float16 hA=(_Float16)wA, hB=(_Float16)wB;
    f16x8 wA8, wB8;
    #pragma unroll
    for (int z=0;z<8;z++){ wA8[z]=hA; wB8[z]=hB; }
    f16x8 mA = xvA + xrh + wA8*eeA;
    f16x8 mB = xvB + xrh + wB8*eeB;
    float sA = dot_leaky(mA, ath);
    float sB = dot_leaky(mB, ath);
    #pragma unroll
    for (int off=1; off<16; off<<=1){
      sA += __shfl_xor(sA, off, 64);
      sB += __shfl_xor(sB, off, 64);
    }
    float nm = fmaxf(mx, fmaxf(sA, sB));
    float f = __expf(mx-nm), gA = __expf(sA-nm), gB = __expf(sB-nm);
    den = den*f + gA + gB;
    #pragma unroll
    for (int z=0;z<8;z++)
      acc[z] = acc[z]*f + gA*(float)xvA[z] + gB*(float)xvB[z];
    mx = nm;
  }
  for (; p+4<=end; p+=4){
    int e = p + g;
    int i0=srcB[e], r0=relB[e]; float w0=w_s[e];
    f16x8 xv = *(const f16x8*)&xg2[(size_t)i0 + ch];
    f16x8 ee = *(const f16x8*)&efb2h[r0 + ch];
    _Float16 h0=(_Float16)w0;
    f16x8 w8;
    #pragma unroll
    for (int z=0;z<8;z++) w8[z]=h0;
    f16x8 m8 = xv + xrh + w8*ee;
    float sc = redux16(dot_leaky(m8, ath));
    float nm = fmaxf(mx, sc);
    float f = __expf(mx-nm), ge = __expf(sc-nm);
    den = den*f + ge;
    #pragma unroll
    for (int z=0;z<8;z++) acc[z] = acc[z]*f + ge*(float)xv[z];
    mx = nm;
  }
  int rem = end - p;
  if (g < rem){
    int e = p + g;
    int i0=srcB[e], r0=relB[e]; float w0=w_s[e];
    f16x8 xv = *(const f16x8*)&xg2[(size_t)i0 + ch];
    f16x8 ee = *(const f16x8*)&efb2h[r0 + ch];
    _Float16 h0=(_Float16)w0;
    f16x8 w8;
    #pragma unroll
    for (int z=0;z<8;z++) w8[z]=h0;
    f16x8 m8 = xv + xrh + w8*ee;
    float sc = redux16(dot_leaky(m8, ath));
    float nm = fmaxf(mx, sc);
    float f = __expf(mx-nm), ge = __expf(sc-nm);
    den = den*f + ge;
    #pragma unroll
    for (int z=0;z<8;z++) acc[z] = acc[z]*f + ge*(float)xv[z];
    mx = nm;
  }
  // butterfly-merge the 4 group states
  #pragma unroll
  for (int off=16; off<=32; off<<=1){
    float mo = __shfl_xor(mx, off, 64);
    float dn = __shfl_xor(den, off, 64);
    float ao[8];
    #pragma unroll
    for (int z=0;z<8;z++) ao[z] = __shfl_xor(acc[z], off, 64);
    float mt = fmaxf(mx, mo);
    float fs = __expf(mx-mt), fo = __expf(mo-mt);
    den = den*fs + dn*fo;
    #pragma unroll
    for (int z=0;z<8;z++) acc[z] = acc[z]*fs + ao[z]*fo;
    mx = mt;
  }
  float inv = 1.f/(den + 1e-16f);
  if (g == 0){
    f32x4 b0 = *(const f32x4*)&bias2[ch];
    f32x4 b1 = *(const f32x4*)&bias2[ch+4];
    f32x4 o0, o1;
    #pragma unroll
    for (int z=0;z<4;z++){ o0[z] = fmaxf(acc[z]*inv   + b0[z], 0.f);
                           o1[z] = fmaxf(acc[4+z]*inv + b1[z], 0.f); }
    *(f32x4*)&h2[(size_t)n*128 + ch]     = o0;
    *(f32x4*)&h2[(size_t)n*128 + ch + 4] = o1;
  }
}

// ---------- graph boundaries ----------
__global__ void k_start(const int* __restrict__ batch, int* __restrict__ start, int N){
  int i = blockIdx.x*256 + threadIdx.x;
  if (i >= N) return;
  int b = batch[i];
  int pb = (i==0)? -1 : batch[i-1];
  for (int g=pb+1; g<=b; g++) start[g] = i;
  if (i == N-1){ for (int g=b+1; g<=NG; g++) start[g] = N; }
}

// ---------- pooling stage A ----------
#define PCHUNK 32
__global__ __launch_bounds__(256) void k_pool_part(const float* __restrict__ x, const _Float16* __restrict__ h1,
                       const float* __restrict__ h2, const int* __restrict__ batch,
                       unsigned* __restrict__ umax, float* __restrict__ fsum, int N){
  int c0 = blockIdx.x * PCHUNK;
  int c1 = min(c0 + PCHUNK, N);
  if (c0 >= N) return;
  int t = threadIdx.x;
  float mx0 = -INFINITY, sm0 = 0.f, mx1 = -INFINITY, sm1 = 0.f;
  int bcur = batch[c0];
  for (int i=c0;i<c1;i++){
    int b = batch[i];
    if (b != bcur){
      atomicMax(&umax[bcur*512 + t], enc_f(mx0));
      atomicAdd(&fsum[bcur*512 + t], sm0);
      atomicMax(&umax[bcur*512 + 256 + t], enc_f(mx1));
      atomicAdd(&fsum[bcur*512 + 256 + t], sm1);
      mx0 = mx1 = -INFINITY; sm0 = sm1 = 0.f; bcur = b;
    }
    float v0 = x[(size_t)i*256 + t];
    float v1 = (t<128) ? (float)h1[(size_t)i*128 + t] : h2[(size_t)i*128 + (t-128)];
    mx0 = fmaxf(mx0, v0); sm0 += v0;
    mx1 = fmaxf(mx1, v1); sm1 += v1;
  }
  atomicMax(&umax[bcur*512 + t], enc_f(mx0));
  atomicAdd(&fsum[bcur*512 + t], sm0);
  atomicMax(&umax[bcur*512 + 256 + t], enc_f(mx1));
  atomicAdd(&fsum[bcur*512 + 256 + t], sm1);
}

// ---------- pooling stage B ----------
__global__ void k_pool_final(const unsigned* __restrict__ umax, const float* __restrict__ fsum,
                             const int* __restrict__ start, float* __restrict__ xpool){
  int g = blockIdx.x; int f = blockIdx.y*256 + threadIdx.x;
  float m = dec_f(umax[g*512 + f]);
  if (!isfinite(m)) m = 0.f;
  int cnt = start[g+1] - start[g];
  xpool[g*1024 + f]       = m;
  xpool[g*1024 + 512 + f] = fsum[g*512 + f] / (float)max(cnt,1);
}

__global__ __launch_bounds__(256) void k_mlp1(const float* __restrict__ xpool, const float* __restrict__ W1,
                       const float* __restrict__ b1, float* __restrict__ hmid){
  __shared__ float part[256];
  int g = blockIdx.x; int c = threadIdx.x & 127; int half = threadIdx.x >> 7;
  float a0=0.f,a1=0.f,a2=0.f,a3=0.f;
  int kb = half*512;
  #pragma unroll 4
  for (int k=0;k<512;k+=4){
    a0 += xpool[g*1024+kb+k+0]*W1[(kb+k+0)*128+c];
    a1 += xpool[g*1024+kb+k+1]*W1[(kb+k+1)*128+c];
    a2 += xpool[g*1024+kb+k+2]*W1[(kb+k+2)*128+c];
    a3 += xpool[g*1024+kb+k+3]*W1[(kb+k+3)*128+c];
  }
  part[threadIdx.x] = (a0+a1)+(a2+a3);
  __syncthreads();
  if (half==0){
    float a = part[c] + part[128+c] + b1[c];
    hmid[g*128+c] = fmaxf(a, 0.f);
  }
}
__global__ void k_mlp2(const float* __restrict__ hmid, const float* __restrict__ W2,
                       const float* __restrict__ b2, float* __restrict__ out){
  int g = threadIdx.x; if (g >= NG) return;
  float a = b2[0];
  for (int k=0;k<128;k++) a += hmid[g*128+k]*W2[k];
  out[g] = a;
}

extern "C" void kernel_launch(void* const* d_in, const int* in_sizes, int n_in,
                              void* d_out, int out_size, void* d_ws, size_t ws_size,
                              hipStream_t stream) {
  const float* x     = (const float*)d_in[0];
  const int*   eidx  = (const int*)d_in[1];
  const int*   eattr = (const int*)d_in[2];
  const float* ew    = (const float*)d_in[3];
  const int*   batch = (const int*)d_in[4];
  const float* irf   = (const float*)d_in[5];
  const float* emb   = (const float*)d_in[6];
  const float* Wl1   = (const float*)d_in[7];
  const float* bl1   = (const float*)d_in[8];
  const float* Wr1   = (const float*)d_in[9];
  const float* br1   = (const float*)d_in[10];
  const float* We1   = (const float*)d_in[11];
  const float* att1  = (const float*)d_in[12];
  const float* bias1 = (const float*)d_in[13];
  const float* Wl2   = (const float*)d_in[14];
  const float* bl2   = (const float*)d_in[15];
  const float* Wr2   = (const float*)d_in[16];
  const float* br2   = (const float*)d_in[17];
  const float* We2   = (const float*)d_in[18];
  const float* att2  = (const float*)d_in[19];
  const float* bias2 = (const float*)d_in[20];
  const float* skipW = (const float*)d_in[21];
  const float* skipb = (const float*)d_in[22];
  const float* W1    = (const float*)d_in[23];
  const float* b1    = (const float*)d_in[24];
  const float* W2    = (const float*)d_in[25];
  const float* b2    = (const float*)d_in[26];

  const int N = in_sizes[4];        // 50000
  const int E = in_sizes[3];        // 800000
  const int* srcp = eidx;
  const int* dstp = eidx + E;

  // ---- workspace carve ----
  char* w = (char*)d_ws;
  size_t off = 0;
  auto alloc = [&](size_t bytes)->void*{
    size_t o = off; off = (off + bytes + 255) & ~(size_t)255; return (void*)(w + o);
  };
  float* base  = (float*)alloc((size_t)40*EDIM*4);
  _Float16* efb1h = (_Float16*)alloc((size_t)40*256*2);
  _Float16* efb2h = (_Float16*)alloc((size_t)40*128*2);
  _Float16* W1cat = (_Float16*)alloc((size_t)640*256*2);
  _Float16* W2cat = (_Float16*)alloc((size_t)256*128*2);
  _Float16* Wecat = (_Float16*)alloc((size_t)384*32*2);
  float* bcat1 = (float*)alloc((size_t)640*4);
  float* bcat2 = (float*)alloc((size_t)256*4);
  _Float16* att1h = (_Float16*)alloc((size_t)256*2);
  _Float16* att2h = (_Float16*)alloc((size_t)128*2);
  // zero-init region
  size_t zoff0 = off;
  int*   cnt   = (int*)alloc((size_t)N*4);
  int*   fillc = (int*)alloc((size_t)N*4);
  unsigned* umax = (unsigned*)alloc((size_t)NG*512*4);
  float* fsum  = (float*)alloc((size_t)NG*512*4);
  float* bcatE = (float*)alloc((size_t)384*4);
  size_t zlen = off - zoff0;
  int*   rowptr= (int*)alloc((size_t)(N+1)*4);
  int*   incl  = (int*)alloc((size_t)N*4);
  int*   bsum  = (int*)alloc((size_t)64*4);
  int*   srcA  = (int*)alloc((size_t)E*4);
  int*   relA  = (int*)alloc((size_t)E*4);
  int*   srcB  = (int*)alloc((size_t)E*4);
  int*   relB  = (int*)alloc((size_t)E*4);
  int*   rel_s = (int*)alloc((size_t)E*4);
  float* w_s   = (float*)alloc((size_t)E*4);
  float* lf    = (float*)alloc((size_t)N*EDIM*4);
  _Float16* xg = (_Float16*)alloc((size_t)N*640*2);
  _Float16* efsc = (_Float16*)alloc((size_t)N*384*2);
  _Float16* h1 = (_Float16*)alloc((size_t)N*128*2);
  int*   start = (int*)alloc((size_t)(NG+1)*4);
  float* xpool = (float*)alloc((size_t)NG*1024*4);
  float* hmid  = (float*)alloc((size_t)NG*128*4);
  _Float16* xg2 = xg;       // reuse: xg dead after attn1

  float* outp  = (float*)d_out;        // (64,1)
  float* h2out = (float*)d_out + NG;   // (N,128)

  hipMemsetAsync((char*)d_ws + zoff0, 0, zlen, stream);

  k_setup<<<859, 256, 0, stream>>>(emb, irf, We1, We2, Wl1, Wr1, skipW, Wl2, Wr2,
                                   bl1, br1, skipb, bl2, br2, att1, att2,
                                   base, efb1h, efb2h, W1cat, W2cat, Wecat,
                                   bcat1, bcat2, att1h, att2h);

  k_count<<<(E+255)/256, 256, 0, stream>>>(dstp, cnt, E);
  int nb = (N + 1023)/1024;
  k_scan1<<<nb, 1024, 0, stream>>>(cnt, incl, bsum, N);
  k_scan2<<<1, 64, 0, stream>>>(bsum, nb);
  k_scan3<<<(N+255)/256, 256, 0, stream>>>(incl, bsum, rowptr, N);
  k_fill<<<(E+255)/256, 256, 0, stream>>>(srcp, dstp, eattr, ew, rowptr, fillc,
                                          srcA, relA, srcB, relB, rel_s, w_s, E);
  k_loopfeat<<<((size_t)N*32+255)/256, 256, 0, stream>>>(rowptr, rel_s, w_s, base, lf, N);

  int gy = (N + 127)/128;
  k_gemm_f16<float><<<dim3(5, gy), 256, 0, stream>>>(x, W1cat, bcat1, xg, N, 640, 256);
  k_gemm_f16<float><<<dim3(3, gy), 256, 0, stream>>>(lf, Wecat, bcatE, efsc, N, 384, 32);

  k_attn1<<<(N+3)/4, 256, 0, stream>>>(xg, efsc, efb1h, att1h, bias1,
                                       rowptr, srcA, relA, w_s, h1, N);

  k_gemm_f16<_Float16><<<dim3(2, gy), 256, 0, stream>>>(h1, W2cat, bcat2, xg2, N, 256, 128);

  k_attn2<<<(N+3)/4, 256, 0, stream>>>(xg2, efsc, efb2h, att2h, bias2,
                                       rowptr, srcB, relB, w_s, h2out, N);

  k_start<<<(N+255)/256, 256, 0, stream>>>(batch, start, N);
  k_pool_part<<<(N+PCHUNK-1)/PCHUNK, 256, 0, stream>>>(x, h1, h2out, batch, umax, fsum, N);
  k_pool_final<<<dim3(NG,2), 256, 0, stream>>>(umax, fsum, start, xpool);
  k_mlp1<<<NG, 256, 0, stream>>>(xpool, W1, b1, hmid);
  k_mlp2<<<1, 64, 0, stream>>>(hmid, W2, b2, outp);
  (void)n_in; (void)out_size; (void)ws_size;
}

// Round 10
// 424.729 us; speedup vs baseline: 6.2319x; 1.0014x over previous
//
#include <hip/hip_runtime.h>
#include <math.h>

#define EDIM 32
#define NG 64

typedef __attribute__((ext_vector_type(8))) _Float16 f16x8;
typedef __attribute__((ext_vector_type(4))) _Float16 f16x4;
typedef __attribute__((ext_vector_type(2))) _Float16 f16x2;
typedef __attribute__((ext_vector_type(4))) float f32x4;

#if __has_builtin(__builtin_amdgcn_fdot2)
#define USE_FDOT2 1
#else
#define USE_FDOT2 0
#endif

__device__ inline unsigned enc_f(float f){
  unsigned b = __float_as_uint(f);
  return (b & 0x80000000u) ? ~b : (b | 0x80000000u);
}
__device__ inline float dec_f(unsigned u){
  unsigned b = (u & 0x80000000u) ? (u & 0x7FFFFFFFu) : ~u;
  return __uint_as_float(b);
}
__device__ inline float redux16(float v){
  #pragma unroll
  for (int off=1; off<16; off<<=1) v += __shfl_xor(v, off, 64);
  return v;
}
// leaky-relu(m) . att  over 8 f16 channels
__device__ inline float dot_leaky(f16x8 m8, f16x8 a8){
#if __has_builtin(__builtin_elementwise_max)
  f16x8 lm = __builtin_elementwise_max(m8, m8*(_Float16)0.2f);
#else
  f16x8 lm;
  #pragma unroll
  for (int z=0;z<8;z++){ _Float16 v=m8[z]; lm[z] = (v>(_Float16)0)? v : v*(_Float16)0.2f; }
#endif
  float s = 0.f;
#if USE_FDOT2
  #pragma unroll
  for (int z=0;z<4;z++){
    f16x2 u; u[0]=lm[2*z]; u[1]=lm[2*z+1];
    f16x2 w2; w2[0]=a8[2*z]; w2[1]=a8[2*z+1];
    s = __builtin_amdgcn_fdot2(u, w2, s, false);
  }
#else
  #pragma unroll
  for (int z=0;z<8;z++) s += (float)lm[z]*(float)a8[z];
#endif
  return s;
}

// ---------- fused setup: rel tables + weight transposes + bias/att concat ----------
__global__ __launch_bounds__(256) void k_setup(
    const float* __restrict__ emb, const float* __restrict__ irf,
    const float* __restrict__ We1, const float* __restrict__ We2,
    const float* __restrict__ Wl1, const float* __restrict__ Wr1, const float* __restrict__ skipW,
    const float* __restrict__ Wl2, const float* __restrict__ Wr2,
    const float* __restrict__ bl1, const float* __restrict__ br1, const float* __restrict__ skipb,
    const float* __restrict__ bl2, const float* __restrict__ br2,
    const float* __restrict__ att1, const float* __restrict__ att2,
    float* __restrict__ base, _Float16* __restrict__ efb1h, _Float16* __restrict__ efb2h,
    _Float16* __restrict__ W1cat, _Float16* __restrict__ W2cat, _Float16* __restrict__ Wecat,
    float* __restrict__ bcat1, float* __restrict__ bcat2,
    _Float16* __restrict__ att1h, _Float16* __restrict__ att2h)
{
  int b = blockIdx.x, t = threadIdx.x;
  if (b < 40){
    __shared__ float bb[EDIM];
    int r = b;
    if (t < 32){
      float v = emb[r*EDIM + t];
      float ss = v*v;
      #pragma unroll
      for (int off=16; off>0; off>>=1) ss += __shfl_xor(ss, off, 64);
      float nrm = sqrtf(ss);
      float w = v / fmaxf(nrm, 1e-12f) * irf[r];
      bb[t] = w;
      base[r*EDIM + t] = w;
    }
    __syncthreads();
    float a1 = 0.f;
    #pragma unroll
    for (int k=0;k<EDIM;k++) a1 += bb[k]*We1[k*256 + t];
    efb1h[r*256 + t] = (_Float16)a1;
    if (t < 128){
      float a2 = 0.f;
      #pragma unroll
      for (int k=0;k<EDIM;k++) a2 += bb[k]*We2[k*128 + t];
      efb2h[r*128 + t] = (_Float16)a2;
    }
  }
  else if (b < 296){ int idx=(b-40)*256+t;  int k=idx>>8, n2=idx&255; W1cat[n2*256+k]          = (_Float16)Wl1[idx]; }
  else if (b < 552){ int idx=(b-296)*256+t; int k=idx>>8, n2=idx&255; W1cat[65536+n2*256+k]    = (_Float16)Wr1[idx]; }
  else if (b < 680){ int idx=(b-552)*256+t; int k=idx>>7, n2=idx&127; W1cat[131072+n2*256+k]   = (_Float16)skipW[idx]; }
  else if (b < 744){ int idx=(b-680)*256+t; int k=idx>>7, n2=idx&127; W2cat[n2*128+k]          = (_Float16)Wl2[idx]; }
  else if (b < 808){ int idx=(b-744)*256+t; int k=idx>>7, n2=idx&127; W2cat[16384+n2*128+k]    = (_Float16)Wr2[idx]; }
  else if (b < 840){ int idx=(b-808)*256+t; int k=idx>>8, n2=idx&255; Wecat[n2*32+k]           = (_Float16)We1[idx]; }
  else if (b < 856){ int idx=(b-840)*256+t; int k=idx>>7, n2=idx&127; Wecat[8192+n2*32+k]      = (_Float16)We2[idx]; }
  else if (b == 856){ bcat1[t] = bl1[t]; }
  else if (b == 857){
    bcat1[256+t] = br1[t];
    if (t < 128) bcat1[512+t] = skipb[t];
    att1h[t] = (_Float16)att1[t];
  } else {
    if (t < 128){
      bcat2[t] = bl2[t];
      bcat2[128+t] = br2[t];
      att2h[t] = (_Float16)att2[t];
    }
  }
}

// ---------- x -> fp16 ----------
__global__ void k_xcvt(const float* __restrict__ x, _Float16* __restrict__ xh, int total8){
  int i = blockIdx.x*256 + threadIdx.x;
  if (i < total8){
    float4 v0 = *(const float4*)&x[(size_t)i*8];
    float4 v1 = *(const float4*)&x[(size_t)i*8 + 4];
    f16x8 o;
    o[0]=(_Float16)v0.x; o[1]=(_Float16)v0.y; o[2]=(_Float16)v0.z; o[3]=(_Float16)v0.w;
    o[4]=(_Float16)v1.x; o[5]=(_Float16)v1.y; o[6]=(_Float16)v1.z; o[7]=(_Float16)v1.w;
    *(f16x8*)&xh[(size_t)i*8] = o;
  }
}

// ---------- CSR build ----------
__global__ void k_count(const int* __restrict__ dst, int* __restrict__ cnt, int E){
  int e = blockIdx.x*256 + threadIdx.x;
  if (e < E) atomicAdd(&cnt[dst[e]], 1);
}

__global__ __launch_bounds__(1024) void k_scan1(const int* __restrict__ cnt, int* __restrict__ incl,
                                                int* __restrict__ bsum, int n){
  __shared__ int s[1024];
  int i = blockIdx.x*1024 + threadIdx.x;
  int v = (i<n)? cnt[i] : 0;
  s[threadIdx.x] = v; __syncthreads();
  for (int off=1; off<1024; off<<=1){
    int add = (threadIdx.x>=(unsigned)off)? s[threadIdx.x-off] : 0;
    __syncthreads();
    s[threadIdx.x] += add;
    __syncthreads();
  }
  if (i<n) incl[i] = s[threadIdx.x];
  if (threadIdx.x==1023) bsum[blockIdx.x] = s[1023];
}
__global__ void k_scan2(int* __restrict__ bsum, int nb){
  if (threadIdx.x==0 && blockIdx.x==0){
    int acc=0;
    for (int b=0;b<nb;b++){ int t=bsum[b]; bsum[b]=acc; acc+=t; }
  }
}
__global__ void k_scan3(const int* __restrict__ incl, const int* __restrict__ bsum,
                        int* __restrict__ rowptr, int n){
  int i = blockIdx.x*256 + threadIdx.x;
  if (i<n) rowptr[i+1] = incl[i] + bsum[i>>10];
  if (i==0) rowptr[0] = 0;
}
// scatter CSR-sorted, pre-scaled edge metadata
__global__ void k_fill(const int* __restrict__ src, const int* __restrict__ dst,
                       const int* __restrict__ rel, const float* __restrict__ ew,
                       const int* __restrict__ rowptr, int* __restrict__ fill,
                       int* __restrict__ srcA, int* __restrict__ relA,
                       int* __restrict__ srcB, int* __restrict__ relB,
                       int* __restrict__ rel_s, float* __restrict__ w_s,
                       int E){
  int e = blockIdx.x*256 + threadIdx.x;
  if (e<E){
    int d = dst[e];
    int pos = rowptr[d] + atomicAdd(&fill[d],1);
    int s = src[e], r = rel[e];
    srcA[pos] = s*640;
    relA[pos] = r*256;
    srcB[pos] = s*256;
    relB[pos] = r*128;
    rel_s[pos] = r;
    w_s[pos]   = ew[e];
  }
}

// ---------- loop_feat ----------
__global__ void k_loopfeat(const int* __restrict__ rowptr, const int* __restrict__ rel_s,
                           const float* __restrict__ w_s,
                           const float* __restrict__ base, float* __restrict__ lf, int N){
  int gid = blockIdx.x*256 + threadIdx.x;
  int n = gid >> 5; int k = gid & 31;
  if (n >= N) return;
  int beg = rowptr[n], end = rowptr[n+1];
  float s = 0.f;
  for (int p=beg;p<end;p++){
    s += w_s[p]*base[rel_s[p]*EDIM + k];
  }
  int c = end - beg;
  lf[n*EDIM + k] = s / (float)max(c,1);
}

// ---------- fp16 MFMA GEMM (double-buffered, T14 split): C = A@Bt^T + bias ----------
// A fp16 [M][K]; tile 128x128, 4 waves 2x2, BK=32
__global__ __launch_bounds__(256) void k_gemm_f16(
    const _Float16* __restrict__ A, const _Float16* __restrict__ Bt,
    const float* __restrict__ bias, _Float16* __restrict__ C,
    int M, int N, int K)
{
  __shared__ __attribute__((aligned(16))) _Float16 As[2][128][40];
  __shared__ __attribute__((aligned(16))) _Float16 Bs[2][128][40];
  int tid = threadIdx.x;
  int wid = tid>>6, lane = tid&63;
  int wm = (wid>>1)*64, wn = (wid&1)*64;
  int bm = blockIdx.y*128, bn = blockIdx.x*128;
  int frow = lane&15, fk = (lane>>4)*8;
  // chunk mapping: 512 16B-chunks per (A or B) tile; this thread owns chunks tid and tid+256
  int r0c = tid>>2,        s0c = (tid&3)*8;
  int r1c = (tid+256)>>2,  s1c = (tid&3)*8;
  auto loadA = [&](int r, int s, int k0)->f16x8{
    int gr = bm + r;
    f16x8 v;
    if (gr < M) v = *(const f16x8*)&A[(size_t)gr*K + k0 + s];
    else { for (int z=0;z<8;z++) v[z]=(_Float16)0.f; }
    return v;
  };
  auto loadB = [&](int r, int s, int k0)->f16x8{
    return *(const f16x8*)&Bt[(size_t)(bn+r)*K + k0 + s];
  };
  f32x4 acc[4][4] = {};
  int nt = K >> 5;
  // prologue: stage tile 0 into buffer 0
  {
    f16x8 a0 = loadA(r0c,s0c,0), a1 = loadA(r1c,s1c,0);
    f16x8 b0 = loadB(r0c,s0c,0), b1 = loadB(r1c,s1c,0);
    *(f16x8*)&As[0][r0c][s0c] = a0;  *(f16x8*)&As[0][r1c][s1c] = a1;
    *(f16x8*)&Bs[0][r0c][s0c] = b0;  *(f16x8*)&Bs[0][r1c][s1c] = b1;
  }
  for (int t=0; t<nt; t++){
    int cur = t&1, nxt = cur^1;
    __syncthreads();
    f16x8 a0,a1,b0,b1;
    bool pf = (t+1 < nt);
    if (pf){
      int k0 = (t+1)<<5;
      a0 = loadA(r0c,s0c,k0); a1 = loadA(r1c,s1c,k0);
      b0 = loadB(r0c,s0c,k0); b1 = loadB(r1c,s1c,k0);
    }
    f16x8 af[4], bfr[4];
    #pragma unroll
    for (int i=0;i<4;i++) af[i]  = *(f16x8*)&As[cur][wm + i*16 + frow][fk];
    #pragma unroll
    for (int j=0;j<4;j++) bfr[j] = *(f16x8*)&Bs[cur][wn + j*16 + frow][fk];
    #pragma unroll
    for (int i=0;i<4;i++)
      #pragma unroll
      for (int j=0;j<4;j++)
        acc[i][j] = __builtin_amdgcn_mfma_f32_16x16x32_f16(af[i], bfr[j], acc[i][j], 0,0,0);
    if (pf){
      *(f16x8*)&As[nxt][r0c][s0c] = a0;  *(f16x8*)&As[nxt][r1c][s1c] = a1;
      *(f16x8*)&Bs[nxt][r0c][s0c] = b0;  *(f16x8*)&Bs[nxt][r1c][s1c] = b1;
    }
  }
  int cl = lane&15, rq = (lane>>4)*4;
  #pragma unroll
  for (int i=0;i<4;i++){
    #pragma unroll
    for (int r4=0;r4<4;r4++){
      int gr = bm + wm + i*16 + rq + r4;
      if (gr < M){
        #pragma unroll
        for (int j=0;j<4;j++){
          int gc = bn + wn + j*16 + cl;
          C[(size_t)gr*N + gc] = (_Float16)(acc[i][j][r4] + bias[gc]);
        }
      }
    }
  }
}

// ---------- fp32-A single-buffer GEMM (for the tiny K=32 efsc projection) ----------
__global__ __launch_bounds__(256) void k_gemm_f32a(
    const float* __restrict__ A, const _Float16* __restrict__ Bt,
    const float* __restrict__ bias, _Float16* __restrict__ C,
    int M, int N, int K)
{
  __shared__ __attribute__((aligned(16))) _Float16 As[128][40];
  __shared__ __attribute__((aligned(16))) _Float16 Bs[128][40];
  int tid = threadIdx.x;
  int wid = tid>>6, lane = tid&63;
  int wm = (wid>>1)*64, wn = (wid&1)*64;
  int bm = blockIdx.y*128, bn = blockIdx.x*128;
  f32x4 acc[4][4] = {};
  int arow = tid>>3, ac4 = (tid&7)*4;
  int brow = tid>>2, bsg = (tid&3)*8;
  int frow = lane&15, fk = (lane>>4)*8;
  for (int k0=0;k0<K;k0+=32){
    #pragma unroll
    for (int it=0;it<4;it++){
      int row = arow + it*32;
      int gr = bm + row;
      float4 v = make_float4(0.f,0.f,0.f,0.f);
      if (gr < M) v = *(const float4*)&A[(size_t)gr*K + k0 + ac4];
      f16x4 h4;
      h4[0]=(_Float16)v.x; h4[1]=(_Float16)v.y; h4[2]=(_Float16)v.z; h4[3]=(_Float16)v.w;
      *(f16x4*)&As[row][ac4] = h4;
    }
    #pragma unroll
    for (int it=0;it<2;it++){
      int row = brow + it*64;
      f16x8 u = *(const f16x8*)&Bt[(size_t)(bn+row)*K + k0 + bsg];
      *(f16x8*)&Bs[row][bsg] = u;
    }
    __syncthreads();
    f16x8 af[4], bfr[4];
    #pragma unroll
    for (int i=0;i<4;i++) af[i]  = *(f16x8*)&As[wm + i*16 + frow][fk];
    #pragma unroll
    for (int j=0;j<4;j++) bfr[j] = *(f16x8*)&Bs[wn + j*16 + frow][fk];
    #pragma unroll
    for (int i=0;i<4;i++)
      #pragma unroll
      for (int j=0;j<4;j++)
        acc[i][j] = __builtin_amdgcn_mfma_f32_16x16x32_f16(af[i], bfr[j], acc[i][j], 0,0,0);
    __syncthreads();
  }
  int cl = lane&15, rq = (lane>>4)*4;
  #pragma unroll
  for (int i=0;i<4;i++){
    #pragma unroll
    for (int r4=0;r4<4;r4++){
      int gr = bm + wm + i*16 + rq + r4;
      if (gr < M){
        #pragma unroll
        for (int j=0;j<4;j++){
          int gc = bn + wn + j*16 + cl;
          C[(size_t)gr*N + gc] = (_Float16)(acc[i][j][r4] + bias[gc]);
        }
      }
    }
  }
}

// ---------- fused GATv2 layer 1: H=2; 4 groups = head x edge-parity; 8ch/lane ----------
// xg: fp16 [N][640] = xl | xr | xskip ; efsc: fp16 [N][384] (cols 0..255 layer1)
__global__ __launch_bounds__(256) void k_attn1(
  const _Float16* __restrict__ xg, const _Float16* __restrict__ efsc,
  const _Float16* __restrict__ efb1h, const _Float16* __restrict__ att1h,
  const float* __restrict__ bias1, const int* __restrict__ rowptr,
  const int* __restrict__ srcA, const int* __restrict__ relA, const float* __restrict__ w_s,
  _Float16* __restrict__ h1, int N)
{
  int wv = threadIdx.x>>6, lane = threadIdx.x&63;
  int n = blockIdx.x*4 + wv;
  if (n >= N) return;
  int sub = (lane>>4)&1, t16 = lane&15;
  int ch = (lane>>5)*128 + t16*8;
  f16x8 xrh = *(const f16x8*)&xg[(size_t)n*640 + 256 + ch];
  f16x8 xlh = *(const f16x8*)&xg[(size_t)n*640 + ch];
  f16x8 efh = *(const f16x8*)&efsc[(size_t)n*384 + ch];
  f16x8 ath = *(const f16x8*)&att1h[ch];
  float acc[8];
  #pragma unroll
  for (int z=0;z<8;z++) acc[z] = (sub==0)? (float)xlh[z] : 0.f;
  f16x8 mself = xlh + xrh + efh;
  float s = redux16(dot_leaky(mself, ath));
  float mx = (sub==0)? s : -1e30f;
  float den = (sub==0)? 1.f : 0.f;

  int beg=rowptr[n], end=rowptr[n+1], p=beg;
  for (; p+4<=end; p+=4){
    int eA=p+sub, eB=p+2+sub;
    int iA=srcA[eA], rA=relA[eA]; float wA=w_s[eA];
    int iB=srcA[eB], rB=relA[eB]; float wB=w_s[eB];
    f16x8 xvA = *(const f16x8*)&xg[(size_t)iA + ch];
    f16x8 eeA = *(const f16x8*)&efb1h[rA + ch];
    f16x8 xvB = *(const f16x8*)&xg[(size_t)iB + ch];
    f16x8 eeB = *(const f16x8*)&efb1h[rB + ch];
    _Float16 hA=(_Float16)wA, hB=(_Float16)wB;
    f16x8 wA8, wB8;
    #pragma unroll
    for (int z=0;z<8;z++){ wA8[z]=hA; wB8[z]=hB; }
    f16x8 mA = xvA + xrh + wA8*eeA;
    f16x8 mB = xvB + xrh + wB8*eeB;
    float sA = dot_leaky(mA, ath);
    float sB = dot_leaky(mB, ath);
    #pragma unroll
    for (int off=1; off<16; off<<=1){
      sA += __shfl_xor(sA, off, 64);
      sB += __shfl_xor(sB, off, 64);
    }
    float nm = fmaxf(mx, fmaxf(sA, sB));
    float f = __expf(mx-nm), gA = __expf(sA-nm), gB = __expf(sB-nm);
    den = den*f + gA + gB;
    #pragma unroll
    for (int z=0;z<8;z++)
      acc[z] = acc[z]*f + gA*(float)xvA[z] + gB*(float)xvB[z];
    mx = nm;
  }
  for (; p+2<=end; p+=2){
    int e = p + sub;
    int i0=srcA[e], r0=relA[e]; float w0=w_s[e];
    f16x8 xv = *(const f16x8*)&xg[(size_t)i0 + ch];
    f16x8 ee = *(const f16x8*)&efb1h[r0 + ch];
    _Float16 h0=(_Float16)w0;
    f16x8 w8;
    #pragma unroll
    for (int z=0;z<8;z++) w8[z]=h0;
    f16x8 m8 = xv + xrh + w8*ee;
    float sc = redux16(dot_leaky(m8, ath));
    float nm = fmaxf(mx, sc);
    float f = __expf(mx-nm), ge = __expf(sc-nm);
    den = den*f + ge;
    #pragma unroll
    for (int z=0;z<8;z++) acc[z] = acc[z]*f + ge*(float)xv[z];
    mx = nm;
  }
  if (p < end && sub == 0){
    int e = p;
    int i0=srcA[e], r0=relA[e]; float w0=w_s[e];
    f16x8 xv = *(const f16x8*)&xg[(size_t)i0 + ch];
    f16x8 ee = *(const f16x8*)&efb1h[r0 + ch];
    _Float16 h0=(_Float16)w0;
    f16x8 w8;
    #pragma unroll
    for (int z=0;z<8;z++) w8[z]=h0;
    f16x8 m8 = xv + xrh + w8*ee;
    float sc = redux16(dot_leaky(m8, ath));
    float nm = fmaxf(mx, sc);
    float f = __expf(mx-nm), ge = __expf(sc-nm);
    den = den*f + ge;
    #pragma unroll
    for (int z=0;z<8;z++) acc[z] = acc[z]*f + ge*(float)xv[z];
    mx = nm;
  }
  // merge the two edge-parity groups within each head
  {
    float mo = __shfl_xor(mx, 16, 64);
    float dn = __shfl_xor(den, 16, 64);
    float ao[8];
    #pragma unroll
    for (int z=0;z<8;z++) ao[z] = __shfl_xor(acc[z], 16, 64);
    float mt = fmaxf(mx, mo);
    float fs = __expf(mx-mt), fo = __expf(mo-mt);
    den = den*fs + dn*fo;
    #pragma unroll
    for (int z=0;z<8;z++) acc[z] = acc[z]*fs + ao[z]*fo;
  }
  float inv = 1.f/(den + 1e-16f);
  float res[8];
  #pragma unroll
  for (int z=0;z<8;z++){
    float v = acc[z]*inv;
    float o = __shfl_xor(v, 32, 64);
    res[z] = 0.5f*(v + o);
  }
  if (lane < 16){
    f16x8 skh = *(const f16x8*)&xg[(size_t)n*640 + 512 + t16*8];
    f32x4 b0 = *(const f32x4*)&bias1[t16*8];
    f32x4 b1 = *(const f32x4*)&bias1[t16*8 + 4];
    f16x8 o;
    #pragma unroll
    for (int z=0;z<4;z++) o[z]   = (_Float16)fmaxf(res[z]   + b0[z] + (float)skh[z],   0.f);
    #pragma unroll
    for (int z=0;z<4;z++) o[4+z] = (_Float16)fmaxf(res[4+z] + b1[z] + (float)skh[4+z], 0.f);
    *(f16x8*)&h1[(size_t)n*128 + t16*8] = o;
  }
}

// ---------- fused GATv2 layer 2: H=1; 4 edge groups; 8ch/lane ----------
// xg2: fp16 [N][256] = xl2 | xr2 ; efsc cols 256..383
__global__ __launch_bounds__(256) void k_attn2(
  const _Float16* __restrict__ xg2, const _Float16* __restrict__ efsc,
  const _Float16* __restrict__ efb2h, const _Float16* __restrict__ att2h,
  const float* __restrict__ bias2, const int* __restrict__ rowptr,
  const int* __restrict__ srcB, const int* __restrict__ relB, const float* __restrict__ w_s,
  float* __restrict__ h2, int N)
{
  int wv = threadIdx.x>>6, lane = threadIdx.x&63;
  int n = blockIdx.x*4 + wv;
  if (n >= N) return;
  int g = lane>>4, t16 = lane&15;
  int ch = t16*8;
  f16x8 xrh = *(const f16x8*)&xg2[(size_t)n*256 + 128 + ch];
  f16x8 xlh = *(const f16x8*)&xg2[(size_t)n*256 + ch];
  f16x8 efh = *(const f16x8*)&efsc[(size_t)n*384 + 256 + ch];
  f16x8 ath = *(const f16x8*)&att2h[ch];
  float acc[8];
  #pragma unroll
  for (int z=0;z<8;z++) acc[z] = (g==0)? (float)xlh[z] : 0.f;
  f16x8 mself = xlh + xrh + efh;
  float s = redux16(dot_leaky(mself, ath));
  float mx = (g==0)? s : -1e30f;
  float den = (g==0)? 1.f : 0.f;

  int beg=rowptr[n], end=rowptr[n+1], p=beg;
  for (; p+8<=end; p+=8){
    int eA=p+g, eB=p+4+g;
    int iA=srcB[eA], rA=relB[eA]; float wA=w_s[eA];
    int iB=srcB[eB], rB=relB[eB]; float wB=w_s[eB];
    f16x8 xvA = *(const f16x8*)&xg2[(size_t)iA + ch];
    f16x8 eeA = *(const f16x8*)&efb2h[rA + ch];
    f16x8 xvB = *(const f16x8*)&xg2[(size_t)iB + ch];
    f16x8 eeB = *(const f16x8*)&efb2h[rB + ch];
    _Float16 hA=(_Float16)wA, hB=(_Float16)wB;
    f16x8 wA8, wB8;
    #pragma unroll
    for (int z=0;z<8;z++){ wA8[z]=hA; wB8[z]=hB; }
    f16x8 mA = xvA + xrh + wA8*eeA;
    f16x8 mB = xvB + xrh + wB8*eeB;
    float sA = dot_leaky(mA, ath);
    float sB = dot_leaky(mB, ath);
    #pragma unroll
    for (int off=1; off<16; off<<=1){
      sA += __shfl_xor(sA, off, 64);
      sB += __shfl_xor(sB, off, 64);
    }
    float nm = fmaxf(mx, fmaxf(sA, sB));
    float f = __expf(mx-nm), gA = __expf(sA-nm), gB = __expf(sB-nm);
    den = den*f + gA + gB;
    #pragma unroll
    for (int z=0;z<8;z++)
      acc[z] = acc[z]*f + gA*(float)xvA[z] + gB*(float)xvB[z];
    mx = nm;
  }
  for (; p+4<=end; p+=4){
    int e = p + g;
    int i0=srcB[e], r0=relB[e]; float w0=w_s[e];
    f16x8 xv = *(const f16x8*)&xg2[(size_t)i0 + ch];
    f16x8 ee = *(const f16x8*)&efb2h[r0 + ch];
    _Float16 h0=(_Float16)w0;
    f16x8 w8;
    #pragma unroll
    for (int z=0;z<8;z++) w8[z]=h0;
    f16x8 m8 = xv + xrh + w8*ee;
    float sc = redux16(dot_leaky(m8, ath));
    float nm = fmaxf(mx, sc);
    float f = __expf(mx-nm), ge = __expf(sc-nm);
    den = den*f + ge;
    #pragma unroll
    for (int z=0;z<8;z++) acc[z] = acc[z]*f + ge*(float)xv[z];
    mx = nm;
  }
  int rem = end - p;
  if (g < rem){
    int e = p + g;
    int i0=srcB[e], r0=relB[e]; float w0=w_s[e];
    f16x8 xv = *(const f16x8*)&xg2[(size_t)i0 + ch];
    f16x8 ee = *(const f16x8*)&efb2h[r0 + ch];
    _Float16 h0=(_Float16)w0;
    f16x8 w8;
    #pragma unroll
    for (int z=0;z<8;z++) w8[z]=h0;
    f16x8 m8 = xv + xrh + w8*ee;
    float sc = redux16(dot_leaky(m8, ath));
    float nm = fmaxf(mx, sc);
    float f = __expf(mx-nm), ge = __expf(sc-nm);
    den = den*f + ge;
    #pragma unroll
    for (int z=0;z<8;z++) acc[z] = acc[z]*f + ge*(float)xv[z];
    mx = nm;
  }
  // butterfly-merge the 4 group states
  #pragma unroll
  for (int off=16; off<=32; off<<=1){
    float mo = __shfl_xor(mx, off, 64);
    float dn = __shfl_xor(den, off, 64);
    float ao[8];
    #pragma unroll
    for (int z=0;z<8;z++) ao[z] = __shfl_xor(acc[z], off, 64);
    float mt = fmaxf(mx, mo);
    float fs = __expf(mx-mt), fo = __expf(mo-mt);
    den = den*fs + dn*fo;
    #pragma unroll
    for (int z=0;z<8;z++) acc[z] = acc[z]*fs + ao[z]*fo;
    mx = mt;
  }
  float inv = 1.f/(den + 1e-16f);
  if (g == 0){
    f32x4 b0 = *(const f32x4*)&bias2[ch];
    f32x4 b1 = *(const f32x4*)&bias2[ch+4];
    f32x4 o0, o1;
    #pragma unroll
    for (int z=0;z<4;z++){ o0[z] = fmaxf(acc[z]*inv   + b0[z], 0.f);
                           o1[z] = fmaxf(acc[4+z]*inv + b1[z], 0.f); }
    *(f32x4*)&h2[(size_t)n*128 + ch]     = o0;
    *(f32x4*)&h2[(size_t)n*128 + ch + 4] = o1;
  }
}

// ---------- graph boundaries ----------
__global__ void k_start(const int* __restrict__ batch, int* __restrict__ start, int N){
  int i = blockIdx.x*256 + threadIdx.x;
  if (i >= N) return;
  int b = batch[i];
  int pb = (i==0)? -1 : batch[i-1];
  for (int g=pb+1; g<=b; g++) start[g] = i;
  if (i == N-1){ for (int g=b+1; g<=NG; g++) start[g] = N; }
}

// ---------- pooling stage A ----------
#define PCHUNK 32
__global__ __launch_bounds__(256) void k_pool_part(const float* __restrict__ x, const _Float16* __restrict__ h1,
                       const float* __restrict__ h2, const int* __restrict__ batch,
                       unsigned* __restrict__ umax, float* __restrict__ fsum, int N){
  int c0 = blockIdx.x * PCHUNK;
  int c1 = min(c0 + PCHUNK, N);
  if (c0 >= N) return;
  int t = threadIdx.x;
  float mx0 = -INFINITY, sm0 = 0.f, mx1 = -INFINITY, sm1 = 0.f;
  int bcur = batch[c0];
  for (int i=c0;i<c1;i++){
    int b = batch[i];
    if (b != bcur){
      atomicMax(&umax[bcur*512 + t], enc_f(mx0));
      atomicAdd(&fsum[bcur*512 + t], sm0);
      atomicMax(&umax[bcur*512 + 256 + t], enc_f(mx1));
      atomicAdd(&fsum[bcur*512 + 256 + t], sm1);
      mx0 = mx1 = -INFINITY; sm0 = sm1 = 0.f; bcur = b;
    }
    float v0 = x[(size_t)i*256 + t];
    float v1 = (t<128) ? (float)h1[(size_t)i*128 + t] : h2[(size_t)i*128 + (t-128)];
    mx0 = fmaxf(mx0, v0); sm0 += v0;
    mx1 = fmaxf(mx1, v1); sm1 += v1;
  }
  atomicMax(&umax[bcur*512 + t], enc_f(mx0));
  atomicAdd(&fsum[bcur*512 + t], sm0);
  atomicMax(&umax[bcur*512 + 256 + t], enc_f(mx1));
  atomicAdd(&fsum[bcur*512 + 256 + t], sm1);
}

// ---------- pooling stage B ----------
__global__ void k_pool_final(const unsigned* __restrict__ umax, const float* __restrict__ fsum,
                             const int* __restrict__ start, float* __restrict__ xpool){
  int g = blockIdx.x; int f = blockIdx.y*256 + threadIdx.x;
  float m = dec_f(umax[g*512 + f]);
  if (!isfinite(m)) m = 0.f;
  int cnt = start[g+1] - start[g];
  xpool[g*1024 + f]       = m;
  xpool[g*1024 + 512 + f] = fsum[g*512 + f] / (float)max(cnt,1);
}

__global__ __launch_bounds__(256) void k_mlp1(const float* __restrict__ xpool, const float* __restrict__ W1,
                       const float* __restrict__ b1, float* __restrict__ hmid){
  __shared__ float part[256];
  int g = blockIdx.x; int c = threadIdx.x & 127; int half = threadIdx.x >> 7;
  float a0=0.f,a1=0.f,a2=0.f,a3=0.f;
  int kb = half*512;
  #pragma unroll 4
  for (int k=0;k<512;k+=4){
    a0 += xpool[g*1024+kb+k+0]*W1[(kb+k+0)*128+c];
    a1 += xpool[g*1024+kb+k+1]*W1[(kb+k+1)*128+c];
    a2 += xpool[g*1024+kb+k+2]*W1[(kb+k+2)*128+c];
    a3 += xpool[g*1024+kb+k+3]*W1[(kb+k+3)*128+c];
  }
  part[threadIdx.x] = (a0+a1)+(a2+a3);
  __syncthreads();
  if (half==0){
    float a = part[c] + part[128+c] + b1[c];
    hmid[g*128+c] = fmaxf(a, 0.f);
  }
}
__global__ void k_mlp2(const float* __restrict__ hmid, const float* __restrict__ W2,
                       const float* __restrict__ b2, float* __restrict__ out){
  int g = threadIdx.x; if (g >= NG) return;
  float a = b2[0];
  for (int k=0;k<128;k++) a += hmid[g*128+k]*W2[k];
  out[g] = a;
}

extern "C" void kernel_launch(void* const* d_in, const int* in_sizes, int n_in,
                              void* d_out, int out_size, void* d_ws, size_t ws_size,
                              hipStream_t stream) {
  const float* x     = (const float*)d_in[0];
  const int*   eidx  = (const int*)d_in[1];
  const int*   eattr = (const int*)d_in[2];
  const float* ew    = (const float*)d_in[3];
  const int*   batch = (const int*)d_in[4];
  const float* irf   = (const float*)d_in[5];
  const float* emb   = (const float*)d_in[6];
  const float* Wl1   = (const float*)d_in[7];
  const float* bl1   = (const float*)d_in[8];
  const float* Wr1   = (const float*)d_in[9];
  const float* br1   = (const float*)d_in[10];
  const float* We1   = (const float*)d_in[11];
  const float* att1  = (const float*)d_in[12];
  const float* bias1 = (const float*)d_in[13];
  const float* Wl2   = (const float*)d_in[14];
  const float* bl2   = (const float*)d_in[15];
  const float* Wr2   = (const float*)d_in[16];
  const float* br2   = (const float*)d_in[17];
  const float* We2   = (const float*)d_in[18];
  const float* att2  = (const float*)d_in[19];
  const float* bias2 = (const float*)d_in[20];
  const float* skipW = (const float*)d_in[21];
  const float* skipb = (const float*)d_in[22];
  const float* W1    = (const float*)d_in[23];
  const float* b1    = (const float*)d_in[24];
  const float* W2    = (const float*)d_in[25];
  const float* b2    = (const float*)d_in[26];

  const int N = in_sizes[4];        // 50000
  const int E = in_sizes[3];        // 800000
  const int* srcp = eidx;
  const int* dstp = eidx + E;

  // ---- workspace carve ----
  char* w = (char*)d_ws;
  size_t off = 0;
  auto alloc = [&](size_t bytes)->void*{
    size_t o = off; off = (off + bytes + 255) & ~(size_t)255; return (void*)(w + o);
  };
  float* base  = (float*)alloc((size_t)40*EDIM*4);
  _Float16* efb1h = (_Float16*)alloc((size_t)40*256*2);
  _Float16* efb2h = (_Float16*)alloc((size_t)40*128*2);
  _Float16* W1cat = (_Float16*)alloc((size_t)640*256*2);
  _Float16* W2cat = (_Float16*)alloc((size_t)256*128*2);
  _Float16* Wecat = (_Float16*)alloc((size_t)384*32*2);
  float* bcat1 = (float*)alloc((size_t)640*4);
  float* bcat2 = (float*)alloc((size_t)256*4);
  _Float16* att1h = (_Float16*)alloc((size_t)256*2);
  _Float16* att2h = (_Float16*)alloc((size_t)128*2);
  // zero-init region
  size_t zoff0 = off;
  int*   cnt   = (int*)alloc((size_t)N*4);
  int*   fillc = (int*)alloc((size_t)N*4);
  unsigned* umax = (unsigned*)alloc((size_t)NG*512*4);
  float* fsum  = (float*)alloc((size_t)NG*512*4);
  float* bcatE = (float*)alloc((size_t)384*4);
  size_t zlen = off - zoff0;
  int*   rowptr= (int*)alloc((size_t)(N+1)*4);
  int*   incl  = (int*)alloc((size_t)N*4);
  int*   bsum  = (int*)alloc((size_t)64*4);
  int*   srcA  = (int*)alloc((size_t)E*4);
  int*   relA  = (int*)alloc((size_t)E*4);
  int*   srcB  = (int*)alloc((size_t)E*4);
  int*   relB  = (int*)alloc((size_t)E*4);
  int*   rel_s = (int*)alloc((size_t)E*4);
  float* w_s   = (float*)alloc((size_t)E*4);
  float* lf    = (float*)alloc((size_t)N*EDIM*4);
  _Float16* xh = (_Float16*)alloc((size_t)N*256*2);
  _Float16* xg = (_Float16*)alloc((size_t)N*640*2);
  _Float16* efsc = (_Float16*)alloc((size_t)N*384*2);
  _Float16* h1 = (_Float16*)alloc((size_t)N*128*2);
  int*   start = (int*)alloc((size_t)(NG+1)*4);
  float* xpool = (float*)alloc((size_t)NG*1024*4);
  float* hmid  = (float*)alloc((size_t)NG*128*4);
  _Float16* xg2 = xg;       // reuse: xg dead after attn1

  float* outp  = (float*)d_out;        // (64,1)
  float* h2out = (float*)d_out + NG;   // (N,128)

  hipMemsetAsync((char*)d_ws + zoff0, 0, zlen, stream);

  k_setup<<<859, 256, 0, stream>>>(emb, irf, We1, We2, Wl1, Wr1, skipW, Wl2, Wr2,
                                   bl1, br1, skipb, bl2, br2, att1, att2,
                                   base, efb1h, efb2h, W1cat, W2cat, Wecat,
                                   bcat1, bcat2, att1h, att2h);
  k_xcvt<<<(N*256/8 + 255)/256, 256, 0, stream>>>(x, xh, N*256/8);

  k_count<<<(E+255)/256, 256, 0, stream>>>(dstp, cnt, E);
  int nb = (N + 1023)/1024;
  k_scan1<<<nb, 1024, 0, stream>>>(cnt, incl, bsum, N);
  k_scan2<<<1, 64, 0, stream>>>(bsum, nb);
  k_scan3<<<(N+255)/256, 256, 0, stream>>>(incl, bsum, rowptr, N);
  k_fill<<<(E+255)/256, 256, 0, stream>>>(srcp, dstp, eattr, ew, rowptr, fillc,
                                          srcA, relA, srcB, relB, rel_s, w_s, E);
  k_loopfeat<<<((size_t)N*32+255)/256, 256, 0, stream>>>(rowptr, rel_s, w_s, base, lf, N);

  int gy = (N + 127)/128;
  k_gemm_f16<<<dim3(5, gy), 256, 0, stream>>>(xh, W1cat, bcat1, xg, N, 640, 256);
  k_gemm_f32a<<<dim3(3, gy), 256, 0, stream>>>(lf, Wecat, bcatE, efsc, N, 384, 32);

  k_attn1<<<(N+3)/4, 256, 0, stream>>>(xg, efsc, efb1h, att1h, bias1,
                                       rowptr, srcA, relA, w_s, h1, N);

  k_gemm_f16<<<dim3(2, gy), 256, 0, stream>>>(h1, W2cat, bcat2, xg2, N, 256, 128);

  k_attn2<<<(N+3)/4, 256, 0, stream>>>(xg2, efsc, efb2h, att2h, bias2,
                                       rowptr, srcB, relB, w_s, h2out, N);

  k_start<<<(N+255)/256, 256, 0, stream>>>(batch, start, N);
  k_pool_part<<<(N+PCHUNK-1)/PCHUNK, 256, 0, stream>>>(x, h1, h2out, batch, umax, fsum, N);
  k_pool_final<<<dim3(NG,2), 256, 0, stream>>>(umax, fsum, start, xpool);
  k_mlp1<<<NG, 256, 0, stream>>>(xpool, W1, b1, hmid);
  k_mlp2<<<1, 64, 0, stream>>>(hmid, W2, b2, outp);
  (void)n_in; (void)out_size; (void)ws_size;
}

// Round 11
// 378.600 us; speedup vs baseline: 6.9912x; 1.1218x over previous
//
#include <hip/hip_runtime.h>
#include <math.h>

#define EDIM 32
#define NG 64

typedef __attribute__((ext_vector_type(8))) _Float16 f16x8;
typedef __attribute__((ext_vector_type(4))) _Float16 f16x4;
typedef __attribute__((ext_vector_type(2))) _Float16 f16x2;
typedef __attribute__((ext_vector_type(4))) float f32x4;

#if __has_builtin(__builtin_amdgcn_fdot2)
#define USE_FDOT2 1
#else
#define USE_FDOT2 0
#endif

__device__ inline unsigned enc_f(float f){
  unsigned b = __float_as_uint(f);
  return (b & 0x80000000u) ? ~b : (b | 0x80000000u);
}
__device__ inline float dec_f(unsigned u){
  unsigned b = (u & 0x80000000u) ? (u & 0x7FFFFFFFu) : ~u;
  return __uint_as_float(b);
}
__device__ inline float redux16(float v){
  #pragma unroll
  for (int off=1; off<16; off<<=1) v += __shfl_xor(v, off, 64);
  return v;
}
// leaky-relu(m) . att  over 8 f16 channels
__device__ inline float dot_leaky(f16x8 m8, f16x8 a8){
#if __has_builtin(__builtin_elementwise_max)
  f16x8 lm = __builtin_elementwise_max(m8, m8*(_Float16)0.2f);
#else
  f16x8 lm;
  #pragma unroll
  for (int z=0;z<8;z++){ _Float16 v=m8[z]; lm[z] = (v>(_Float16)0)? v : v*(_Float16)0.2f; }
#endif
  float s = 0.f;
#if USE_FDOT2
  #pragma unroll
  for (int z=0;z<4;z++){
    f16x2 u; u[0]=lm[2*z]; u[1]=lm[2*z+1];
    f16x2 w2; w2[0]=a8[2*z]; w2[1]=a8[2*z+1];
    s = __builtin_amdgcn_fdot2(u, w2, s, false);
  }
#else
  #pragma unroll
  for (int z=0;z<8;z++) s += (float)lm[z]*(float)a8[z];
#endif
  return s;
}

// ---------- fused setup: rel tables + weight transposes + bias/att concat ----------
__global__ __launch_bounds__(256) void k_setup(
    const float* __restrict__ emb, const float* __restrict__ irf,
    const float* __restrict__ We1, const float* __restrict__ We2,
    const float* __restrict__ Wl1, const float* __restrict__ Wr1, const float* __restrict__ skipW,
    const float* __restrict__ Wl2, const float* __restrict__ Wr2,
    const float* __restrict__ bl1, const float* __restrict__ br1, const float* __restrict__ skipb,
    const float* __restrict__ bl2, const float* __restrict__ br2,
    const float* __restrict__ att1, const float* __restrict__ att2,
    float* __restrict__ base, _Float16* __restrict__ efb1h, _Float16* __restrict__ efb2h,
    _Float16* __restrict__ W1cat, _Float16* __restrict__ W2cat, _Float16* __restrict__ Wecat,
    float* __restrict__ bcat1, float* __restrict__ bcat2,
    _Float16* __restrict__ att1h, _Float16* __restrict__ att2h)
{
  int b = blockIdx.x, t = threadIdx.x;
  if (b < 40){
    __shared__ float bb[EDIM];
    int r = b;
    if (t < 32){
      float v = emb[r*EDIM + t];
      float ss = v*v;
      #pragma unroll
      for (int off=16; off>0; off>>=1) ss += __shfl_xor(ss, off, 64);
      float nrm = sqrtf(ss);
      float w = v / fmaxf(nrm, 1e-12f) * irf[r];
      bb[t] = w;
      base[r*EDIM + t] = w;
    }
    __syncthreads();
    float a1 = 0.f;
    #pragma unroll
    for (int k=0;k<EDIM;k++) a1 += bb[k]*We1[k*256 + t];
    efb1h[r*256 + t] = (_Float16)a1;
    if (t < 128){
      float a2 = 0.f;
      #pragma unroll
      for (int k=0;k<EDIM;k++) a2 += bb[k]*We2[k*128 + t];
      efb2h[r*128 + t] = (_Float16)a2;
    }
  }
  else if (b < 296){ int idx=(b-40)*256+t;  int k=idx>>8, n2=idx&255; W1cat[n2*256+k]          = (_Float16)Wl1[idx]; }
  else if (b < 552){ int idx=(b-296)*256+t; int k=idx>>8, n2=idx&255; W1cat[65536+n2*256+k]    = (_Float16)Wr1[idx]; }
  else if (b < 680){ int idx=(b-552)*256+t; int k=idx>>7, n2=idx&127; W1cat[131072+n2*256+k]   = (_Float16)skipW[idx]; }
  else if (b < 744){ int idx=(b-680)*256+t; int k=idx>>7, n2=idx&127; W2cat[n2*128+k]          = (_Float16)Wl2[idx]; }
  else if (b < 808){ int idx=(b-744)*256+t; int k=idx>>7, n2=idx&127; W2cat[16384+n2*128+k]    = (_Float16)Wr2[idx]; }
  else if (b < 840){ int idx=(b-808)*256+t; int k=idx>>8, n2=idx&255; Wecat[n2*32+k]           = (_Float16)We1[idx]; }
  else if (b < 856){ int idx=(b-840)*256+t; int k=idx>>7, n2=idx&127; Wecat[8192+n2*32+k]      = (_Float16)We2[idx]; }
  else if (b == 856){ bcat1[t] = bl1[t]; }
  else if (b == 857){
    bcat1[256+t] = br1[t];
    if (t < 128) bcat1[512+t] = skipb[t];
    att1h[t] = (_Float16)att1[t];
  } else {
    if (t < 128){
      bcat2[t] = bl2[t];
      bcat2[128+t] = br2[t];
      att2h[t] = (_Float16)att2[t];
    }
  }
}

// ---------- x -> fp16 ----------
__global__ void k_xcvt(const float* __restrict__ x, _Float16* __restrict__ xh, int total8){
  int i = blockIdx.x*256 + threadIdx.x;
  if (i < total8){
    float4 v0 = *(const float4*)&x[(size_t)i*8];
    float4 v1 = *(const float4*)&x[(size_t)i*8 + 4];
    f16x8 o;
    o[0]=(_Float16)v0.x; o[1]=(_Float16)v0.y; o[2]=(_Float16)v0.z; o[3]=(_Float16)v0.w;
    o[4]=(_Float16)v1.x; o[5]=(_Float16)v1.y; o[6]=(_Float16)v1.z; o[7]=(_Float16)v1.w;
    *(f16x8*)&xh[(size_t)i*8] = o;
  }
}

// ---------- CSR build ----------
__global__ void k_count(const int* __restrict__ dst, int* __restrict__ cnt, int E){
  int e = blockIdx.x*256 + threadIdx.x;
  if (e < E) atomicAdd(&cnt[dst[e]], 1);
}

__global__ __launch_bounds__(1024) void k_scan1(const int* __restrict__ cnt, int* __restrict__ incl,
                                                int* __restrict__ bsum, int n){
  __shared__ int s[1024];
  int i = blockIdx.x*1024 + threadIdx.x;
  int v = (i<n)? cnt[i] : 0;
  s[threadIdx.x] = v; __syncthreads();
  for (int off=1; off<1024; off<<=1){
    int add = (threadIdx.x>=(unsigned)off)? s[threadIdx.x-off] : 0;
    __syncthreads();
    s[threadIdx.x] += add;
    __syncthreads();
  }
  if (i<n) incl[i] = s[threadIdx.x];
  if (threadIdx.x==1023) bsum[blockIdx.x] = s[1023];
}
__global__ void k_scan2(int* __restrict__ bsum, int nb){
  if (threadIdx.x==0 && blockIdx.x==0){
    int acc=0;
    for (int b=0;b<nb;b++){ int t=bsum[b]; bsum[b]=acc; acc+=t; }
  }
}
__global__ void k_scan3(const int* __restrict__ incl, const int* __restrict__ bsum,
                        int* __restrict__ rowptr, int n){
  int i = blockIdx.x*256 + threadIdx.x;
  if (i<n) rowptr[i+1] = incl[i] + bsum[i>>10];
  if (i==0) rowptr[0] = 0;
}
// scatter ONE packed 8B record per edge: {src | rel<<20, w-bits}
__global__ void k_fill(const int* __restrict__ src, const int* __restrict__ dst,
                       const int* __restrict__ rel, const float* __restrict__ ew,
                       const int* __restrict__ rowptr, int* __restrict__ fill,
                       int2* __restrict__ epack, int E){
  int e = blockIdx.x*256 + threadIdx.x;
  if (e<E){
    int d = dst[e];
    int pos = rowptr[d] + atomicAdd(&fill[d],1);
    int2 rec;
    rec.x = src[e] | (rel[e]<<20);
    rec.y = __float_as_int(ew[e]);
    epack[pos] = rec;
  }
}

// ---------- loop_feat ----------
__global__ void k_loopfeat(const int* __restrict__ rowptr, const int2* __restrict__ epack,
                           const float* __restrict__ base, float* __restrict__ lf, int N){
  int gid = blockIdx.x*256 + threadIdx.x;
  int n = gid >> 5; int k = gid & 31;
  if (n >= N) return;
  int beg = rowptr[n], end = rowptr[n+1];
  float s = 0.f;
  for (int p=beg;p<end;p++){
    int2 ep = epack[p];
    s += __int_as_float(ep.y)*base[((ep.x>>20)<<5) + k];
  }
  int c = end - beg;
  lf[n*EDIM + k] = s / (float)max(c,1);
}

// ---------- fp16 MFMA GEMM (double-buffered): C = A@Bt^T + bias ----------
__global__ __launch_bounds__(256) void k_gemm_f16(
    const _Float16* __restrict__ A, const _Float16* __restrict__ Bt,
    const float* __restrict__ bias, _Float16* __restrict__ C,
    int M, int N, int K)
{
  __shared__ __attribute__((aligned(16))) _Float16 As[2][128][40];
  __shared__ __attribute__((aligned(16))) _Float16 Bs[2][128][40];
  int tid = threadIdx.x;
  int wid = tid>>6, lane = tid&63;
  int wm = (wid>>1)*64, wn = (wid&1)*64;
  int bm = blockIdx.y*128, bn = blockIdx.x*128;
  int frow = lane&15, fk = (lane>>4)*8;
  int r0c = tid>>2,        s0c = (tid&3)*8;
  int r1c = (tid+256)>>2,  s1c = (tid&3)*8;
  auto loadA = [&](int r, int s, int k0)->f16x8{
    int gr = bm + r;
    f16x8 v;
    if (gr < M) v = *(const f16x8*)&A[(size_t)gr*K + k0 + s];
    else { for (int z=0;z<8;z++) v[z]=(_Float16)0.f; }
    return v;
  };
  auto loadB = [&](int r, int s, int k0)->f16x8{
    return *(const f16x8*)&Bt[(size_t)(bn+r)*K + k0 + s];
  };
  f32x4 acc[4][4] = {};
  int nt = K >> 5;
  {
    f16x8 a0 = loadA(r0c,s0c,0), a1 = loadA(r1c,s1c,0);
    f16x8 b0 = loadB(r0c,s0c,0), b1 = loadB(r1c,s1c,0);
    *(f16x8*)&As[0][r0c][s0c] = a0;  *(f16x8*)&As[0][r1c][s1c] = a1;
    *(f16x8*)&Bs[0][r0c][s0c] = b0;  *(f16x8*)&Bs[0][r1c][s1c] = b1;
  }
  for (int t=0; t<nt; t++){
    int cur = t&1, nxt = cur^1;
    __syncthreads();
    f16x8 a0,a1,b0,b1;
    bool pf = (t+1 < nt);
    if (pf){
      int k0 = (t+1)<<5;
      a0 = loadA(r0c,s0c,k0); a1 = loadA(r1c,s1c,k0);
      b0 = loadB(r0c,s0c,k0); b1 = loadB(r1c,s1c,k0);
    }
    f16x8 af[4], bfr[4];
    #pragma unroll
    for (int i=0;i<4;i++) af[i]  = *(f16x8*)&As[cur][wm + i*16 + frow][fk];
    #pragma unroll
    for (int j=0;j<4;j++) bfr[j] = *(f16x8*)&Bs[cur][wn + j*16 + frow][fk];
    #pragma unroll
    for (int i=0;i<4;i++)
      #pragma unroll
      for (int j=0;j<4;j++)
        acc[i][j] = __builtin_amdgcn_mfma_f32_16x16x32_f16(af[i], bfr[j], acc[i][j], 0,0,0);
    if (pf){
      *(f16x8*)&As[nxt][r0c][s0c] = a0;  *(f16x8*)&As[nxt][r1c][s1c] = a1;
      *(f16x8*)&Bs[nxt][r0c][s0c] = b0;  *(f16x8*)&Bs[nxt][r1c][s1c] = b1;
    }
  }
  int cl = lane&15, rq = (lane>>4)*4;
  #pragma unroll
  for (int i=0;i<4;i++){
    #pragma unroll
    for (int r4=0;r4<4;r4++){
      int gr = bm + wm + i*16 + rq + r4;
      if (gr < M){
        #pragma unroll
        for (int j=0;j<4;j++){
          int gc = bn + wn + j*16 + cl;
          C[(size_t)gr*N + gc] = (_Float16)(acc[i][j][r4] + bias[gc]);
        }
      }
    }
  }
}

// ---------- fp32-A single-buffer GEMM (tiny K=32 efsc projection) ----------
__global__ __launch_bounds__(256) void k_gemm_f32a(
    const float* __restrict__ A, const _Float16* __restrict__ Bt,
    const float* __restrict__ bias, _Float16* __restrict__ C,
    int M, int N, int K)
{
  __shared__ __attribute__((aligned(16))) _Float16 As[128][40];
  __shared__ __attribute__((aligned(16))) _Float16 Bs[128][40];
  int tid = threadIdx.x;
  int wid = tid>>6, lane = tid&63;
  int wm = (wid>>1)*64, wn = (wid&1)*64;
  int bm = blockIdx.y*128, bn = blockIdx.x*128;
  f32x4 acc[4][4] = {};
  int arow = tid>>3, ac4 = (tid&7)*4;
  int brow = tid>>2, bsg = (tid&3)*8;
  int frow = lane&15, fk = (lane>>4)*8;
  for (int k0=0;k0<K;k0+=32){
    #pragma unroll
    for (int it=0;it<4;it++){
      int row = arow + it*32;
      int gr = bm + row;
      float4 v = make_float4(0.f,0.f,0.f,0.f);
      if (gr < M) v = *(const float4*)&A[(size_t)gr*K + k0 + ac4];
      f16x4 h4;
      h4[0]=(_Float16)v.x; h4[1]=(_Float16)v.y; h4[2]=(_Float16)v.z; h4[3]=(_Float16)v.w;
      *(f16x4*)&As[row][ac4] = h4;
    }
    #pragma unroll
    for (int it=0;it<2;it++){
      int row = brow + it*64;
      f16x8 u = *(const f16x8*)&Bt[(size_t)(bn+row)*K + k0 + bsg];
      *(f16x8*)&Bs[row][bsg] = u;
    }
    __syncthreads();
    f16x8 af[4], bfr[4];
    #pragma unroll
    for (int i=0;i<4;i++) af[i]  = *(f16x8*)&As[wm + i*16 + frow][fk];
    #pragma unroll
    for (int j=0;j<4;j++) bfr[j] = *(f16x8*)&Bs[wn + j*16 + frow][fk];
    #pragma unroll
    for (int i=0;i<4;i++)
      #pragma unroll
      for (int j=0;j<4;j++)
        acc[i][j] = __builtin_amdgcn_mfma_f32_16x16x32_f16(af[i], bfr[j], acc[i][j], 0,0,0);
    __syncthreads();
  }
  int cl = lane&15, rq = (lane>>4)*4;
  #pragma unroll
  for (int i=0;i<4;i++){
    #pragma unroll
    for (int r4=0;r4<4;r4++){
      int gr = bm + wm + i*16 + rq + r4;
      if (gr < M){
        #pragma unroll
        for (int j=0;j<4;j++){
          int gc = bn + wn + j*16 + cl;
          C[(size_t)gr*N + gc] = (_Float16)(acc[i][j][r4] + bias[gc]);
        }
      }
    }
  }
}

// ---------- fused GATv2 layer 1: H=2; 4 groups = head x edge-parity; 8ch/lane ----------
__global__ __launch_bounds__(256) void k_attn1(
  const _Float16* __restrict__ xg, const _Float16* __restrict__ efsc,
  const _Float16* __restrict__ efb1h, const _Float16* __restrict__ att1h,
  const float* __restrict__ bias1, const int* __restrict__ rowptr,
  const int2* __restrict__ epack,
  _Float16* __restrict__ h1, int N)
{
  int wv = threadIdx.x>>6, lane = threadIdx.x&63;
  int n = blockIdx.x*4 + wv;
  if (n >= N) return;
  int sub = (lane>>4)&1, t16 = lane&15;
  int ch = (lane>>5)*128 + t16*8;
  f16x8 xrh = *(const f16x8*)&xg[(size_t)n*640 + 256 + ch];
  f16x8 xlh = *(const f16x8*)&xg[(size_t)n*640 + ch];
  f16x8 efh = *(const f16x8*)&efsc[(size_t)n*384 + ch];
  f16x8 ath = *(const f16x8*)&att1h[ch];
  float acc[8];
  #pragma unroll
  for (int z=0;z<8;z++) acc[z] = (sub==0)? (float)xlh[z] : 0.f;
  f16x8 mself = xlh + xrh + efh;
  float s = redux16(dot_leaky(mself, ath));
  float mx = (sub==0)? s : -1e30f;
  float den = (sub==0)? 1.f : 0.f;

  int beg=rowptr[n], end=rowptr[n+1], p=beg;
  for (; p+4<=end; p+=4){
    int2 pA = epack[p+sub], pB = epack[p+2+sub];
    int iA = (pA.x & 0xFFFFF)*640, rA = (pA.x>>20)<<8; float wA = __int_as_float(pA.y);
    int iB = (pB.x & 0xFFFFF)*640, rB = (pB.x>>20)<<8; float wB = __int_as_float(pB.y);
    f16x8 xvA = *(const f16x8*)&xg[(size_t)iA + ch];
    f16x8 eeA = *(const f16x8*)&efb1h[rA + ch];
    f16x8 xvB = *(const f16x8*)&xg[(size_t)iB + ch];
    f16x8 eeB = *(const f16x8*)&efb1h[rB + ch];
    _Float16 hA=(_Float16)wA, hB=(_Float16)wB;
    f16x8 wA8, wB8;
    #pragma unroll
    for (int z=0;z<8;z++){ wA8[z]=hA; wB8[z]=hB; }
    f16x8 mA = xvA + xrh + wA8*eeA;
    f16x8 mB = xvB + xrh + wB8*eeB;
    float sA = dot_leaky(mA, ath);
    float sB = dot_leaky(mB, ath);
    #pragma unroll
    for (int off=1; off<16; off<<=1){
      sA += __shfl_xor(sA, off, 64);
      sB += __shfl_xor(sB, off, 64);
    }
    float nm = fmaxf(mx, fmaxf(sA, sB));
    float f = __expf(mx-nm), gA = __expf(sA-nm), gB = __expf(sB-nm);
    den = den*f + gA + gB;
    #pragma unroll
    for (int z=0;z<8;z++)
      acc[z] = acc[z]*f + gA*(float)xvA[z] + gB*(float)xvB[z];
    mx = nm;
  }
  for (; p+2<=end; p+=2){
    int2 pE = epack[p+sub];
    int i0 = (pE.x & 0xFFFFF)*640, r0 = (pE.x>>20)<<8; float w0 = __int_as_float(pE.y);
    f16x8 xv = *(const f16x8*)&xg[(size_t)i0 + ch];
    f16x8 ee = *(const f16x8*)&efb1h[r0 + ch];
    _Float16 h0=(_Float16)w0;
    f16x8 w8;
    #pragma unroll
    for (int z=0;z<8;z++) w8[z]=h0;
    f16x8 m8 = xv + xrh + w8*ee;
    float sc = redux16(dot_leaky(m8, ath));
    float nm = fmaxf(mx, sc);
    float f = __expf(mx-nm), ge = __expf(sc-nm);
    den = den*f + ge;
    #pragma unroll
    for (int z=0;z<8;z++) acc[z] = acc[z]*f + ge*(float)xv[z];
    mx = nm;
  }
  if (p < end && sub == 0){
    int2 pE = epack[p];
    int i0 = (pE.x & 0xFFFFF)*640, r0 = (pE.x>>20)<<8; float w0 = __int_as_float(pE.y);
    f16x8 xv = *(const f16x8*)&xg[(size_t)i0 + ch];
    f16x8 ee = *(const f16x8*)&efb1h[r0 + ch];
    _Float16 h0=(_Float16)w0;
    f16x8 w8;
    #pragma unroll
    for (int z=0;z<8;z++) w8[z]=h0;
    f16x8 m8 = xv + xrh + w8*ee;
    float sc = redux16(dot_leaky(m8, ath));
    float nm = fmaxf(mx, sc);
    float f = __expf(mx-nm), ge = __expf(sc-nm);
    den = den*f + ge;
    #pragma unroll
    for (int z=0;z<8;z++) acc[z] = acc[z]*f + ge*(float)xv[z];
    mx = nm;
  }
  // merge the two edge-parity groups within each head
  {
    float mo = __shfl_xor(mx, 16, 64);
    float dn = __shfl_xor(den, 16, 64);
    float ao[8];
    #pragma unroll
    for (int z=0;z<8;z++) ao[z] = __shfl_xor(acc[z], 16, 64);
    float mt = fmaxf(mx, mo);
    float fs = __expf(mx-mt), fo = __expf(mo-mt);
    den = den*fs + dn*fo;
    #pragma unroll
    for (int z=0;z<8;z++) acc[z] = acc[z]*fs + ao[z]*fo;
  }
  float inv = 1.f/(den + 1e-16f);
  float res[8];
  #pragma unroll
  for (int z=0;z<8;z++){
    float v = acc[z]*inv;
    float o = __shfl_xor(v, 32, 64);
    res[z] = 0.5f*(v + o);
  }
  if (lane < 16){
    f16x8 skh = *(const f16x8*)&xg[(size_t)n*640 + 512 + t16*8];
    f32x4 b0 = *(const f32x4*)&bias1[t16*8];
    f32x4 b1 = *(const f32x4*)&bias1[t16*8 + 4];
    f16x8 o;
    #pragma unroll
    for (int z=0;z<4;z++) o[z]   = (_Float16)fmaxf(res[z]   + b0[z] + (float)skh[z],   0.f);
    #pragma unroll
    for (int z=0;z<4;z++) o[4+z] = (_Float16)fmaxf(res[4+z] + b1[z] + (float)skh[4+z], 0.f);
    *(f16x8*)&h1[(size_t)n*128 + t16*8] = o;
  }
}

// ---------- fused GATv2 layer 2: H=1; 4 edge groups; 8ch/lane ----------
__global__ __launch_bounds__(256) void k_attn2(
  const _Float16* __restrict__ xg2, const _Float16* __restrict__ efsc,
  const _Float16* __restrict__ efb2h, const _Float16* __restrict__ att2h,
  const float* __restrict__ bias2, const int* __restrict__ rowptr,
  const int2* __restrict__ epack,
  float* __restrict__ h2, int N)
{
  int wv = threadIdx.x>>6, lane = threadIdx.x&63;
  int n = blockIdx.x*4 + wv;
  if (n >= N) return;
  int g = lane>>4, t16 = lane&15;
  int ch = t16*8;
  f16x8 xrh = *(const f16x8*)&xg2[(size_t)n*256 + 128 + ch];
  f16x8 xlh = *(const f16x8*)&xg2[(size_t)n*256 + ch];
  f16x8 efh = *(const f16x8*)&efsc[(size_t)n*384 + 256 + ch];
  f16x8 ath = *(const f16x8*)&att2h[ch];
  float acc[8];
  #pragma unroll
  for (int z=0;z<8;z++) acc[z] = (g==0)? (float)xlh[z] : 0.f;
  f16x8 mself = xlh + xrh + efh;
  float s = redux16(dot_leaky(mself, ath));
  float mx = (g==0)? s : -1e30f;
  float den = (g==0)? 1.f : 0.f;

  int beg=rowptr[n], end=rowptr[n+1], p=beg;
  for (; p+8<=end; p+=8){
    int2 pA = epack[p+g], pB = epack[p+4+g];
    int iA = (pA.x & 0xFFFFF)<<8, rA = (pA.x>>20)<<7; float wA = __int_as_float(pA.y);
    int iB = (pB.x & 0xFFFFF)<<8, rB = (pB.x>>20)<<7; float wB = __int_as_float(pB.y);
    f16x8 xvA = *(const f16x8*)&xg2[(size_t)iA + ch];
    f16x8 eeA = *(const f16x8*)&efb2h[rA + ch];
    f16x8 xvB = *(const f16x8*)&xg2[(size_t)iB + ch];
    f16x8 eeB = *(const f16x8*)&efb2h[rB + ch];
    _Float16 hA=(_Float16)wA, hB=(_Float16)wB;
    f16x8 wA8, wB8;
    #pragma unroll
    for (int z=0;z<8;z++){ wA8[z]=hA; wB8[z]=hB; }
    f16x8 mA = xvA + xrh + wA8*eeA;
    f16x8 mB = xvB + xrh + wB8*eeB;
    float sA = dot_leaky(mA, ath);
    float sB = dot_leaky(mB, ath);
    #pragma unroll
    for (int off=1; off<16; off<<=1){
      sA += __shfl_xor(sA, off, 64);
      sB += __shfl_xor(sB, off, 64);
    }
    float nm = fmaxf(mx, fmaxf(sA, sB));
    float f = __expf(mx-nm), gA = __expf(sA-nm), gB = __expf(sB-nm);
    den = den*f + gA + gB;
    #pragma unroll
    for (int z=0;z<8;z++)
      acc[z] = acc[z]*f + gA*(float)xvA[z] + gB*(float)xvB[z];
    mx = nm;
  }
  for (; p+4<=end; p+=4){
    int2 pE = epack[p+g];
    int i0 = (pE.x & 0xFFFFF)<<8, r0 = (pE.x>>20)<<7; float w0 = __int_as_float(pE.y);
    f16x8 xv = *(const f16x8*)&xg2[(size_t)i0 + ch];
    f16x8 ee = *(const f16x8*)&efb2h[r0 + ch];
    _Float16 h0=(_Float16)w0;
    f16x8 w8;
    #pragma unroll
    for (int z=0;z<8;z++) w8[z]=h0;
    f16x8 m8 = xv + xrh + w8*ee;
    float sc = redux16(dot_leaky(m8, ath));
    float nm = fmaxf(mx, sc);
    float f = __expf(mx-nm), ge = __expf(sc-nm);
    den = den*f + ge;
    #pragma unroll
    for (int z=0;z<8;z++) acc[z] = acc[z]*f + ge*(float)xv[z];
    mx = nm;
  }
  int rem = end - p;
  if (g < rem){
    int2 pE = epack[p+g];
    int i0 = (pE.x & 0xFFFFF)<<8, r0 = (pE.x>>20)<<7; float w0 = __int_as_float(pE.y);
    f16x8 xv = *(const f16x8*)&xg2[(size_t)i0 + ch];
    f16x8 ee = *(const f16x8*)&efb2h[r0 + ch];
    _Float16 h0=(_Float16)w0;
    f16x8 w8;
    #pragma unroll
    for (int z=0;z<8;z++) w8[z]=h0;
    f16x8 m8 = xv + xrh + w8*ee;
    float sc = redux16(dot_leaky(m8, ath));
    float nm = fmaxf(mx, sc);
    float f = __expf(mx-nm), ge = __expf(sc-nm);
    den = den*f + ge;
    #pragma unroll
    for (int z=0;z<8;z++) acc[z] = acc[z]*f + ge*(float)xv[z];
    mx = nm;
  }
  // butterfly-merge the 4 group states
  #pragma unroll
  for (int off=16; off<=32; off<<=1){
    float mo = __shfl_xor(mx, off, 64);
    float dn = __shfl_xor(den, off, 64);
    float ao[8];
    #pragma unroll
    for (int z=0;z<8;z++) ao[z] = __shfl_xor(acc[z], off, 64);
    float mt = fmaxf(mx, mo);
    float fs = __expf(mx-mt), fo = __expf(mo-mt);
    den = den*fs + dn*fo;
    #pragma unroll
    for (int z=0;z<8;z++) acc[z] = acc[z]*fs + ao[z]*fo;
    mx = mt;
  }
  float inv = 1.f/(den + 1e-16f);
  if (g == 0){
    f32x4 b0 = *(const f32x4*)&bias2[ch];
    f32x4 b1 = *(const f32x4*)&bias2[ch+4];
    f32x4 o0, o1;
    #pragma unroll
    for (int z=0;z<4;z++){ o0[z] = fmaxf(acc[z]*inv   + b0[z], 0.f);
                           o1[z] = fmaxf(acc[4+z]*inv + b1[z], 0.f); }
    *(f32x4*)&h2[(size_t)n*128 + ch]     = o0;
    *(f32x4*)&h2[(size_t)n*128 + ch + 4] = o1;
  }
}

// ---------- graph boundaries ----------
__global__ void k_start(const int* __restrict__ batch, int* __restrict__ start, int N){
  int i = blockIdx.x*256 + threadIdx.x;
  if (i >= N) return;
  int b = batch[i];
  int pb = (i==0)? -1 : batch[i-1];
  for (int g=pb+1; g<=b; g++) start[g] = i;
  if (i == N-1){ for (int g=b+1; g<=NG; g++) start[g] = N; }
}

// ---------- pooling stage A ----------
#define PCHUNK 32
__global__ __launch_bounds__(256) void k_pool_part(const float* __restrict__ x, const _Float16* __restrict__ h1,
                       const float* __restrict__ h2, const int* __restrict__ batch,
                       unsigned* __restrict__ umax, float* __restrict__ fsum, int N){
  int c0 = blockIdx.x * PCHUNK;
  int c1 = min(c0 + PCHUNK, N);
  if (c0 >= N) return;
  int t = threadIdx.x;
  float mx0 = -INFINITY, sm0 = 0.f, mx1 = -INFINITY, sm1 = 0.f;
  int bcur = batch[c0];
  for (int i=c0;i<c1;i++){
    int b = batch[i];
    if (b != bcur){
      atomicMax(&umax[bcur*512 + t], enc_f(mx0));
      atomicAdd(&fsum[bcur*512 + t], sm0);
      atomicMax(&umax[bcur*512 + 256 + t], enc_f(mx1));
      atomicAdd(&fsum[bcur*512 + 256 + t], sm1);
      mx0 = mx1 = -INFINITY; sm0 = sm1 = 0.f; bcur = b;
    }
    float v0 = x[(size_t)i*256 + t];
    float v1 = (t<128) ? (float)h1[(size_t)i*128 + t] : h2[(size_t)i*128 + (t-128)];
    mx0 = fmaxf(mx0, v0); sm0 += v0;
    mx1 = fmaxf(mx1, v1); sm1 += v1;
  }
  atomicMax(&umax[bcur*512 + t], enc_f(mx0));
  atomicAdd(&fsum[bcur*512 + t], sm0);
  atomicMax(&umax[bcur*512 + 256 + t], enc_f(mx1));
  atomicAdd(&fsum[bcur*512 + 256 + t], sm1);
}

// ---------- pooling stage B ----------
__global__ void k_pool_final(const unsigned* __restrict__ umax, const float* __restrict__ fsum,
                             const int* __restrict__ start, float* __restrict__ xpool){
  int g = blockIdx.x; int f = blockIdx.y*256 + threadIdx.x;
  float m = dec_f(umax[g*512 + f]);
  if (!isfinite(m)) m = 0.f;
  int cnt = start[g+1] - start[g];
  xpool[g*1024 + f]       = m;
  xpool[g*1024 + 512 + f] = fsum[g*512 + f] / (float)max(cnt,1);
}

__global__ __launch_bounds__(256) void k_mlp1(const float* __restrict__ xpool, const float* __restrict__ W1,
                       const float* __restrict__ b1, float* __restrict__ hmid){
  __shared__ float part[256];
  int g = blockIdx.x; int c = threadIdx.x & 127; int half = threadIdx.x >> 7;
  float a0=0.f,a1=0.f,a2=0.f,a3=0.f;
  int kb = half*512;
  #pragma unroll 4
  for (int k=0;k<512;k+=4){
    a0 += xpool[g*1024+kb+k+0]*W1[(kb+k+0)*128+c];
    a1 += xpool[g*1024+kb+k+1]*W1[(kb+k+1)*128+c];
    a2 += xpool[g*1024+kb+k+2]*W1[(kb+k+2)*128+c];
    a3 += xpool[g*1024+kb+k+3]*W1[(kb+k+3)*128+c];
  }
  part[threadIdx.x] = (a0+a1)+(a2+a3);
  __syncthreads();
  if (half==0){
    float a = part[c] + part[128+c] + b1[c];
    hmid[g*128+c] = fmaxf(a, 0.f);
  }
}
__global__ void k_mlp2(const float* __restrict__ hmid, const float* __restrict__ W2,
                       const float* __restrict__ b2, float* __restrict__ out){
  int g = threadIdx.x; if (g >= NG) return;
  float a = b2[0];
  for (int k=0;k<128;k++) a += hmid[g*128+k]*W2[k];
  out[g] = a;
}

extern "C" void kernel_launch(void* const* d_in, const int* in_sizes, int n_in,
                              void* d_out, int out_size, void* d_ws, size_t ws_size,
                              hipStream_t stream) {
  const float* x     = (const float*)d_in[0];
  const int*   eidx  = (const int*)d_in[1];
  const int*   eattr = (const int*)d_in[2];
  const float* ew    = (const float*)d_in[3];
  const int*   batch = (const int*)d_in[4];
  const float* irf   = (const float*)d_in[5];
  const float* emb   = (const float*)d_in[6];
  const float* Wl1   = (const float*)d_in[7];
  const float* bl1   = (const float*)d_in[8];
  const float* Wr1   = (const float*)d_in[9];
  const float* br1   = (const float*)d_in[10];
  const float* We1   = (const float*)d_in[11];
  const float* att1  = (const float*)d_in[12];
  const float* bias1 = (const float*)d_in[13];
  const float* Wl2   = (const float*)d_in[14];
  const float* bl2   = (const float*)d_in[15];
  const float* Wr2   = (const float*)d_in[16];
  const float* br2   = (const float*)d_in[17];
  const float* We2   = (const float*)d_in[18];
  const float* att2  = (const float*)d_in[19];
  const float* bias2 = (const float*)d_in[20];
  const float* skipW = (const float*)d_in[21];
  const float* skipb = (const float*)d_in[22];
  const float* W1    = (const float*)d_in[23];
  const float* b1    = (const float*)d_in[24];
  const float* W2    = (const float*)d_in[25];
  const float* b2    = (const float*)d_in[26];

  const int N = in_sizes[4];        // 50000
  const int E = in_sizes[3];        // 800000
  const int* srcp = eidx;
  const int* dstp = eidx + E;

  // ---- workspace carve ----
  char* w = (char*)d_ws;
  size_t off = 0;
  auto alloc = [&](size_t bytes)->void*{
    size_t o = off; off = (off + bytes + 255) & ~(size_t)255; return (void*)(w + o);
  };
  float* base  = (float*)alloc((size_t)40*EDIM*4);
  _Float16* efb1h = (_Float16*)alloc((size_t)40*256*2);
  _Float16* efb2h = (_Float16*)alloc((size_t)40*128*2);
  _Float16* W1cat = (_Float16*)alloc((size_t)640*256*2);
  _Float16* W2cat = (_Float16*)alloc((size_t)256*128*2);
  _Float16* Wecat = (_Float16*)alloc((size_t)384*32*2);
  float* bcat1 = (float*)alloc((size_t)640*4);
  float* bcat2 = (float*)alloc((size_t)256*4);
  _Float16* att1h = (_Float16*)alloc((size_t)256*2);
  _Float16* att2h = (_Float16*)alloc((size_t)128*2);
  // zero-init region
  size_t zoff0 = off;
  int*   cnt   = (int*)alloc((size_t)N*4);
  int*   fillc = (int*)alloc((size_t)N*4);
  unsigned* umax = (unsigned*)alloc((size_t)NG*512*4);
  float* fsum  = (float*)alloc((size_t)NG*512*4);
  float* bcatE = (float*)alloc((size_t)384*4);
  size_t zlen = off - zoff0;
  int*   rowptr= (int*)alloc((size_t)(N+1)*4);
  int*   incl  = (int*)alloc((size_t)N*4);
  int*   bsum  = (int*)alloc((size_t)64*4);
  int2*  epack = (int2*)alloc((size_t)E*8);
  float* lf    = (float*)alloc((size_t)N*EDIM*4);
  _Float16* xh = (_Float16*)alloc((size_t)N*256*2);
  _Float16* xg = (_Float16*)alloc((size_t)N*640*2);
  _Float16* efsc = (_Float16*)alloc((size_t)N*384*2);
  _Float16* h1 = (_Float16*)alloc((size_t)N*128*2);
  int*   start = (int*)alloc((size_t)(NG+1)*4);
  float* xpool = (float*)alloc((size_t)NG*1024*4);
  float* hmid  = (float*)alloc((size_t)NG*128*4);
  _Float16* xg2 = xg;       // reuse: xg dead after attn1

  float* outp  = (float*)d_out;        // (64,1)
  float* h2out = (float*)d_out + NG;   // (N,128)

  hipMemsetAsync((char*)d_ws + zoff0, 0, zlen, stream);

  k_setup<<<859, 256, 0, stream>>>(emb, irf, We1, We2, Wl1, Wr1, skipW, Wl2, Wr2,
                                   bl1, br1, skipb, bl2, br2, att1, att2,
                                   base, efb1h, efb2h, W1cat, W2cat, Wecat,
                                   bcat1, bcat2, att1h, att2h);
  k_xcvt<<<(N*256/8 + 255)/256, 256, 0, stream>>>(x, xh, N*256/8);

  k_count<<<(E+255)/256, 256, 0, stream>>>(dstp, cnt, E);
  int nb = (N + 1023)/1024;
  k_scan1<<<nb, 1024, 0, stream>>>(cnt, incl, bsum, N);
  k_scan2<<<1, 64, 0, stream>>>(bsum, nb);
  k_scan3<<<(N+255)/256, 256, 0, stream>>>(incl, bsum, rowptr, N);
  k_fill<<<(E+255)/256, 256, 0, stream>>>(srcp, dstp, eattr, ew, rowptr, fillc,
                                          epack, E);
  k_loopfeat<<<((size_t)N*32+255)/256, 256, 0, stream>>>(rowptr, epack, base, lf, N);

  int gy = (N + 127)/128;
  k_gemm_f16<<<dim3(5, gy), 256, 0, stream>>>(xh, W1cat, bcat1, xg, N, 640, 256);
  k_gemm_f32a<<<dim3(3, gy), 256, 0, stream>>>(lf, Wecat, bcatE, efsc, N, 384, 32);

  k_attn1<<<(N+3)/4, 256, 0, stream>>>(xg, efsc, efb1h, att1h, bias1,
                                       rowptr, epack, h1, N);

  k_gemm_f16<<<dim3(2, gy), 256, 0, stream>>>(h1, W2cat, bcat2, xg2, N, 256, 128);

  k_attn2<<<(N+3)/4, 256, 0, stream>>>(xg2, efsc, efb2h, att2h, bias2,
                                       rowptr, epack, h2out, N);

  k_start<<<(N+255)/256, 256, 0, stream>>>(batch, start, N);
  k_pool_part<<<(N+PCHUNK-1)/PCHUNK, 256, 0, stream>>>(x, h1, h2out, batch, umax, fsum, N);
  k_pool_final<<<dim3(NG,2), 256, 0, stream>>>(umax, fsum, start, xpool);
  k_mlp1<<<NG, 256, 0, stream>>>(xpool, W1, b1, hmid);
  k_mlp2<<<1, 64, 0, stream>>>(hmid, W2, b2, outp);
  (void)n_in; (void)out_size; (void)ws_size;
}